// Round 2
// baseline (3879.309 us; speedup 1.0000x reference)
//
#include <hip/hip_runtime.h>
#include <math.h>

// Problem constants (fixed by the reference)
#define NPTS 150000
#define CH   128
#define NSEG_ 4096
#define KOFF 27
#define BN_EPS 1e-5f

// ---------- helpers ----------
__device__ __forceinline__ unsigned int fenc(float f) {
    unsigned int b = __float_as_uint(f);
    return (b & 0x80000000u) ? ~b : (b | 0x80000000u);
}
__device__ __forceinline__ float fdec(unsigned int u) {
    return __uint_as_float((u & 0x80000000u) ? (u & 0x7fffffffu) : ~u);
}

__global__ void zero_kernel(float4* __restrict__ p, int n4) {
    for (int i = blockIdx.x * 256 + threadIdx.x; i < n4; i += gridDim.x * 256)
        p[i] = make_float4(0.f, 0.f, 0.f, 0.f);
}

// ---------- GEMM: C[N,128] = A'[N,128] @ W[128,128] ----------
// FLAGS: 1=ACEN (A = pw - seg[cl]*invcnt), 2=ABN (A = relu(A*sc+sh)), 4=ACCUM (C += ),
//        8=STATS (column sum/sumsq atomics), 16=MAXRED (global max of outputs)
template<int FLAGS>
__global__ __launch_bounds__(256) void gemm128(
    const float* __restrict__ A, const float* __restrict__ W, float* __restrict__ C,
    const int* __restrict__ cl, const float* __restrict__ seg, const float* __restrict__ invcnt,
    const float* __restrict__ bnsc, const float* __restrict__ bnsh,
    float* __restrict__ colsum, float* __restrict__ colsq,
    unsigned int* __restrict__ gmax)
{
    constexpr bool ACEN   = (FLAGS & 1)  != 0;
    constexpr bool ABN    = (FLAGS & 2)  != 0;
    constexpr bool ACCUM  = (FLAGS & 4)  != 0;
    constexpr bool STATS  = (FLAGS & 8)  != 0;
    constexpr bool MAXRED = (FLAGS & 16) != 0;

    __shared__ float As[16][132];
    __shared__ float Bs[16][132];
    __shared__ unsigned int mred[256];

    const int t  = threadIdx.x;
    const int tx = t & 15, ty = t >> 4;
    const int m0 = blockIdx.x * 128;

    float acc[8][8];
#pragma unroll
    for (int i = 0; i < 8; ++i)
#pragma unroll
        for (int j = 0; j < 8; ++j) acc[i][j] = 0.f;

    for (int k0 = 0; k0 < 128; k0 += 16) {
        // A tile: 128 rows x 16 k  (512 float4)
#pragma unroll
        for (int h = 0; h < 2; ++h) {
            int f = t + h * 256;
            int row = f >> 2;
            int kq  = (f & 3) * 4;
            int gr  = m0 + row;
            float4 v = make_float4(0.f, 0.f, 0.f, 0.f);
            if (gr < NPTS) {
                v = *(const float4*)(A + (size_t)gr * CH + k0 + kq);
                if constexpr (ACEN) {
                    int s = cl[gr];
                    float ic = invcnt[s];
                    float4 sv = *(const float4*)(seg + (size_t)s * CH + k0 + kq);
                    v.x -= sv.x * ic; v.y -= sv.y * ic; v.z -= sv.z * ic; v.w -= sv.w * ic;
                }
                if constexpr (ABN) {
                    float4 s4 = *(const float4*)(bnsc + k0 + kq);
                    float4 h4 = *(const float4*)(bnsh + k0 + kq);
                    v.x = fmaxf(v.x * s4.x + h4.x, 0.f);
                    v.y = fmaxf(v.y * s4.y + h4.y, 0.f);
                    v.z = fmaxf(v.z * s4.z + h4.z, 0.f);
                    v.w = fmaxf(v.w * s4.w + h4.w, 0.f);
                }
            }
            As[kq + 0][row] = v.x; As[kq + 1][row] = v.y;
            As[kq + 2][row] = v.z; As[kq + 3][row] = v.w;
        }
        // B tile: 16 k x 128 n
#pragma unroll
        for (int h = 0; h < 2; ++h) {
            int f = t + h * 256;
            int kk = f >> 5;
            int n4 = (f & 31) * 4;
            float4 v = *(const float4*)(W + (size_t)(k0 + kk) * CH + n4);
            *(float4*)&Bs[kk][n4] = v;
        }
        __syncthreads();
#pragma unroll
        for (int kk = 0; kk < 16; ++kk) {
            float a[8], b[8];
#pragma unroll
            for (int i = 0; i < 8; ++i) a[i] = As[kk][ty * 8 + i];
#pragma unroll
            for (int j = 0; j < 8; ++j) b[j] = Bs[kk][tx * 8 + j];
#pragma unroll
            for (int i = 0; i < 8; ++i)
#pragma unroll
                for (int j = 0; j < 8; ++j)
                    acc[i][j] = fmaf(a[i], b[j], acc[i][j]);
        }
        __syncthreads();
    }

    // epilogue
    float csum[8], csq[8];
#pragma unroll
    for (int j = 0; j < 8; ++j) { csum[j] = 0.f; csq[j] = 0.f; }
    unsigned int lmax = 0u;

#pragma unroll
    for (int i = 0; i < 8; ++i) {
        int gr = m0 + ty * 8 + i;
        if (gr < NPTS) {
            float* crow = C + (size_t)gr * CH + tx * 8;
            float v[8];
#pragma unroll
            for (int j = 0; j < 8; ++j) v[j] = acc[i][j];
            if constexpr (ACCUM) {
                float4 p0 = *(const float4*)crow;
                float4 p1 = *(const float4*)(crow + 4);
                v[0] += p0.x; v[1] += p0.y; v[2] += p0.z; v[3] += p0.w;
                v[4] += p1.x; v[5] += p1.y; v[6] += p1.z; v[7] += p1.w;
            }
            *(float4*)crow       = make_float4(v[0], v[1], v[2], v[3]);
            *(float4*)(crow + 4) = make_float4(v[4], v[5], v[6], v[7]);
            if constexpr (STATS) {
#pragma unroll
                for (int j = 0; j < 8; ++j) { csum[j] += v[j]; csq[j] += v[j] * v[j]; }
            }
            if constexpr (MAXRED) {
#pragma unroll
                for (int j = 0; j < 8; ++j) {
                    unsigned int e = fenc(v[j]);
                    if (e > lmax) lmax = e;
                }
            }
        }
    }

    if constexpr (STATS) {
        __syncthreads();
#pragma unroll
        for (int j = 0; j < 8; ++j) { As[ty][tx * 8 + j] = csum[j]; Bs[ty][tx * 8 + j] = csq[j]; }
        __syncthreads();
        if (t < 128) {
            float s = 0.f, q = 0.f;
#pragma unroll
            for (int r = 0; r < 16; ++r) { s += As[r][t]; q += Bs[r][t]; }
            atomicAdd(colsum + t, s);
            atomicAdd(colsq + t, q);
        }
    }
    if constexpr (MAXRED) {
        mred[t] = lmax;
        __syncthreads();
        for (int sft = 128; sft > 0; sft >>= 1) {
            if (t < sft) { unsigned int o = mred[t + sft]; if (o > mred[t]) mred[t] = o; }
            __syncthreads();
        }
        if (t == 0) atomicMax(gmax, mred[0]);
    }
}

// ---------- small kernels ----------
__global__ void count_kernel(const int* __restrict__ clusters, int* __restrict__ cnt) {
    const int tot = 3 * NPTS;
    for (int f = blockIdx.x * 256 + threadIdx.x; f < tot; f += gridDim.x * 256) {
        int i = f / NPTS;
        atomicAdd(cnt + i * NSEG_ + clusters[f], 1);
    }
}

__global__ void invcnt_kernel(const int* __restrict__ cnt, float* __restrict__ invc) {
    int x = blockIdx.x * 256 + threadIdx.x;
    if (x < 3 * NSEG_) {
        int c = cnt[x];
        invc[x] = 1.0f / (float)(c > 1 ? c : 1);
    }
}

__global__ void finalize_kernel(const float* __restrict__ colsum, const float* __restrict__ colsq,
                                const float* __restrict__ g, const float* __restrict__ b,
                                float* __restrict__ sc, float* __restrict__ sh)
{
    int c = threadIdx.x;  // 128
    float mean = colsum[c] / (float)NPTS;
    float var  = colsq[c] / (float)NPTS - mean * mean;
    float istd = rsqrtf(var + BN_EPS);
    float s = istd * g[c];
    sc[c] = s;
    sh[c] = b[c] - mean * s;
}

// pw = relu(bn(Y)); s1[cl] += pw; write pw
__global__ void pw_kernel(const float* __restrict__ Y, const float* __restrict__ sc, const float* __restrict__ sh,
                          const int* __restrict__ cl, float* __restrict__ pw, float* __restrict__ s1)
{
    const int tot = NPTS * 32;
    for (int f = blockIdx.x * 256 + threadIdx.x; f < tot; f += gridDim.x * 256) {
        int n = f >> 5, c4 = (f & 31) << 2;
        float4 y  = *(const float4*)(Y + (size_t)n * CH + c4);
        float4 s4 = *(const float4*)(sc + c4);
        float4 h4 = *(const float4*)(sh + c4);
        float4 p;
        p.x = fmaxf(y.x * s4.x + h4.x, 0.f);
        p.y = fmaxf(y.y * s4.y + h4.y, 0.f);
        p.z = fmaxf(y.z * s4.z + h4.z, 0.f);
        p.w = fmaxf(y.w * s4.w + h4.w, 0.f);
        *(float4*)(pw + (size_t)n * CH + c4) = p;
        int s = cl[n];
        float* sp = s1 + (size_t)s * CH + c4;
        atomicAdd(sp + 0, p.x); atomicAdd(sp + 1, p.y);
        atomicAdd(sp + 2, p.z); atomicAdd(sp + 3, p.w);
    }
}

// e = exp(q - max); s2[cl] += e; write in-place
__global__ void exp_kernel(float* __restrict__ q, const unsigned int* __restrict__ gmax,
                           const int* __restrict__ cl, float* __restrict__ s2)
{
    const float m = fdec(*gmax);
    const int tot = NPTS * 32;
    for (int f = blockIdx.x * 256 + threadIdx.x; f < tot; f += gridDim.x * 256) {
        int n = f >> 5, c4 = (f & 31) << 2;
        float4 v = *(const float4*)(q + (size_t)n * CH + c4);
        float4 e;
        e.x = expf(v.x - m); e.y = expf(v.y - m);
        e.z = expf(v.z - m); e.w = expf(v.w - m);
        *(float4*)(q + (size_t)n * CH + c4) = e;
        int s = cl[n];
        float* sp = s2 + (size_t)s * CH + c4;
        atomicAdd(sp + 0, e.x); atomicAdd(sp + 1, e.y);
        atomicAdd(sp + 2, e.z); atomicAdd(sp + 3, e.w);
    }
}

// pf = relu(bn(Y)) * e/(s2[cl]+1e-6); s3[cl] += pf  (pf not materialized)
__global__ void pf_kernel(const float* __restrict__ Y, const float* __restrict__ sc, const float* __restrict__ sh,
                          const float* __restrict__ e, const int* __restrict__ cl,
                          const float* __restrict__ s2, float* __restrict__ s3)
{
    const int tot = NPTS * 32;
    for (int f = blockIdx.x * 256 + threadIdx.x; f < tot; f += gridDim.x * 256) {
        int n = f >> 5, c4 = (f & 31) << 2;
        float4 y  = *(const float4*)(Y + (size_t)n * CH + c4);
        float4 s4 = *(const float4*)(sc + c4);
        float4 h4 = *(const float4*)(sh + c4);
        float4 ev = *(const float4*)(e + (size_t)n * CH + c4);
        int s = cl[n];
        float4 d = *(const float4*)(s2 + (size_t)s * CH + c4);
        float4 p;
        p.x = fmaxf(y.x * s4.x + h4.x, 0.f) * (ev.x / (d.x + 1e-6f));
        p.y = fmaxf(y.y * s4.y + h4.y, 0.f) * (ev.y / (d.y + 1e-6f));
        p.z = fmaxf(y.z * s4.z + h4.z, 0.f) * (ev.z / (d.z + 1e-6f));
        p.w = fmaxf(y.w * s4.w + h4.w, 0.f) * (ev.w / (d.w + 1e-6f));
        float* sp = s3 + (size_t)s * CH + c4;
        atomicAdd(sp + 0, p.x); atomicAdd(sp + 1, p.y);
        atomicAdd(sp + 2, p.z); atomicAdd(sp + 3, p.w);
    }
}

// adp = softmax(feat @ adp_W, axis=1); agg = sum_l adp[:,l] * s3_l[cl_l]
__global__ __launch_bounds__(256) void adpagg_kernel(
    const float* __restrict__ feat, const float* __restrict__ adpW,
    const int* __restrict__ cl0, const int* __restrict__ cl1, const int* __restrict__ cl2,
    const float* __restrict__ s30, const float* __restrict__ s31, const float* __restrict__ s32,
    float* __restrict__ agg)
{
    __shared__ float ftile[64][132];
    __shared__ float wl[128][3];
    __shared__ float pr[64][3];
    __shared__ int   cls[64][3];
    const int t = threadIdx.x;
    const int n0 = blockIdx.x * 64;

    if (t < 128) { wl[t][0] = adpW[t * 3]; wl[t][1] = adpW[t * 3 + 1]; wl[t][2] = adpW[t * 3 + 2]; }
#pragma unroll
    for (int h = 0; h < 8; ++h) {
        int f = t + h * 256;
        int r = f >> 5, c4 = (f & 31) << 2;
        int n = n0 + r;
        float4 v = (n < NPTS) ? *(const float4*)(feat + (size_t)n * CH + c4)
                              : make_float4(0.f, 0.f, 0.f, 0.f);
        *(float4*)&ftile[r][c4] = v;
    }
    if (t < 64) {
        int n = n0 + t;
        if (n < NPTS) { cls[t][0] = cl0[n]; cls[t][1] = cl1[n]; cls[t][2] = cl2[n]; }
        else { cls[t][0] = 0; cls[t][1] = 0; cls[t][2] = 0; }
    }
    __syncthreads();

    if (t < 64) {
        float p0 = 0.f, p1 = 0.f, p2 = 0.f;
        for (int k = 0; k < 128; ++k) {
            float fv = ftile[t][k];
            p0 += fv * wl[k][0]; p1 += fv * wl[k][1]; p2 += fv * wl[k][2];
        }
        float m = fmaxf(p0, fmaxf(p1, p2));
        float e0 = expf(p0 - m), e1 = expf(p1 - m), e2 = expf(p2 - m);
        float inv = 1.f / (e0 + e1 + e2);
        pr[t][0] = e0 * inv; pr[t][1] = e1 * inv; pr[t][2] = e2 * inv;
    }
    __syncthreads();

#pragma unroll
    for (int h = 0; h < 8; ++h) {
        int f = t + h * 256;
        int r = f >> 5, c4 = (f & 31) << 2;
        int n = n0 + r;
        if (n < NPTS) {
            float a0 = pr[r][0], a1 = pr[r][1], a2 = pr[r][2];
            float4 v0 = *(const float4*)(s30 + (size_t)cls[r][0] * CH + c4);
            float4 v1 = *(const float4*)(s31 + (size_t)cls[r][1] * CH + c4);
            float4 v2 = *(const float4*)(s32 + (size_t)cls[r][2] * CH + c4);
            float4 o;
            o.x = a0 * v0.x + a1 * v1.x + a2 * v2.x;
            o.y = a0 * v0.y + a1 * v1.y + a2 * v2.y;
            o.z = a0 * v0.z + a1 * v1.z + a2 * v2.z;
            o.w = a0 * v0.w + a1 * v1.w + a2 * v2.w;
            *(float4*)(agg + (size_t)n * CH + c4) = o;
        }
    }
}

// fused = relu(bn(fuseY)) + feat
__global__ void fused_kernel(const float* __restrict__ fY, const float* __restrict__ sc, const float* __restrict__ sh,
                             const float* __restrict__ feat, float* __restrict__ outF)
{
    const int tot = NPTS * 32;
    for (int f = blockIdx.x * 256 + threadIdx.x; f < tot; f += gridDim.x * 256) {
        int n = f >> 5, c4 = (f & 31) << 2;
        float4 y  = *(const float4*)(fY + (size_t)n * CH + c4);
        float4 s4 = *(const float4*)(sc + c4);
        float4 h4 = *(const float4*)(sh + c4);
        float4 ft = *(const float4*)(feat + (size_t)n * CH + c4);
        float4 o;
        o.x = fmaxf(y.x * s4.x + h4.x, 0.f) + ft.x;
        o.y = fmaxf(y.y * s4.y + h4.y, 0.f) + ft.y;
        o.z = fmaxf(y.z * s4.z + h4.z, 0.f) + ft.z;
        o.w = fmaxf(y.w * s4.w + h4.w, 0.f) + ft.w;
        *(float4*)(outF + (size_t)n * CH + c4) = o;
    }
}

// grouped submanifold conv, 64 points/block, weights staged in LDS [k][i][g*4+o]
template<bool INBN>
__global__ __launch_bounds__(256) void conv_kernel(
    const float* __restrict__ X, const float* __restrict__ Wc, const int* __restrict__ nidx,
    const float* __restrict__ bnsc_g, const float* __restrict__ bnsh_g,
    float* __restrict__ Y, float* __restrict__ colsum, float* __restrict__ colsq)
{
    __shared__ float Wlds[KOFF * 4 * 128];  // 55296 B
    __shared__ int   nlds[64 * KOFF];       // 6912 B (aliased as reduction buffer later)
    __shared__ float bnp[256];
    float* red = (float*)nlds;

    const int t = threadIdx.x;
    const int g = t & 31, ps = t >> 5;
    const int n0 = blockIdx.x * 64;

    for (int f = t; f < KOFF * 512; f += 256) {
        int k = f >> 9, rem = f & 511;
        int gg = rem >> 4, ii = (rem >> 2) & 3, oo = rem & 3;
        Wlds[(k * 4 + ii) * 128 + gg * 4 + oo] = Wc[f];
    }
    for (int f = t; f < 64 * KOFF; f += 256) {
        int p = f / KOFF, k = f - p * KOFF;
        int n = n0 + p;
        nlds[f] = (n < NPTS) ? nidx[(size_t)n * KOFF + k] : -1;
    }
    if (INBN && t < 128) { bnp[t] = bnsc_g[t]; bnp[128 + t] = bnsh_g[t]; }
    __syncthreads();

    float4 bs4 = make_float4(1.f,1.f,1.f,1.f), bh4 = make_float4(0.f,0.f,0.f,0.f);
    if (INBN) { bs4 = *(float4*)&bnp[g * 4]; bh4 = *(float4*)&bnp[128 + g * 4]; }

    float acc[8][4];
#pragma unroll
    for (int j = 0; j < 8; ++j)
#pragma unroll
        for (int o = 0; o < 4; ++o) acc[j][o] = 0.f;

    for (int k = 0; k < KOFF; ++k) {
        const float4 w0 = *(const float4*)&Wlds[(k * 4 + 0) * 128 + g * 4];
        const float4 w1 = *(const float4*)&Wlds[(k * 4 + 1) * 128 + g * 4];
        const float4 w2 = *(const float4*)&Wlds[(k * 4 + 2) * 128 + g * 4];
        const float4 w3 = *(const float4*)&Wlds[(k * 4 + 3) * 128 + g * 4];
#pragma unroll
        for (int j = 0; j < 8; ++j) {
            int p = ps * 8 + j;
            int idx = nlds[p * KOFF + k];
            if (idx >= 0) {
                float4 v = *(const float4*)(X + (size_t)idx * CH + g * 4);
                if (INBN) {
                    v.x = v.x * bs4.x + bh4.x; v.y = v.y * bs4.y + bh4.y;
                    v.z = v.z * bs4.z + bh4.z; v.w = v.w * bs4.w + bh4.w;
                }
                acc[j][0] += v.x * w0.x + v.y * w1.x + v.z * w2.x + v.w * w3.x;
                acc[j][1] += v.x * w0.y + v.y * w1.y + v.z * w2.y + v.w * w3.y;
                acc[j][2] += v.x * w0.z + v.y * w1.z + v.z * w2.z + v.w * w3.z;
                acc[j][3] += v.x * w0.w + v.y * w1.w + v.z * w2.w + v.w * w3.w;
            }
        }
    }

    float s[4] = {0.f,0.f,0.f,0.f}, q[4] = {0.f,0.f,0.f,0.f};
#pragma unroll
    for (int j = 0; j < 8; ++j) {
        int n = n0 + ps * 8 + j;
        if (n < NPTS) {
            float4 o4 = make_float4(acc[j][0], acc[j][1], acc[j][2], acc[j][3]);
            *(float4*)(Y + (size_t)n * CH + g * 4) = o4;
            s[0] += o4.x; s[1] += o4.y; s[2] += o4.z; s[3] += o4.w;
            q[0] += o4.x * o4.x; q[1] += o4.y * o4.y;
            q[2] += o4.z * o4.z; q[3] += o4.w * o4.w;
        }
    }
    __syncthreads();  // done reading nlds; safe to alias as red
    *(float4*)&red[ps * 128 + g * 4] = make_float4(s[0], s[1], s[2], s[3]);
    __syncthreads();
    if (t < 128) {
        float tot = 0.f;
#pragma unroll
        for (int r = 0; r < 8; ++r) tot += red[r * 128 + t];
        atomicAdd(colsum + t, tot);
    }
    __syncthreads();
    *(float4*)&red[ps * 128 + g * 4] = make_float4(q[0], q[1], q[2], q[3]);
    __syncthreads();
    if (t < 128) {
        float tot = 0.f;
#pragma unroll
        for (int r = 0; r < 8; ++r) tot += red[r * 128 + t];
        atomicAdd(colsq + t, tot);
    }
}

// out = relu(bn2(conv2out) + fused)   (safe in-place: same-index elementwise)
__global__ void final_kernel(const float* __restrict__ c2, const float* __restrict__ sc, const float* __restrict__ sh,
                             const float* __restrict__ fused, float* __restrict__ out)
{
    const int tot = NPTS * 32;
    for (int f = blockIdx.x * 256 + threadIdx.x; f < tot; f += gridDim.x * 256) {
        int n = f >> 5, c4 = (f & 31) << 2;
        float4 y  = *(const float4*)(c2 + (size_t)n * CH + c4);
        float4 s4 = *(const float4*)(sc + c4);
        float4 h4 = *(const float4*)(sh + c4);
        float4 r  = *(const float4*)(fused + (size_t)n * CH + c4);
        float4 o;
        o.x = fmaxf(y.x * s4.x + h4.x + r.x, 0.f);
        o.y = fmaxf(y.y * s4.y + h4.y + r.y, 0.f);
        o.z = fmaxf(y.z * s4.z + h4.z + r.z, 0.f);
        o.w = fmaxf(y.w * s4.w + h4.w + r.w, 0.f);
        *(float4*)(out + (size_t)n * CH + c4) = o;
    }
}

// ---------- host ----------
extern "C" void kernel_launch(void* const* d_in, const int* in_sizes, int n_in,
                              void* d_out, int out_size, void* d_ws, size_t ws_size,
                              hipStream_t stream) {
    (void)in_sizes; (void)n_in; (void)out_size;
    const float* feat    = (const float*)d_in[0];
    const float* lw_W    = (const float*)d_in[1];
    const float* lw_g    = (const float*)d_in[2];
    const float* lw_b    = (const float*)d_in[3];
    const float* w_W     = (const float*)d_in[4];
    const float* proj_W  = (const float*)d_in[5];
    const float* proj_g  = (const float*)d_in[6];
    const float* proj_b  = (const float*)d_in[7];
    const float* adp_W   = (const float*)d_in[8];
    const float* fuse_W  = (const float*)d_in[9];
    const float* fuse_g  = (const float*)d_in[10];
    const float* fuse_b  = (const float*)d_in[11];
    const float* conv1_W = (const float*)d_in[12];
    const float* norm1_g = (const float*)d_in[13];
    const float* norm1_b = (const float*)d_in[14];
    const float* conv2_W = (const float*)d_in[15];
    const float* norm2_g = (const float*)d_in[16];
    const float* norm2_b = (const float*)d_in[17];
    const int*   clusters= (const int*)d_in[18];
    const int*   nidx    = (const int*)d_in[19];
    float* out = (float*)d_out;

    const size_t NC  = (size_t)NPTS * CH;       // 19.2M floats
    const size_t SEG = (size_t)NSEG_ * CH;      // 524288 floats
    // Z layout: s1[3*SEG] s2[3*SEG] s3[3*SEG] cnt[3*NSEG] invc[3*NSEG] stats[10*256] scsh[10*256] qmax[4]
    const size_t zwords = 9 * SEG + 6 * NSEG_ + 20 * 256 + 4;
    const size_t needed = (2 * NC + zwords) * sizeof(float);   // ~172.6 MB
    if (ws_size < needed) return;  // clean fail (diagnosable) instead of GPU memory fault

    float* ws = (float*)d_ws;
    float* W0 = ws;               // big scratch 0
    float* W1 = ws + NC;          // big scratch 1
    float* Z  = ws + 2 * NC;
    float* s1 = Z;
    float* s2 = Z + 3 * SEG;
    float* s3 = Z + 6 * SEG;
    int*   cnt   = (int*)(Z + 9 * SEG);
    float* invc  = Z + 9 * SEG + 3 * NSEG_;
    float* stats = Z + 9 * SEG + 6 * NSEG_;   // 10 slots x (128 sum + 128 sumsq)
    float* scsh  = stats + 10 * 256;          // 10 slots x (128 sc + 128 sh)
    unsigned int* qmax = (unsigned int*)(scsh + 10 * 256);  // 3 used

    const int gemmGrid = (NPTS + 127) / 128;
    const int convGrid = (NPTS + 63) / 64;
    const int mapGrid  = 2048;

    zero_kernel<<<2048, 256, 0, stream>>>((float4*)Z, (int)(zwords / 4));
    count_kernel<<<512, 256, 0, stream>>>(clusters, cnt);
    invcnt_kernel<<<(3 * NSEG_ + 255) / 256, 256, 0, stream>>>(cnt, invc);

    for (int i = 0; i < 3; ++i) {
        const int* cli = clusters + (size_t)i * NPTS;
        float* st  = stats + i * 256;
        float* ss  = scsh + i * 256;
        float* stp = stats + (3 + i) * 256;
        float* ssp = scsh + (3 + i) * 256;
        // L_i = feat @ lw_W[i] -> W0, with column stats
        gemm128<8><<<gemmGrid, 256, 0, stream>>>(feat, lw_W + (size_t)i * CH * CH, W0,
            nullptr, nullptr, nullptr, nullptr, nullptr, st, st + 128, nullptr);
        finalize_kernel<<<1, 128, 0, stream>>>(st, st + 128, lw_g + i * CH, lw_b + i * CH, ss, ss + 128);
        // pw = relu(bn(L_i)) -> W1; s1 += seg
        pw_kernel<<<mapGrid, 256, 0, stream>>>(W0, ss, ss + 128, cli, W1, s1 + i * SEG);
        // q = (pw - seg/cnt) @ w_W[i] -> OUT (scratch), global max
        gemm128<17><<<gemmGrid, 256, 0, stream>>>(W1, w_W + (size_t)i * CH * CH, out,
            cli, s1 + i * SEG, invc + i * NSEG_, nullptr, nullptr, nullptr, nullptr, qmax + i);
        // P_i = feat @ proj_W[i] -> W0, with column stats
        gemm128<8><<<gemmGrid, 256, 0, stream>>>(feat, proj_W + (size_t)i * CH * CH, W0,
            nullptr, nullptr, nullptr, nullptr, nullptr, stp, stp + 128, nullptr);
        finalize_kernel<<<1, 128, 0, stream>>>(stp, stp + 128, proj_g + i * CH, proj_b + i * CH, ssp, ssp + 128);
        // e = exp(q - max) in OUT; s2 += seg
        exp_kernel<<<mapGrid, 256, 0, stream>>>(out, qmax + i, cli, s2 + i * SEG);
        // pf = relu(bn(P_i)) * e/(s2[cl]+1e-6); s3 += seg
        pf_kernel<<<mapGrid, 256, 0, stream>>>(W0, ssp, ssp + 128, out, cli, s2 + i * SEG, s3 + i * SEG);
    }

    // agg (with in-kernel adp softmax) -> W0
    adpagg_kernel<<<convGrid, 256, 0, stream>>>(feat, adp_W,
        clusters, clusters + NPTS, clusters + 2 * (size_t)NPTS,
        s3, s3 + SEG, s3 + 2 * SEG, W0);

    // P3 -> W1, with stats
    {
        float* st = stats + 6 * 256; float* ss = scsh + 6 * 256;
        gemm128<8><<<gemmGrid, 256, 0, stream>>>(feat, proj_W + 3 * (size_t)CH * CH, W1,
            nullptr, nullptr, nullptr, nullptr, nullptr, st, st + 128, nullptr);
        finalize_kernel<<<1, 128, 0, stream>>>(st, st + 128, proj_g + 3 * CH, proj_b + 3 * CH, ss, ss + 128);
    }
    // fuseY = relu(bn(P3)) @ fuse_W[:128] -> OUT;  += agg @ fuse_W[128:], with stats
    gemm128<2><<<gemmGrid, 256, 0, stream>>>(W1, fuse_W, out,
        nullptr, nullptr, nullptr, scsh + 6 * 256, scsh + 6 * 256 + 128, nullptr, nullptr, nullptr);
    {
        float* st = stats + 7 * 256; float* ss = scsh + 7 * 256;
        gemm128<12><<<gemmGrid, 256, 0, stream>>>(W0, fuse_W + 128 * (size_t)CH, out,
            nullptr, nullptr, nullptr, nullptr, nullptr, st, st + 128, nullptr);
        finalize_kernel<<<1, 128, 0, stream>>>(st, st + 128, fuse_g, fuse_b, ss, ss + 128);
    }
    // fused = relu(bn(fuseY)) + feat -> W0  (persists as residual)
    fused_kernel<<<mapGrid, 256, 0, stream>>>(out, scsh + 7 * 256, scsh + 7 * 256 + 128, feat, W0);

    // conv1: W0 -> W1 (+stats slot8)
    {
        float* st = stats + 8 * 256; float* ss = scsh + 8 * 256;
        conv_kernel<false><<<convGrid, 256, 0, stream>>>(W0, conv1_W, nidx, nullptr, nullptr,
            W1, st, st + 128);
        finalize_kernel<<<1, 128, 0, stream>>>(st, st + 128, norm1_g, norm1_b, ss, ss + 128);
    }
    // conv2: bn1(W1) -> OUT (+stats slot9)
    {
        float* st = stats + 9 * 256; float* ss = scsh + 9 * 256;
        conv_kernel<true><<<convGrid, 256, 0, stream>>>(W1, conv2_W, nidx,
            scsh + 8 * 256, scsh + 8 * 256 + 128, out, st, st + 128);
        finalize_kernel<<<1, 128, 0, stream>>>(st, st + 128, norm2_g, norm2_b, ss, ss + 128);
    }
    // out = relu(bn2(OUT) + W0)  (in-place elementwise)
    final_kernel<<<mapGrid, 256, 0, stream>>>(out, scsh + 9 * 256, scsh + 9 * 256 + 128, W0, out);
}

// Round 3
// 1984.327 us; speedup vs baseline: 1.9550x; 1.9550x over previous
//
#include <hip/hip_runtime.h>
#include <math.h>

// Problem constants (fixed by the reference)
#define NPTS 150000
#define CH   128
#define NSEG_ 4096
#define KOFF 27
#define BN_EPS 1e-5f

// ---------- helpers ----------
__device__ __forceinline__ unsigned int fenc(float f) {
    unsigned int b = __float_as_uint(f);
    return (b & 0x80000000u) ? ~b : (b | 0x80000000u);
}
__device__ __forceinline__ float fdec(unsigned int u) {
    return __uint_as_float((u & 0x80000000u) ? (u & 0x7fffffffu) : ~u);
}

__global__ void zero_kernel(float4* __restrict__ p, int n4) {
    for (int i = blockIdx.x * 256 + threadIdx.x; i < n4; i += gridDim.x * 256)
        p[i] = make_float4(0.f, 0.f, 0.f, 0.f);
}

// ---------- GEMM: C[N,128] = A'[N,128] @ W[128,128] ----------
// FLAGS: 1=ACEN (A -= seg[cl]*invcnt, applied AFTER ABN), 2=ABN (A = relu(A*sc+sh)),
//        4=ACCUM (C += ), 8=STATS (column sum/sumsq atomics), 16=MAXRED (global max)
template<int FLAGS>
__global__ __launch_bounds__(256) void gemm128(
    const float* __restrict__ A, const float* __restrict__ W, float* __restrict__ C,
    const int* __restrict__ cl, const float* __restrict__ seg, const float* __restrict__ invcnt,
    const float* __restrict__ bnsc, const float* __restrict__ bnsh,
    float* __restrict__ colsum, float* __restrict__ colsq,
    unsigned int* __restrict__ gmax)
{
    constexpr bool ACEN   = (FLAGS & 1)  != 0;
    constexpr bool ABN    = (FLAGS & 2)  != 0;
    constexpr bool ACCUM  = (FLAGS & 4)  != 0;
    constexpr bool STATS  = (FLAGS & 8)  != 0;
    constexpr bool MAXRED = (FLAGS & 16) != 0;

    __shared__ float As[16][132];
    __shared__ float Bs[16][132];
    __shared__ unsigned int mred[256];

    const int t  = threadIdx.x;
    const int tx = t & 15, ty = t >> 4;
    const int m0 = blockIdx.x * 128;

    float acc[8][8];
#pragma unroll
    for (int i = 0; i < 8; ++i)
#pragma unroll
        for (int j = 0; j < 8; ++j) acc[i][j] = 0.f;

    for (int k0 = 0; k0 < 128; k0 += 16) {
        // A tile: 128 rows x 16 k  (512 float4)
#pragma unroll
        for (int h = 0; h < 2; ++h) {
            int f = t + h * 256;
            int row = f >> 2;
            int kq  = (f & 3) * 4;
            int gr  = m0 + row;
            float4 v = make_float4(0.f, 0.f, 0.f, 0.f);
            if (gr < NPTS) {
                v = *(const float4*)(A + (size_t)gr * CH + k0 + kq);
                if constexpr (ABN) {   // bn+relu FIRST
                    float4 s4 = *(const float4*)(bnsc + k0 + kq);
                    float4 h4 = *(const float4*)(bnsh + k0 + kq);
                    v.x = fmaxf(v.x * s4.x + h4.x, 0.f);
                    v.y = fmaxf(v.y * s4.y + h4.y, 0.f);
                    v.z = fmaxf(v.z * s4.z + h4.z, 0.f);
                    v.w = fmaxf(v.w * s4.w + h4.w, 0.f);
                }
                if constexpr (ACEN) {  // then center by cluster mean
                    int s = cl[gr];
                    float ic = invcnt[s];
                    float4 sv = *(const float4*)(seg + (size_t)s * CH + k0 + kq);
                    v.x -= sv.x * ic; v.y -= sv.y * ic; v.z -= sv.z * ic; v.w -= sv.w * ic;
                }
            }
            As[kq + 0][row] = v.x; As[kq + 1][row] = v.y;
            As[kq + 2][row] = v.z; As[kq + 3][row] = v.w;
        }
        // B tile: 16 k x 128 n
#pragma unroll
        for (int h = 0; h < 2; ++h) {
            int f = t + h * 256;
            int kk = f >> 5;
            int n4 = (f & 31) * 4;
            float4 v = *(const float4*)(W + (size_t)(k0 + kk) * CH + n4);
            *(float4*)&Bs[kk][n4] = v;
        }
        __syncthreads();
#pragma unroll
        for (int kk = 0; kk < 16; ++kk) {
            float a[8], b[8];
#pragma unroll
            for (int i = 0; i < 8; ++i) a[i] = As[kk][ty * 8 + i];
#pragma unroll
            for (int j = 0; j < 8; ++j) b[j] = Bs[kk][tx * 8 + j];
#pragma unroll
            for (int i = 0; i < 8; ++i)
#pragma unroll
                for (int j = 0; j < 8; ++j)
                    acc[i][j] = fmaf(a[i], b[j], acc[i][j]);
        }
        __syncthreads();
    }

    // epilogue
    float csum[8], csq[8];
#pragma unroll
    for (int j = 0; j < 8; ++j) { csum[j] = 0.f; csq[j] = 0.f; }
    unsigned int lmax = 0u;

#pragma unroll
    for (int i = 0; i < 8; ++i) {
        int gr = m0 + ty * 8 + i;
        if (gr < NPTS) {
            float* crow = C + (size_t)gr * CH + tx * 8;
            float v[8];
#pragma unroll
            for (int j = 0; j < 8; ++j) v[j] = acc[i][j];
            if constexpr (ACCUM) {
                float4 p0 = *(const float4*)crow;
                float4 p1 = *(const float4*)(crow + 4);
                v[0] += p0.x; v[1] += p0.y; v[2] += p0.z; v[3] += p0.w;
                v[4] += p1.x; v[5] += p1.y; v[6] += p1.z; v[7] += p1.w;
            }
            *(float4*)crow       = make_float4(v[0], v[1], v[2], v[3]);
            *(float4*)(crow + 4) = make_float4(v[4], v[5], v[6], v[7]);
            if constexpr (STATS) {
#pragma unroll
                for (int j = 0; j < 8; ++j) { csum[j] += v[j]; csq[j] += v[j] * v[j]; }
            }
            if constexpr (MAXRED) {
#pragma unroll
                for (int j = 0; j < 8; ++j) {
                    unsigned int e = fenc(v[j]);
                    if (e > lmax) lmax = e;
                }
            }
        }
    }

    if constexpr (STATS) {
        __syncthreads();
#pragma unroll
        for (int j = 0; j < 8; ++j) { As[ty][tx * 8 + j] = csum[j]; Bs[ty][tx * 8 + j] = csq[j]; }
        __syncthreads();
        if (t < 128) {
            float s = 0.f, q = 0.f;
#pragma unroll
            for (int r = 0; r < 16; ++r) { s += As[r][t]; q += Bs[r][t]; }
            atomicAdd(colsum + t, s);
            atomicAdd(colsq + t, q);
        }
    }
    if constexpr (MAXRED) {
        mred[t] = lmax;
        __syncthreads();
        for (int sft = 128; sft > 0; sft >>= 1) {
            if (t < sft) { unsigned int o = mred[t + sft]; if (o > mred[t]) mred[t] = o; }
            __syncthreads();
        }
        if (t == 0) atomicMax(gmax, mred[0]);
    }
}

// ---------- CSR build ----------
__global__ void count_kernel(const int* __restrict__ clusters, int* __restrict__ cnt) {
    const int tot = 3 * NPTS;
    for (int f = blockIdx.x * 256 + threadIdx.x; f < tot; f += gridDim.x * 256) {
        int i = f / NPTS;
        atomicAdd(cnt + i * NSEG_ + clusters[f], 1);
    }
}

__global__ void invcnt_kernel(const int* __restrict__ cnt, float* __restrict__ invc) {
    int x = blockIdx.x * 256 + threadIdx.x;
    if (x < 3 * NSEG_) {
        int c = cnt[x];
        invc[x] = 1.0f / (float)(c > 1 ? c : 1);
    }
}

// exclusive prefix sum over 4096 counts; one block (1024 thr) per layer
__global__ __launch_bounds__(1024) void scan_kernel(const int* __restrict__ cnt, int* __restrict__ off) {
    __shared__ int tot[1024];
    const int L = blockIdx.x;
    const int* c = cnt + L * NSEG_;
    int* o = off + L * NSEG_;
    const int t = threadIdx.x;
    int v[4];
    int s = 0;
#pragma unroll
    for (int j = 0; j < 4; ++j) { v[j] = s; s += c[t * 4 + j]; }
    tot[t] = s;
    __syncthreads();
    for (int d = 1; d < 1024; d <<= 1) {
        int x = (t >= d) ? tot[t - d] : 0;
        __syncthreads();
        tot[t] += x;
        __syncthreads();
    }
    int pre = (t == 0) ? 0 : tot[t - 1];
#pragma unroll
    for (int j = 0; j < 4; ++j) o[t * 4 + j] = pre + v[j];
}

__global__ void fill_kernel(const int* __restrict__ clusters, const int* __restrict__ off,
                            int* __restrict__ fpos, int* __restrict__ perm) {
    const int tot = 3 * NPTS;
    for (int f = blockIdx.x * 256 + threadIdx.x; f < tot; f += gridDim.x * 256) {
        int i = f / NPTS;
        int n = f - i * NPTS;
        int s = i * NSEG_ + clusters[f];
        int pos = off[s] + atomicAdd(fpos + s, 1);
        perm[(size_t)i * NPTS + pos] = n;
    }
}

// ---------- CSR gather segment-sum (no atomics) ----------
// MODE 0: sum relu(A*sc+sh)            (s1 over pw)
// MODE 1: sum A                        (s2 over e)
// MODE 2: sum relu(A*sc+sh)*E/(s2+eps) (s3 over pf)
template<int MODE>
__global__ __launch_bounds__(256) void gather_seg(
    const float* __restrict__ A, const float* __restrict__ E,
    const float* __restrict__ sc, const float* __restrict__ sh,
    const float* __restrict__ s2,
    const int* __restrict__ perm, const int* __restrict__ off, const int* __restrict__ cnt,
    float* __restrict__ segout)
{
    __shared__ float red[256];
    const int s = blockIdx.x;
    const int t = threadIdx.x;
    const int c = t & 127, h = t >> 7;
    const int start = off[s], m = cnt[s];
    float scv = 0.f, shv = 0.f, dinv = 0.f;
    if constexpr (MODE != 1) { scv = sc[c]; shv = sh[c]; }
    if constexpr (MODE == 2) { dinv = 1.0f / (s2[(size_t)s * CH + c] + 1e-6f); }
    float acc = 0.f;
    for (int j = h; j < m; j += 2) {
        int p = perm[start + j];
        float v = A[(size_t)p * CH + c];
        if constexpr (MODE != 1) v = fmaxf(v * scv + shv, 0.f);
        if constexpr (MODE == 2) v *= E[(size_t)p * CH + c] * dinv;
        acc += v;
    }
    red[t] = acc;
    __syncthreads();
    if (h == 0) segout[(size_t)s * CH + c] = red[c] + red[c + 128];
}

// ---------- small kernels ----------
__global__ void finalize_kernel(const float* __restrict__ colsum, const float* __restrict__ colsq,
                                const float* __restrict__ g, const float* __restrict__ b,
                                float* __restrict__ sc, float* __restrict__ sh)
{
    int c = threadIdx.x;  // 128
    float mean = colsum[c] / (float)NPTS;
    float var  = colsq[c] / (float)NPTS - mean * mean;
    float istd = rsqrtf(var + BN_EPS);
    float s = istd * g[c];
    sc[c] = s;
    sh[c] = b[c] - mean * s;
}

// e = exp(q - max), pure streaming map (in place)
__global__ void exp_map(float* __restrict__ q, const unsigned int* __restrict__ gmax) {
    const float m = fdec(*gmax);
    const int tot = NPTS * 32;
    for (int f = blockIdx.x * 256 + threadIdx.x; f < tot; f += gridDim.x * 256) {
        float4 v = *(const float4*)(q + (size_t)f * 4);
        v.x = expf(v.x - m); v.y = expf(v.y - m);
        v.z = expf(v.z - m); v.w = expf(v.w - m);
        *(float4*)(q + (size_t)f * 4) = v;
    }
}

// adp = softmax(feat @ adp_W, axis=1); agg = sum_l adp[:,l] * s3_l[cl_l]
__global__ __launch_bounds__(256) void adpagg_kernel(
    const float* __restrict__ feat, const float* __restrict__ adpW,
    const int* __restrict__ cl0, const int* __restrict__ cl1, const int* __restrict__ cl2,
    const float* __restrict__ s30, const float* __restrict__ s31, const float* __restrict__ s32,
    float* __restrict__ agg)
{
    __shared__ float ftile[64][132];
    __shared__ float wl[128][3];
    __shared__ float pr[64][3];
    __shared__ int   cls[64][3];
    const int t = threadIdx.x;
    const int n0 = blockIdx.x * 64;

    if (t < 128) { wl[t][0] = adpW[t * 3]; wl[t][1] = adpW[t * 3 + 1]; wl[t][2] = adpW[t * 3 + 2]; }
#pragma unroll
    for (int h = 0; h < 8; ++h) {
        int f = t + h * 256;
        int r = f >> 5, c4 = (f & 31) << 2;
        int n = n0 + r;
        float4 v = (n < NPTS) ? *(const float4*)(feat + (size_t)n * CH + c4)
                              : make_float4(0.f, 0.f, 0.f, 0.f);
        *(float4*)&ftile[r][c4] = v;
    }
    if (t < 64) {
        int n = n0 + t;
        if (n < NPTS) { cls[t][0] = cl0[n]; cls[t][1] = cl1[n]; cls[t][2] = cl2[n]; }
        else { cls[t][0] = 0; cls[t][1] = 0; cls[t][2] = 0; }
    }
    __syncthreads();

    if (t < 64) {
        float p0 = 0.f, p1 = 0.f, p2 = 0.f;
        for (int k = 0; k < 128; ++k) {
            float fv = ftile[t][k];
            p0 += fv * wl[k][0]; p1 += fv * wl[k][1]; p2 += fv * wl[k][2];
        }
        float m = fmaxf(p0, fmaxf(p1, p2));
        float e0 = expf(p0 - m), e1 = expf(p1 - m), e2 = expf(p2 - m);
        float inv = 1.f / (e0 + e1 + e2);
        pr[t][0] = e0 * inv; pr[t][1] = e1 * inv; pr[t][2] = e2 * inv;
    }
    __syncthreads();

#pragma unroll
    for (int h = 0; h < 8; ++h) {
        int f = t + h * 256;
        int r = f >> 5, c4 = (f & 31) << 2;
        int n = n0 + r;
        if (n < NPTS) {
            float a0 = pr[r][0], a1 = pr[r][1], a2 = pr[r][2];
            float4 v0 = *(const float4*)(s30 + (size_t)cls[r][0] * CH + c4);
            float4 v1 = *(const float4*)(s31 + (size_t)cls[r][1] * CH + c4);
            float4 v2 = *(const float4*)(s32 + (size_t)cls[r][2] * CH + c4);
            float4 o;
            o.x = a0 * v0.x + a1 * v1.x + a2 * v2.x;
            o.y = a0 * v0.y + a1 * v1.y + a2 * v2.y;
            o.z = a0 * v0.z + a1 * v1.z + a2 * v2.z;
            o.w = a0 * v0.w + a1 * v1.w + a2 * v2.w;
            *(float4*)(agg + (size_t)n * CH + c4) = o;
        }
    }
}

// fused = relu(bn(fuseY)) + feat
__global__ void fused_kernel(const float* __restrict__ fY, const float* __restrict__ sc, const float* __restrict__ sh,
                             const float* __restrict__ feat, float* __restrict__ outF)
{
    const int tot = NPTS * 32;
    for (int f = blockIdx.x * 256 + threadIdx.x; f < tot; f += gridDim.x * 256) {
        int n = f >> 5, c4 = (f & 31) << 2;
        float4 y  = *(const float4*)(fY + (size_t)n * CH + c4);
        float4 s4 = *(const float4*)(sc + c4);
        float4 h4 = *(const float4*)(sh + c4);
        float4 ft = *(const float4*)(feat + (size_t)n * CH + c4);
        float4 o;
        o.x = fmaxf(y.x * s4.x + h4.x, 0.f) + ft.x;
        o.y = fmaxf(y.y * s4.y + h4.y, 0.f) + ft.y;
        o.z = fmaxf(y.z * s4.z + h4.z, 0.f) + ft.z;
        o.w = fmaxf(y.w * s4.w + h4.w, 0.f) + ft.w;
        *(float4*)(outF + (size_t)n * CH + c4) = o;
    }
}

// grouped submanifold conv, 64 points/block, weights staged in LDS [k][i][g*4+o]
template<bool INBN>
__global__ __launch_bounds__(256) void conv_kernel(
    const float* __restrict__ X, const float* __restrict__ Wc, const int* __restrict__ nidx,
    const float* __restrict__ bnsc_g, const float* __restrict__ bnsh_g,
    float* __restrict__ Y, float* __restrict__ colsum, float* __restrict__ colsq)
{
    __shared__ float Wlds[KOFF * 4 * 128];  // 55296 B
    __shared__ int   nlds[64 * KOFF];       // 6912 B (aliased as reduction buffer later)
    __shared__ float bnp[256];
    float* red = (float*)nlds;

    const int t = threadIdx.x;
    const int g = t & 31, ps = t >> 5;
    const int n0 = blockIdx.x * 64;

    for (int f = t; f < KOFF * 512; f += 256) {
        int k = f >> 9, rem = f & 511;
        int gg = rem >> 4, ii = (rem >> 2) & 3, oo = rem & 3;
        Wlds[(k * 4 + ii) * 128 + gg * 4 + oo] = Wc[f];
    }
    for (int f = t; f < 64 * KOFF; f += 256) {
        int p = f / KOFF, k = f - p * KOFF;
        int n = n0 + p;
        nlds[f] = (n < NPTS) ? nidx[(size_t)n * KOFF + k] : -1;
    }
    if (INBN && t < 128) { bnp[t] = bnsc_g[t]; bnp[128 + t] = bnsh_g[t]; }
    __syncthreads();

    float4 bs4 = make_float4(1.f,1.f,1.f,1.f), bh4 = make_float4(0.f,0.f,0.f,0.f);
    if (INBN) { bs4 = *(float4*)&bnp[g * 4]; bh4 = *(float4*)&bnp[128 + g * 4]; }

    float acc[8][4];
#pragma unroll
    for (int j = 0; j < 8; ++j)
#pragma unroll
        for (int o = 0; o < 4; ++o) acc[j][o] = 0.f;

    for (int k = 0; k < KOFF; ++k) {
        const float4 w0 = *(const float4*)&Wlds[(k * 4 + 0) * 128 + g * 4];
        const float4 w1 = *(const float4*)&Wlds[(k * 4 + 1) * 128 + g * 4];
        const float4 w2 = *(const float4*)&Wlds[(k * 4 + 2) * 128 + g * 4];
        const float4 w3 = *(const float4*)&Wlds[(k * 4 + 3) * 128 + g * 4];
#pragma unroll
        for (int j = 0; j < 8; ++j) {
            int p = ps * 8 + j;
            int idx = nlds[p * KOFF + k];
            if (idx >= 0) {
                float4 v = *(const float4*)(X + (size_t)idx * CH + g * 4);
                if (INBN) {
                    v.x = v.x * bs4.x + bh4.x; v.y = v.y * bs4.y + bh4.y;
                    v.z = v.z * bs4.z + bh4.z; v.w = v.w * bs4.w + bh4.w;
                }
                acc[j][0] += v.x * w0.x + v.y * w1.x + v.z * w2.x + v.w * w3.x;
                acc[j][1] += v.x * w0.y + v.y * w1.y + v.z * w2.y + v.w * w3.y;
                acc[j][2] += v.x * w0.z + v.y * w1.z + v.z * w2.z + v.w * w3.z;
                acc[j][3] += v.x * w0.w + v.y * w1.w + v.z * w2.w + v.w * w3.w;
            }
        }
    }

    float s[4] = {0.f,0.f,0.f,0.f}, q[4] = {0.f,0.f,0.f,0.f};
#pragma unroll
    for (int j = 0; j < 8; ++j) {
        int n = n0 + ps * 8 + j;
        if (n < NPTS) {
            float4 o4 = make_float4(acc[j][0], acc[j][1], acc[j][2], acc[j][3]);
            *(float4*)(Y + (size_t)n * CH + g * 4) = o4;
            s[0] += o4.x; s[1] += o4.y; s[2] += o4.z; s[3] += o4.w;
            q[0] += o4.x * o4.x; q[1] += o4.y * o4.y;
            q[2] += o4.z * o4.z; q[3] += o4.w * o4.w;
        }
    }
    __syncthreads();  // done reading nlds; safe to alias as red
    *(float4*)&red[ps * 128 + g * 4] = make_float4(s[0], s[1], s[2], s[3]);
    __syncthreads();
    if (t < 128) {
        float tot = 0.f;
#pragma unroll
        for (int r = 0; r < 8; ++r) tot += red[r * 128 + t];
        atomicAdd(colsum + t, tot);
    }
    __syncthreads();
    *(float4*)&red[ps * 128 + g * 4] = make_float4(q[0], q[1], q[2], q[3]);
    __syncthreads();
    if (t < 128) {
        float tot = 0.f;
#pragma unroll
        for (int r = 0; r < 8; ++r) tot += red[r * 128 + t];
        atomicAdd(colsq + t, tot);
    }
}

// out = relu(bn2(conv2out) + fused)   (safe in-place: same-index elementwise)
__global__ void final_kernel(const float* __restrict__ c2, const float* __restrict__ sc, const float* __restrict__ sh,
                             const float* __restrict__ fused, float* __restrict__ out)
{
    const int tot = NPTS * 32;
    for (int f = blockIdx.x * 256 + threadIdx.x; f < tot; f += gridDim.x * 256) {
        int n = f >> 5, c4 = (f & 31) << 2;
        float4 y  = *(const float4*)(c2 + (size_t)n * CH + c4);
        float4 s4 = *(const float4*)(sc + c4);
        float4 h4 = *(const float4*)(sh + c4);
        float4 r  = *(const float4*)(fused + (size_t)n * CH + c4);
        float4 o;
        o.x = fmaxf(y.x * s4.x + h4.x + r.x, 0.f);
        o.y = fmaxf(y.y * s4.y + h4.y + r.y, 0.f);
        o.z = fmaxf(y.z * s4.z + h4.z + r.z, 0.f);
        o.w = fmaxf(y.w * s4.w + h4.w + r.w, 0.f);
        *(float4*)(out + (size_t)n * CH + c4) = o;
    }
}

// ---------- host ----------
extern "C" void kernel_launch(void* const* d_in, const int* in_sizes, int n_in,
                              void* d_out, int out_size, void* d_ws, size_t ws_size,
                              hipStream_t stream) {
    (void)in_sizes; (void)n_in; (void)out_size;
    const float* feat    = (const float*)d_in[0];
    const float* lw_W    = (const float*)d_in[1];
    const float* lw_g    = (const float*)d_in[2];
    const float* lw_b    = (const float*)d_in[3];
    const float* w_W     = (const float*)d_in[4];
    const float* proj_W  = (const float*)d_in[5];
    const float* proj_g  = (const float*)d_in[6];
    const float* proj_b  = (const float*)d_in[7];
    const float* adp_W   = (const float*)d_in[8];
    const float* fuse_W  = (const float*)d_in[9];
    const float* fuse_g  = (const float*)d_in[10];
    const float* fuse_b  = (const float*)d_in[11];
    const float* conv1_W = (const float*)d_in[12];
    const float* norm1_g = (const float*)d_in[13];
    const float* norm1_b = (const float*)d_in[14];
    const float* conv2_W = (const float*)d_in[15];
    const float* norm2_g = (const float*)d_in[16];
    const float* norm2_b = (const float*)d_in[17];
    const int*   clusters= (const int*)d_in[18];
    const int*   nidx    = (const int*)d_in[19];
    float* out = (float*)d_out;

    const size_t NC  = (size_t)NPTS * CH;
    const size_t SEG = (size_t)NSEG_ * CH;

    // Workspace layout (zero region first):
    //   [ZERO] cnt(3*4096 i32) fpos(3*4096 i32) stats(10*256 f32) qmax(4 u32)  = 27140 words
    //   [no-zero] off(3*4096) invc(3*4096) perm(3*NPTS) scsh(10*256) S1(SEG) S2(SEG) s3(3*SEG)
    const size_t zwords = 6 * NSEG_ + 10 * 256 + 4;                     // 27140
    const size_t needed = (2 * NC + zwords + 6 * NSEG_ + 3 * (size_t)NPTS
                           + 10 * 256 + 5 * SEG) * sizeof(float);       // ~166 MB
    if (ws_size < needed) return;  // clean diagnosable failure

    float* ws = (float*)d_ws;
    float* W0 = ws;
    float* W1 = ws + NC;
    float* Z  = ws + 2 * NC;
    int*   cnt   = (int*)Z;
    int*   fpos  = cnt + 3 * NSEG_;
    float* stats = (float*)(fpos + 3 * NSEG_);           // 10 x (128 sum + 128 sumsq)
    unsigned int* qmax = (unsigned int*)(stats + 10 * 256);
    int*   off   = (int*)(qmax + 4);
    float* invc  = (float*)(off + 3 * NSEG_);
    int*   perm  = (int*)(invc + 3 * NSEG_);
    float* scsh  = (float*)(perm + 3 * (size_t)NPTS);    // 10 x (128 sc + 128 sh)
    float* S1    = scsh + 10 * 256;
    float* S2    = S1 + SEG;
    float* s3    = S2 + SEG;

    const int gemmGrid = (NPTS + 127) / 128;
    const int convGrid = (NPTS + 63) / 64;
    const int mapGrid  = 2048;

    zero_kernel<<<64, 256, 0, stream>>>((float4*)Z, (int)(zwords / 4));
    count_kernel<<<512, 256, 0, stream>>>(clusters, cnt);
    invcnt_kernel<<<(3 * NSEG_ + 255) / 256, 256, 0, stream>>>(cnt, invc);
    scan_kernel<<<3, 1024, 0, stream>>>(cnt, off);
    fill_kernel<<<512, 256, 0, stream>>>(clusters, off, fpos, perm);

    for (int i = 0; i < 3; ++i) {
        const int* cli   = clusters + (size_t)i * NPTS;
        const int* permi = perm + (size_t)i * NPTS;
        const int* offi  = off + i * NSEG_;
        const int* cnti  = cnt + i * NSEG_;
        float* st  = stats + i * 256;
        float* ss  = scsh + i * 256;
        float* stp = stats + (3 + i) * 256;
        float* ssp = scsh + (3 + i) * 256;
        // L = feat @ lw_W[i] -> W0, column stats
        gemm128<8><<<gemmGrid, 256, 0, stream>>>(feat, lw_W + (size_t)i * CH * CH, W0,
            nullptr, nullptr, nullptr, nullptr, nullptr, st, st + 128, nullptr);
        finalize_kernel<<<1, 128, 0, stream>>>(st, st + 128, lw_g + i * CH, lw_b + i * CH, ss, ss + 128);
        // s1 = seg_sum(relu(bn(L))) via CSR gather (pw never materialized)
        gather_seg<0><<<NSEG_, 256, 0, stream>>>(W0, nullptr, ss, ss + 128, nullptr,
            permi, offi, cnti, S1);
        // q = (relu(bn(L)) - s1[cl]/cnt) @ w_W[i] -> OUT, global max
        gemm128<19><<<gemmGrid, 256, 0, stream>>>(W0, w_W + (size_t)i * CH * CH, out,
            cli, S1, invc + i * NSEG_, ss, ss + 128, nullptr, nullptr, qmax + i);
        // P = feat @ proj_W[i] -> W1, column stats
        gemm128<8><<<gemmGrid, 256, 0, stream>>>(feat, proj_W + (size_t)i * CH * CH, W1,
            nullptr, nullptr, nullptr, nullptr, nullptr, stp, stp + 128, nullptr);
        finalize_kernel<<<1, 128, 0, stream>>>(stp, stp + 128, proj_g + i * CH, proj_b + i * CH, ssp, ssp + 128);
        // e = exp(q - max) in place (OUT)
        exp_map<<<mapGrid, 256, 0, stream>>>(out, qmax + i);
        // s2 = seg_sum(e) via CSR gather
        gather_seg<1><<<NSEG_, 256, 0, stream>>>(out, nullptr, nullptr, nullptr, nullptr,
            permi, offi, cnti, S2);
        // s3 = seg_sum(relu(bn(P)) * e/(s2+eps)) via CSR gather (pf never materialized)
        gather_seg<2><<<NSEG_, 256, 0, stream>>>(W1, out, ssp, ssp + 128, S2,
            permi, offi, cnti, s3 + (size_t)i * SEG);
    }

    // agg (with in-kernel adp softmax) -> W0
    adpagg_kernel<<<convGrid, 256, 0, stream>>>(feat, adp_W,
        clusters, clusters + NPTS, clusters + 2 * (size_t)NPTS,
        s3, s3 + SEG, s3 + 2 * SEG, W0);

    // P3 -> W1, with stats
    {
        float* st = stats + 6 * 256; float* ss = scsh + 6 * 256;
        gemm128<8><<<gemmGrid, 256, 0, stream>>>(feat, proj_W + 3 * (size_t)CH * CH, W1,
            nullptr, nullptr, nullptr, nullptr, nullptr, st, st + 128, nullptr);
        finalize_kernel<<<1, 128, 0, stream>>>(st, st + 128, proj_g + 3 * CH, proj_b + 3 * CH, ss, ss + 128);
    }
    // fuseY = relu(bn(P3)) @ fuse_W[:128] -> OUT; += agg @ fuse_W[128:], stats
    gemm128<2><<<gemmGrid, 256, 0, stream>>>(W1, fuse_W, out,
        nullptr, nullptr, nullptr, scsh + 6 * 256, scsh + 6 * 256 + 128, nullptr, nullptr, nullptr);
    {
        float* st = stats + 7 * 256; float* ss = scsh + 7 * 256;
        gemm128<12><<<gemmGrid, 256, 0, stream>>>(W0, fuse_W + 128 * (size_t)CH, out,
            nullptr, nullptr, nullptr, nullptr, nullptr, st, st + 128, nullptr);
        finalize_kernel<<<1, 128, 0, stream>>>(st, st + 128, fuse_g, fuse_b, ss, ss + 128);
    }
    // fused = relu(bn(fuseY)) + feat -> W0 (residual)
    fused_kernel<<<mapGrid, 256, 0, stream>>>(out, scsh + 7 * 256, scsh + 7 * 256 + 128, feat, W0);

    // conv1: W0 -> W1 (+stats slot8)
    {
        float* st = stats + 8 * 256; float* ss = scsh + 8 * 256;
        conv_kernel<false><<<convGrid, 256, 0, stream>>>(W0, conv1_W, nidx, nullptr, nullptr,
            W1, st, st + 128);
        finalize_kernel<<<1, 128, 0, stream>>>(st, st + 128, norm1_g, norm1_b, ss, ss + 128);
    }
    // conv2: bn1(W1) -> OUT (+stats slot9)
    {
        float* st = stats + 9 * 256; float* ss = scsh + 9 * 256;
        conv_kernel<true><<<convGrid, 256, 0, stream>>>(W1, conv2_W, nidx,
            scsh + 8 * 256, scsh + 8 * 256 + 128, out, st, st + 128);
        finalize_kernel<<<1, 128, 0, stream>>>(st, st + 128, norm2_g, norm2_b, ss, ss + 128);
    }
    // out = relu(bn2(OUT) + W0)  (in-place elementwise)
    final_kernel<<<mapGrid, 256, 0, stream>>>(out, scsh + 9 * 256, scsh + 9 * 256 + 128, W0, out);
}

// Round 4
// 1676.229 us; speedup vs baseline: 2.3143x; 1.1838x over previous
//
#include <hip/hip_runtime.h>
#include <math.h>

#define NPTS 150000
#define CH   128
#define NSEG_ 4096
#define KOFF 27
#define BN_EPS 1e-5f

typedef __attribute__((ext_vector_type(8))) short bf16x8;
typedef __attribute__((ext_vector_type(4))) float f32x4;

// ---------- helpers ----------
__device__ __forceinline__ unsigned int fenc(float f) {
    unsigned int b = __float_as_uint(f);
    return (b & 0x80000000u) ? ~b : (b | 0x80000000u);
}
__device__ __forceinline__ float fdec(unsigned int u) {
    return __uint_as_float((u & 0x80000000u) ? (u & 0x7fffffffu) : ~u);
}
__device__ __forceinline__ unsigned short f2bf(float f) {
    unsigned int u = __float_as_uint(f);
    unsigned int r = (u + 0x7fffu + ((u >> 16) & 1u)) >> 16;
    return (unsigned short)r;
}
// bijective XCD swizzle (m204): consecutive output blocks stay on one XCD
__device__ __forceinline__ int xcd_swz(int bid, int nwg) {
    int q = nwg >> 3, r = nwg & 7;
    int xcd = bid & 7, idx = bid >> 3;
    return (xcd < r ? xcd * (q + 1) : r * (q + 1) + (xcd - r) * q) + idx;
}

__global__ void zero_kernel(float4* __restrict__ p, int n4) {
    for (int i = blockIdx.x * 256 + threadIdx.x; i < n4; i += gridDim.x * 256)
        p[i] = make_float4(0.f, 0.f, 0.f, 0.f);
}

// ---------- weight transpose+cvt: W[K][128] fp32 -> Wt[128][K] bf16 ----------
__global__ void wtr_kernel(const float* __restrict__ W, unsigned short* __restrict__ Wt, int K) {
    int i = blockIdx.x * 256 + threadIdx.x;
    if (i < 128 * K) {
        int n = i / K, k = i - n * K;
        Wt[i] = f2bf(W[(size_t)k * 128 + n]);
    }
}

// ---------- MFMA GEMM: C[N,128] = f(A)[N,K] @ W[K,128], Wt is [128][K] bf16 ----------
// FLAGS: 1=ACEN (A -= seg[cl]*invcnt after ABN), 2=ABN (A=relu(A*sc+sh)),
//        8=STATS, 16=MAXRED, 32=K256 (A1 = second fp32 A, plain, k=128..255)
template<int FLAGS>
__global__ __launch_bounds__(256) void gemm_mfma(
    const float* __restrict__ A0, const float* __restrict__ A1,
    const unsigned short* __restrict__ Wt, float* __restrict__ C,
    const int* __restrict__ cl, const float* __restrict__ seg,
    const float* __restrict__ invcnt,
    const float* __restrict__ bnsc, const float* __restrict__ bnsh,
    float* __restrict__ colsum, float* __restrict__ colsq,
    unsigned int* __restrict__ gmax)
{
    constexpr bool ACEN   = (FLAGS & 1)  != 0;
    constexpr bool ABN    = (FLAGS & 2)  != 0;
    constexpr bool STATS  = (FLAGS & 8)  != 0;
    constexpr bool MAXRED = (FLAGS & 16) != 0;
    constexpr bool K256   = (FLAGS & 32) != 0;
    constexpr int  KS = K256 ? 8 : 4;
    constexpr int  KW = KS * 32;   // Wt row length

    const int t  = threadIdx.x;
    const int l  = t & 63, w = t >> 6;
    const int lc = l & 15, lk = l >> 4;
    const int wr = w >> 1, wc = w & 1;           // 2x2 waves, each 64x64
    const int R  = blockIdx.x * 128 + wr * 64;
    const int C0 = wc * 64;

    f32x4 acc[4][4];
#pragma unroll
    for (int mi = 0; mi < 4; ++mi)
#pragma unroll
        for (int ni = 0; ni < 4; ++ni) acc[mi][ni] = (f32x4){0.f, 0.f, 0.f, 0.f};

#pragma unroll
    for (int ks = 0; ks < KS; ++ks) {
        const float* Asrc = A0;
        int ka = ks * 32;
        bool xf = true;
        if constexpr (K256) { if (ks >= 4) { Asrc = A1; ka -= 128; xf = false; } }
        const int kb = ka + lk * 8;

        bf16x8 b[4];
#pragma unroll
        for (int ni = 0; ni < 4; ++ni)
            b[ni] = *(const bf16x8*)(Wt + (size_t)(C0 + ni * 16 + lc) * KW + ks * 32 + lk * 8);

        float4 s0, s1v, h0, h1;
        if constexpr (ABN) {
            if (xf) {
                s0  = *(const float4*)(bnsc + kb); s1v = *(const float4*)(bnsc + kb + 4);
                h0  = *(const float4*)(bnsh + kb); h1  = *(const float4*)(bnsh + kb + 4);
            }
        }

        bf16x8 a[4];
#pragma unroll
        for (int mi = 0; mi < 4; ++mi) {
            int row = R + mi * 16 + lc;
            if (row > NPTS - 1) row = NPTS - 1;
            const float* ap = Asrc + (size_t)row * CH + kb;
            float4 v0 = *(const float4*)ap;
            float4 v1 = *(const float4*)(ap + 4);
            if constexpr (ABN) {
                if (xf) {
                    v0.x = fmaxf(v0.x * s0.x + h0.x, 0.f);  v0.y = fmaxf(v0.y * s0.y + h0.y, 0.f);
                    v0.z = fmaxf(v0.z * s0.z + h0.z, 0.f);  v0.w = fmaxf(v0.w * s0.w + h0.w, 0.f);
                    v1.x = fmaxf(v1.x * s1v.x + h1.x, 0.f); v1.y = fmaxf(v1.y * s1v.y + h1.y, 0.f);
                    v1.z = fmaxf(v1.z * s1v.z + h1.z, 0.f); v1.w = fmaxf(v1.w * s1v.w + h1.w, 0.f);
                }
            }
            if constexpr (ACEN) {
                int sg = cl[row];
                float ic = invcnt[sg];
                const float* sp = seg + (size_t)sg * CH + kb;
                float4 m0 = *(const float4*)sp, m1 = *(const float4*)(sp + 4);
                v0.x -= m0.x * ic; v0.y -= m0.y * ic; v0.z -= m0.z * ic; v0.w -= m0.w * ic;
                v1.x -= m1.x * ic; v1.y -= m1.y * ic; v1.z -= m1.z * ic; v1.w -= m1.w * ic;
            }
            union { unsigned short u[8]; bf16x8 v; } pk;
            pk.u[0] = f2bf(v0.x); pk.u[1] = f2bf(v0.y); pk.u[2] = f2bf(v0.z); pk.u[3] = f2bf(v0.w);
            pk.u[4] = f2bf(v1.x); pk.u[5] = f2bf(v1.y); pk.u[6] = f2bf(v1.z); pk.u[7] = f2bf(v1.w);
            a[mi] = pk.v;
        }
#pragma unroll
        for (int mi = 0; mi < 4; ++mi)
#pragma unroll
            for (int ni = 0; ni < 4; ++ni)
                acc[mi][ni] = __builtin_amdgcn_mfma_f32_16x16x32_bf16(a[mi], b[ni], acc[mi][ni], 0, 0, 0);
    }

    // epilogue: C write (+stats/max).  C/D layout: col=lane&15, row=(lane>>4)*4+reg  [m89]
    float s[4] = {0.f, 0.f, 0.f, 0.f}, q[4] = {0.f, 0.f, 0.f, 0.f};
    unsigned int lmax = 0u;
#pragma unroll
    for (int mi = 0; mi < 4; ++mi) {
#pragma unroll
        for (int r = 0; r < 4; ++r) {
            int row = R + mi * 16 + lk * 4 + r;
            if (row < NPTS) {
#pragma unroll
                for (int ni = 0; ni < 4; ++ni) {
                    float v = acc[mi][ni][r];
                    C[(size_t)row * CH + C0 + ni * 16 + lc] = v;
                    if constexpr (STATS) { s[ni] += v; q[ni] += v * v; }
                    if constexpr (MAXRED) { unsigned int e = fenc(v); if (e > lmax) lmax = e; }
                }
            }
        }
    }

    if constexpr (STATS) {
        __shared__ float reds[4][4][16], redq[4][4][16];
#pragma unroll
        for (int ni = 0; ni < 4; ++ni) {
            s[ni] += __shfl_xor(s[ni], 16); s[ni] += __shfl_xor(s[ni], 32);
            q[ni] += __shfl_xor(q[ni], 16); q[ni] += __shfl_xor(q[ni], 32);
        }
        if (lk == 0) {
#pragma unroll
            for (int ni = 0; ni < 4; ++ni) { reds[w][ni][lc] = s[ni]; redq[w][ni][lc] = q[ni]; }
        }
        __syncthreads();
        if (t < 128) {
            int half = t >> 6, fr = (t >> 4) & 3, cc = t & 15;
            atomicAdd(colsum + t, reds[half][fr][cc] + reds[half + 2][fr][cc]);
            atomicAdd(colsq  + t, redq[half][fr][cc] + redq[half + 2][fr][cc]);
        }
    }
    if constexpr (MAXRED) {
        __shared__ unsigned int smax;
#pragma unroll
        for (int d = 1; d < 64; d <<= 1) {
            unsigned int o = __shfl_xor(lmax, d);
            if (o > lmax) lmax = o;
        }
        if (t == 0) smax = 0u;
        __syncthreads();
        if (l == 0) atomicMax(&smax, lmax);
        __syncthreads();
        if (t == 0) atomicMax(gmax, smax);
    }
}

// ---------- CSR build ----------
__global__ void count_kernel(const int* __restrict__ clusters, int* __restrict__ cnt) {
    const int tot = 3 * NPTS;
    for (int f = blockIdx.x * 256 + threadIdx.x; f < tot; f += gridDim.x * 256) {
        int i = f / NPTS;
        atomicAdd(cnt + i * NSEG_ + clusters[f], 1);
    }
}

__global__ void invcnt_kernel(const int* __restrict__ cnt, float* __restrict__ invc) {
    int x = blockIdx.x * 256 + threadIdx.x;
    if (x < 3 * NSEG_) {
        int c = cnt[x];
        invc[x] = 1.0f / (float)(c > 1 ? c : 1);
    }
}

__global__ __launch_bounds__(1024) void scan_kernel(const int* __restrict__ cnt, int* __restrict__ off) {
    __shared__ int tot[1024];
    const int L = blockIdx.x;
    const int* c = cnt + L * NSEG_;
    int* o = off + L * NSEG_;
    const int t = threadIdx.x;
    int v[4];
    int s = 0;
#pragma unroll
    for (int j = 0; j < 4; ++j) { v[j] = s; s += c[t * 4 + j]; }
    tot[t] = s;
    __syncthreads();
    for (int d = 1; d < 1024; d <<= 1) {
        int x = (t >= d) ? tot[t - d] : 0;
        __syncthreads();
        tot[t] += x;
        __syncthreads();
    }
    int pre = (t == 0) ? 0 : tot[t - 1];
#pragma unroll
    for (int j = 0; j < 4; ++j) o[t * 4 + j] = pre + v[j];
}

__global__ void fill_kernel(const int* __restrict__ clusters, const int* __restrict__ off,
                            int* __restrict__ fpos, int* __restrict__ perm) {
    const int tot = 3 * NPTS;
    for (int f = blockIdx.x * 256 + threadIdx.x; f < tot; f += gridDim.x * 256) {
        int i = f / NPTS;
        int n = f - i * NPTS;
        int s = i * NSEG_ + clusters[f];
        int pos = off[s] + atomicAdd(fpos + s, 1);
        perm[(size_t)i * NPTS + pos] = n;
    }
}

// ---------- CSR gather segment-sum ----------
// MODE0: sum relu(A*sc+sh); MODE1: sum exp(Q-m); MODE2: sum relu(A*sc+sh)*exp(Q-m)*dinv
template<int MODE>
__global__ __launch_bounds__(256) void gather_seg(
    const float* __restrict__ A, const float* __restrict__ Q,
    const float* __restrict__ sc, const float* __restrict__ sh,
    const float* __restrict__ s2, const unsigned int* __restrict__ gmax,
    const int* __restrict__ perm, const int* __restrict__ off,
    const int* __restrict__ cnt, float* __restrict__ segout)
{
    __shared__ float red[256];
    const int s = blockIdx.x;
    const int t = threadIdx.x;
    const int c = t & 127, h = t >> 7;
    const int start = off[s], m = cnt[s];
    float mx = 0.f, scv = 0.f, shv = 0.f, dinv = 0.f;
    if constexpr (MODE >= 1) mx = fdec(*gmax);
    if constexpr (MODE != 1) { scv = sc[c]; shv = sh[c]; }
    if constexpr (MODE == 2) dinv = 1.0f / (s2[(size_t)s * CH + c] + 1e-6f);
    float acc = 0.f;
    for (int j = h; j < m; j += 2) {
        int p = perm[start + j];
        if constexpr (MODE == 0) {
            acc += fmaxf(A[(size_t)p * CH + c] * scv + shv, 0.f);
        } else if constexpr (MODE == 1) {
            acc += expf(Q[(size_t)p * CH + c] - mx);
        } else {
            acc += fmaxf(A[(size_t)p * CH + c] * scv + shv, 0.f)
                 * expf(Q[(size_t)p * CH + c] - mx) * dinv;
        }
    }
    red[t] = acc;
    __syncthreads();
    if (h == 0) segout[(size_t)s * CH + c] = red[c] + red[c + 128];
}

// ---------- small kernels ----------
__global__ void finalize_kernel(const float* __restrict__ colsum, const float* __restrict__ colsq,
                                const float* __restrict__ g, const float* __restrict__ b,
                                float* __restrict__ sc, float* __restrict__ sh)
{
    int c = threadIdx.x;
    float mean = colsum[c] / (float)NPTS;
    float var  = colsq[c] / (float)NPTS - mean * mean;
    float istd = rsqrtf(var + BN_EPS);
    float s = istd * g[c];
    sc[c] = s;
    sh[c] = b[c] - mean * s;
}

// adp = softmax(feat @ adp_W, axis=1); agg = sum_l adp[:,l] * s3_l[cl_l]
__global__ __launch_bounds__(256) void adpagg_kernel(
    const float* __restrict__ feat, const float* __restrict__ adpW,
    const int* __restrict__ cl0, const int* __restrict__ cl1, const int* __restrict__ cl2,
    const float* __restrict__ s30, const float* __restrict__ s31, const float* __restrict__ s32,
    float* __restrict__ agg)
{
    __shared__ float ftile[64][132];
    __shared__ float wl[128][3];
    __shared__ float pr[64][3];
    __shared__ int   cls[64][3];
    const int t = threadIdx.x;
    const int n0 = blockIdx.x * 64;

    if (t < 128) { wl[t][0] = adpW[t * 3]; wl[t][1] = adpW[t * 3 + 1]; wl[t][2] = adpW[t * 3 + 2]; }
#pragma unroll
    for (int h = 0; h < 8; ++h) {
        int f = t + h * 256;
        int r = f >> 5, c4 = (f & 31) << 2;
        int n = n0 + r;
        float4 v = (n < NPTS) ? *(const float4*)(feat + (size_t)n * CH + c4)
                              : make_float4(0.f, 0.f, 0.f, 0.f);
        *(float4*)&ftile[r][c4] = v;
    }
    if (t < 64) {
        int n = n0 + t;
        if (n < NPTS) { cls[t][0] = cl0[n]; cls[t][1] = cl1[n]; cls[t][2] = cl2[n]; }
        else { cls[t][0] = 0; cls[t][1] = 0; cls[t][2] = 0; }
    }
    __syncthreads();

    if (t < 64) {
        float p0 = 0.f, p1 = 0.f, p2 = 0.f;
        for (int k = 0; k < 128; ++k) {
            float fv = ftile[t][k];
            p0 += fv * wl[k][0]; p1 += fv * wl[k][1]; p2 += fv * wl[k][2];
        }
        float m = fmaxf(p0, fmaxf(p1, p2));
        float e0 = expf(p0 - m), e1 = expf(p1 - m), e2 = expf(p2 - m);
        float inv = 1.f / (e0 + e1 + e2);
        pr[t][0] = e0 * inv; pr[t][1] = e1 * inv; pr[t][2] = e2 * inv;
    }
    __syncthreads();

#pragma unroll
    for (int h = 0; h < 8; ++h) {
        int f = t + h * 256;
        int r = f >> 5, c4 = (f & 31) << 2;
        int n = n0 + r;
        if (n < NPTS) {
            float a0 = pr[r][0], a1 = pr[r][1], a2 = pr[r][2];
            float4 v0 = *(const float4*)(s30 + (size_t)cls[r][0] * CH + c4);
            float4 v1 = *(const float4*)(s31 + (size_t)cls[r][1] * CH + c4);
            float4 v2 = *(const float4*)(s32 + (size_t)cls[r][2] * CH + c4);
            float4 o;
            o.x = a0 * v0.x + a1 * v1.x + a2 * v2.x;
            o.y = a0 * v0.y + a1 * v1.y + a2 * v2.y;
            o.z = a0 * v0.z + a1 * v1.z + a2 * v2.z;
            o.w = a0 * v0.w + a1 * v1.w + a2 * v2.w;
            *(float4*)(agg + (size_t)n * CH + c4) = o;
        }
    }
}

// fused = relu(bn(fuseY)) + feat
__global__ void fused_kernel(const float* __restrict__ fY, const float* __restrict__ sc, const float* __restrict__ sh,
                             const float* __restrict__ feat, float* __restrict__ outF)
{
    const int tot = NPTS * 32;
    for (int f = blockIdx.x * 256 + threadIdx.x; f < tot; f += gridDim.x * 256) {
        int n = f >> 5, c4 = (f & 31) << 2;
        float4 y  = *(const float4*)(fY + (size_t)n * CH + c4);
        float4 s4 = *(const float4*)(sc + c4);
        float4 h4 = *(const float4*)(sh + c4);
        float4 ft = *(const float4*)(feat + (size_t)n * CH + c4);
        float4 o;
        o.x = fmaxf(y.x * s4.x + h4.x, 0.f) + ft.x;
        o.y = fmaxf(y.y * s4.y + h4.y, 0.f) + ft.y;
        o.z = fmaxf(y.z * s4.z + h4.z, 0.f) + ft.z;
        o.w = fmaxf(y.w * s4.w + h4.w, 0.f) + ft.w;
        *(float4*)(outF + (size_t)n * CH + c4) = o;
    }
}

// grouped submanifold conv, 128 points/block, 512 threads (2 blocks/CU -> 50% occ ceiling)
template<bool INBN>
__global__ __launch_bounds__(512) void conv_kernel(
    const float* __restrict__ X, const float* __restrict__ Wc, const int* __restrict__ nidx,
    const float* __restrict__ bnsc_g, const float* __restrict__ bnsh_g,
    float* __restrict__ Y, float* __restrict__ colsum, float* __restrict__ colsq)
{
    __shared__ float Wlds[KOFF * 4 * 128];  // 55296 B
    __shared__ int   nlds[128 * KOFF];      // 13824 B (aliased as 16x128 reduction buffer later)
    __shared__ float bnp[256];
    float* red = (float*)nlds;

    const int t = threadIdx.x;
    const int g = t & 31, ps = t >> 5;      // ps 0..15
    const int bid = xcd_swz((int)blockIdx.x, (int)gridDim.x);
    const int n0 = bid * 128;

    for (int f = t; f < KOFF * 512; f += 512) {
        int k = f >> 9, rem = f & 511;
        int gg = rem >> 4, ii = (rem >> 2) & 3, oo = rem & 3;
        Wlds[(k * 4 + ii) * 128 + gg * 4 + oo] = Wc[f];
    }
    for (int f = t; f < 128 * KOFF; f += 512) {
        int p = f / KOFF, k = f - p * KOFF;
        int n = n0 + p;
        nlds[f] = (n < NPTS) ? nidx[(size_t)n * KOFF + k] : -1;
    }
    if (INBN && t < 128) { bnp[t] = bnsc_g[t]; bnp[128 + t] = bnsh_g[t]; }
    __syncthreads();

    float4 bs4 = make_float4(1.f, 1.f, 1.f, 1.f), bh4 = make_float4(0.f, 0.f, 0.f, 0.f);
    if (INBN) { bs4 = *(float4*)&bnp[g * 4]; bh4 = *(float4*)&bnp[128 + g * 4]; }

    float acc[8][4];
#pragma unroll
    for (int j = 0; j < 8; ++j)
#pragma unroll
        for (int o = 0; o < 4; ++o) acc[j][o] = 0.f;

    for (int k = 0; k < KOFF; ++k) {
        const float4 w0 = *(const float4*)&Wlds[(k * 4 + 0) * 128 + g * 4];
        const float4 w1 = *(const float4*)&Wlds[(k * 4 + 1) * 128 + g * 4];
        const float4 w2 = *(const float4*)&Wlds[(k * 4 + 2) * 128 + g * 4];
        const float4 w3 = *(const float4*)&Wlds[(k * 4 + 3) * 128 + g * 4];
#pragma unroll
        for (int j = 0; j < 8; ++j) {
            int p = ps * 8 + j;
            int idx = nlds[p * KOFF + k];
            if (idx >= 0) {
                float4 v = *(const float4*)(X + (size_t)idx * CH + g * 4);
                if (INBN) {
                    v.x = v.x * bs4.x + bh4.x; v.y = v.y * bs4.y + bh4.y;
                    v.z = v.z * bs4.z + bh4.z; v.w = v.w * bs4.w + bh4.w;
                }
                acc[j][0] += v.x * w0.x + v.y * w1.x + v.z * w2.x + v.w * w3.x;
                acc[j][1] += v.x * w0.y + v.y * w1.y + v.z * w2.y + v.w * w3.y;
                acc[j][2] += v.x * w0.z + v.y * w1.z + v.z * w2.z + v.w * w3.z;
                acc[j][3] += v.x * w0.w + v.y * w1.w + v.z * w2.w + v.w * w3.w;
            }
        }
    }

    float s[4] = {0.f, 0.f, 0.f, 0.f}, q[4] = {0.f, 0.f, 0.f, 0.f};
#pragma unroll
    for (int j = 0; j < 8; ++j) {
        int n = n0 + ps * 8 + j;
        if (n < NPTS) {
            float4 o4 = make_float4(acc[j][0], acc[j][1], acc[j][2], acc[j][3]);
            *(float4*)(Y + (size_t)n * CH + g * 4) = o4;
            s[0] += o4.x; s[1] += o4.y; s[2] += o4.z; s[3] += o4.w;
            q[0] += o4.x * o4.x; q[1] += o4.y * o4.y;
            q[2] += o4.z * o4.z; q[3] += o4.w * o4.w;
        }
    }
    __syncthreads();  // done with nlds; alias as red[16][128]
    *(float4*)&red[ps * 128 + g * 4] = make_float4(s[0], s[1], s[2], s[3]);
    __syncthreads();
    if (t < 128) {
        float tot = 0.f;
#pragma unroll
        for (int r = 0; r < 16; ++r) tot += red[r * 128 + t];
        atomicAdd(colsum + t, tot);
    }
    __syncthreads();
    *(float4*)&red[ps * 128 + g * 4] = make_float4(q[0], q[1], q[2], q[3]);
    __syncthreads();
    if (t < 128) {
        float tot = 0.f;
#pragma unroll
        for (int r = 0; r < 16; ++r) tot += red[r * 128 + t];
        atomicAdd(colsq + t, tot);
    }
}

// out = relu(bn2(conv2out) + fused)  (safe in-place elementwise)
__global__ void final_kernel(const float* __restrict__ c2, const float* __restrict__ sc, const float* __restrict__ sh,
                             const float* __restrict__ fused, float* __restrict__ out)
{
    const int tot = NPTS * 32;
    for (int f = blockIdx.x * 256 + threadIdx.x; f < tot; f += gridDim.x * 256) {
        int n = f >> 5, c4 = (f & 31) << 2;
        float4 y  = *(const float4*)(c2 + (size_t)n * CH + c4);
        float4 s4 = *(const float4*)(sc + c4);
        float4 h4 = *(const float4*)(sh + c4);
        float4 r  = *(const float4*)(fused + (size_t)n * CH + c4);
        float4 o;
        o.x = fmaxf(y.x * s4.x + h4.x + r.x, 0.f);
        o.y = fmaxf(y.y * s4.y + h4.y + r.y, 0.f);
        o.z = fmaxf(y.z * s4.z + h4.z + r.z, 0.f);
        o.w = fmaxf(y.w * s4.w + h4.w + r.w, 0.f);
        *(float4*)(out + (size_t)n * CH + c4) = o;
    }
}

// ---------- host ----------
extern "C" void kernel_launch(void* const* d_in, const int* in_sizes, int n_in,
                              void* d_out, int out_size, void* d_ws, size_t ws_size,
                              hipStream_t stream) {
    (void)in_sizes; (void)n_in; (void)out_size;
    const float* feat    = (const float*)d_in[0];
    const float* lw_W    = (const float*)d_in[1];
    const float* lw_g    = (const float*)d_in[2];
    const float* lw_b    = (const float*)d_in[3];
    const float* w_W     = (const float*)d_in[4];
    const float* proj_W  = (const float*)d_in[5];
    const float* proj_g  = (const float*)d_in[6];
    const float* proj_b  = (const float*)d_in[7];
    const float* adp_W   = (const float*)d_in[8];
    const float* fuse_W  = (const float*)d_in[9];
    const float* fuse_g  = (const float*)d_in[10];
    const float* fuse_b  = (const float*)d_in[11];
    const float* conv1_W = (const float*)d_in[12];
    const float* norm1_g = (const float*)d_in[13];
    const float* norm1_b = (const float*)d_in[14];
    const float* conv2_W = (const float*)d_in[15];
    const float* norm2_g = (const float*)d_in[16];
    const float* norm2_b = (const float*)d_in[17];
    const int*   clusters= (const int*)d_in[18];
    const int*   nidx    = (const int*)d_in[19];
    float* out = (float*)d_out;

    const size_t NC  = (size_t)NPTS * CH;
    const size_t SEG = (size_t)NSEG_ * CH;

    // Layout: W0,W1 | [ZERO: cnt,fpos,stats,qmax] | off,invc,perm,scsh,S1,S2,s3 | Wt16
    const size_t zwords = 6 * NSEG_ + 10 * 256 + 4;
    const size_t needed = (2 * NC + zwords + 6 * NSEG_ + 3 * (size_t)NPTS
                           + 10 * 256 + 5 * SEG + 98304) * sizeof(float);  // ~167 MB
    if (ws_size < needed) return;

    float* ws = (float*)d_ws;
    float* W0 = ws;
    float* W1 = ws + NC;
    float* Z  = ws + 2 * NC;
    int*   cnt   = (int*)Z;
    int*   fpos  = cnt + 3 * NSEG_;
    float* stats = (float*)(fpos + 3 * NSEG_);
    unsigned int* qmax = (unsigned int*)(stats + 10 * 256);
    int*   off   = (int*)(qmax + 4);
    float* invc  = (float*)(off + 3 * NSEG_);
    int*   perm  = (int*)(invc + 3 * NSEG_);
    float* scsh  = (float*)(perm + 3 * (size_t)NPTS);
    float* S1    = scsh + 10 * 256;
    float* S2    = S1 + SEG;
    float* s3    = S2 + SEG;
    unsigned short* Wt16 = (unsigned short*)(s3 + 3 * SEG);  // 196608 ushort
    unsigned short* lwT   = Wt16;
    unsigned short* wT    = Wt16 + 3 * 16384;
    unsigned short* projT = Wt16 + 6 * 16384;
    unsigned short* fuseT = Wt16 + 10 * 16384;               // [128][256]

    const int gemmGrid = (NPTS + 127) / 128;   // 1172
    const int convGrid = (NPTS + 127) / 128;   // 1172 (128 pts/block)
    const int aggGrid  = (NPTS + 63) / 64;
    const int mapGrid  = 2048;

    zero_kernel<<<64, 256, 0, stream>>>((float4*)Z, (int)(zwords / 4));
    count_kernel<<<512, 256, 0, stream>>>(clusters, cnt);
    invcnt_kernel<<<(3 * NSEG_ + 255) / 256, 256, 0, stream>>>(cnt, invc);
    scan_kernel<<<3, 1024, 0, stream>>>(cnt, off);
    fill_kernel<<<512, 256, 0, stream>>>(clusters, off, fpos, perm);

    // weight transpose+cvt (K=128 -> 64 blocks; K=256 -> 128 blocks)
    for (int i = 0; i < 3; ++i) {
        wtr_kernel<<<64, 256, 0, stream>>>(lw_W + (size_t)i * 16384, lwT + (size_t)i * 16384, 128);
        wtr_kernel<<<64, 256, 0, stream>>>(w_W + (size_t)i * 16384, wT + (size_t)i * 16384, 128);
    }
    for (int i = 0; i < 4; ++i)
        wtr_kernel<<<64, 256, 0, stream>>>(proj_W + (size_t)i * 16384, projT + (size_t)i * 16384, 128);
    wtr_kernel<<<128, 256, 0, stream>>>(fuse_W, fuseT, 256);

    for (int i = 0; i < 3; ++i) {
        const int* cli   = clusters + (size_t)i * NPTS;
        const int* permi = perm + (size_t)i * NPTS;
        const int* offi  = off + i * NSEG_;
        const int* cnti  = cnt + i * NSEG_;
        float* st  = stats + i * 256;
        float* ss  = scsh + i * 256;
        float* stp = stats + (3 + i) * 256;
        float* ssp = scsh + (3 + i) * 256;
        // L = feat @ lw_W[i] -> W0, stats
        gemm_mfma<8><<<gemmGrid, 256, 0, stream>>>(feat, nullptr, lwT + (size_t)i * 16384, W0,
            nullptr, nullptr, nullptr, nullptr, nullptr, st, st + 128, nullptr);
        finalize_kernel<<<1, 128, 0, stream>>>(st, st + 128, lw_g + i * CH, lw_b + i * CH, ss, ss + 128);
        // s1 = seg_sum(relu(bn(L)))
        gather_seg<0><<<NSEG_, 256, 0, stream>>>(W0, nullptr, ss, ss + 128, nullptr, nullptr,
            permi, offi, cnti, S1);
        // q = (relu(bn(L)) - mean[cl]) @ w_W[i] -> OUT, global max   (ABN|ACEN|MAXRED)
        gemm_mfma<19><<<gemmGrid, 256, 0, stream>>>(W0, nullptr, wT + (size_t)i * 16384, out,
            cli, S1, invc + i * NSEG_, ss, ss + 128, nullptr, nullptr, qmax + i);
        // P = feat @ proj_W[i] -> W1, stats
        gemm_mfma<8><<<gemmGrid, 256, 0, stream>>>(feat, nullptr, projT + (size_t)i * 16384, W1,
            nullptr, nullptr, nullptr, nullptr, nullptr, stp, stp + 128, nullptr);
        finalize_kernel<<<1, 128, 0, stream>>>(stp, stp + 128, proj_g + i * CH, proj_b + i * CH, ssp, ssp + 128);
        // s2 = seg_sum(exp(q-max))   (exp fused into gather)
        gather_seg<1><<<NSEG_, 256, 0, stream>>>(nullptr, out, nullptr, nullptr, nullptr, qmax + i,
            permi, offi, cnti, S2);
        // s3 = seg_sum(relu(bn(P)) * exp(q-max)/(s2+eps))
        gather_seg<2><<<NSEG_, 256, 0, stream>>>(W1, out, ssp, ssp + 128, S2, qmax + i,
            permi, offi, cnti, s3 + (size_t)i * SEG);
    }

    // agg -> W0
    adpagg_kernel<<<aggGrid, 256, 0, stream>>>(feat, adp_W,
        clusters, clusters + NPTS, clusters + 2 * (size_t)NPTS,
        s3, s3 + SEG, s3 + 2 * SEG, W0);

    // P3 -> W1, stats
    {
        float* st = stats + 6 * 256; float* ss = scsh + 6 * 256;
        gemm_mfma<8><<<gemmGrid, 256, 0, stream>>>(feat, nullptr, projT + 3 * (size_t)16384, W1,
            nullptr, nullptr, nullptr, nullptr, nullptr, st, st + 128, nullptr);
        finalize_kernel<<<1, 128, 0, stream>>>(st, st + 128, proj_g + 3 * CH, proj_b + 3 * CH, ss, ss + 128);
    }
    // fuseY = [relu(bn(P3)), agg] @ fuse_W -> OUT, stats  (K256 | ABN | STATS)
    {
        float* st = stats + 7 * 256; float* ss7 = scsh + 7 * 256;
        gemm_mfma<42><<<gemmGrid, 256, 0, stream>>>(W1, W0, fuseT, out,
            nullptr, nullptr, nullptr, scsh + 6 * 256, scsh + 6 * 256 + 128, st, st + 128, nullptr);
        finalize_kernel<<<1, 128, 0, stream>>>(st, st + 128, fuse_g, fuse_b, ss7, ss7 + 128);
    }
    // fused = relu(bn(fuseY)) + feat -> W0 (residual)
    fused_kernel<<<mapGrid, 256, 0, stream>>>(out, scsh + 7 * 256, scsh + 7 * 256 + 128, feat, W0);

    // conv1: W0 -> W1 (+stats)
    {
        float* st = stats + 8 * 256; float* ss = scsh + 8 * 256;
        conv_kernel<false><<<convGrid, 512, 0, stream>>>(W0, conv1_W, nidx, nullptr, nullptr,
            W1, st, st + 128);
        finalize_kernel<<<1, 128, 0, stream>>>(st, st + 128, norm1_g, norm1_b, ss, ss + 128);
    }
    // conv2: bn1(W1) -> OUT (+stats)
    {
        float* st = stats + 9 * 256; float* ss = scsh + 9 * 256;
        conv_kernel<true><<<convGrid, 512, 0, stream>>>(W1, conv2_W, nidx,
            scsh + 8 * 256, scsh + 8 * 256 + 128, out, st, st + 128);
        finalize_kernel<<<1, 128, 0, stream>>>(st, st + 128, norm2_g, norm2_b, ss, ss + 128);
    }
    // out = relu(bn2(OUT) + W0)
    final_kernel<<<mapGrid, 256, 0, stream>>>(out, scsh + 9 * 256, scsh + 9 * 256 + 128, W0, out);
}

// Round 5
// 1373.356 us; speedup vs baseline: 2.8247x; 1.2205x over previous
//
#include <hip/hip_runtime.h>
#include <math.h>

#define NPTS 150000
#define CH   128
#define NSEG_ 4096
#define KOFF 27
#define BN_EPS 1e-5f

typedef __attribute__((ext_vector_type(8))) short bf16x8;
typedef __attribute__((ext_vector_type(4))) float f32x4;

// ---------- helpers ----------
__device__ __forceinline__ unsigned int fenc(float f) {
    unsigned int b = __float_as_uint(f);
    return (b & 0x80000000u) ? ~b : (b | 0x80000000u);
}
__device__ __forceinline__ float fdec(unsigned int u) {
    return __uint_as_float((u & 0x80000000u) ? (u & 0x7fffffffu) : ~u);
}
__device__ __forceinline__ unsigned short f2bf(float f) {
    unsigned int u = __float_as_uint(f);
    unsigned int r = (u + 0x7fffu + ((u >> 16) & 1u)) >> 16;
    return (unsigned short)r;
}
__device__ __forceinline__ float bf2f(unsigned short h) {
    return __uint_as_float(((unsigned int)h) << 16);
}
__device__ __forceinline__ float blo(unsigned int u) { return __uint_as_float(u << 16); }
__device__ __forceinline__ float bhi(unsigned int u) { return __uint_as_float(u & 0xffff0000u); }
__device__ __forceinline__ unsigned int pk2(float a, float b) {
    return (unsigned int)f2bf(a) | ((unsigned int)f2bf(b) << 16);
}
__device__ __forceinline__ int xcd_swz(int bid, int nwg) {
    int q = nwg >> 3, r = nwg & 7;
    int xcd = bid & 7, idx = bid >> 3;
    return (xcd < r ? xcd * (q + 1) : r * (q + 1) + (xcd - r) * q) + idx;
}

__global__ void zero_kernel(float4* __restrict__ p, int n4) {
    for (int i = blockIdx.x * 256 + threadIdx.x; i < n4; i += gridDim.x * 256)
        p[i] = make_float4(0.f, 0.f, 0.f, 0.f);
}

// fp32 -> bf16 cvt, 8 elems/thread
__global__ void cvt_bf16(const float* __restrict__ in, unsigned short* __restrict__ o, int n8) {
    for (int i = blockIdx.x * 256 + threadIdx.x; i < n8; i += gridDim.x * 256) {
        float4 a = *(const float4*)(in + (size_t)i * 8);
        float4 b = *(const float4*)(in + (size_t)i * 8 + 4);
        uint4 w;
        w.x = pk2(a.x, a.y); w.y = pk2(a.z, a.w);
        w.z = pk2(b.x, b.y); w.w = pk2(b.z, b.w);
        *(uint4*)(o + (size_t)i * 8) = w;
    }
}

// W[K][128] fp32 -> Wt[128][K] bf16
__global__ void wtr_kernel(const float* __restrict__ W, unsigned short* __restrict__ Wt, int K) {
    int i = blockIdx.x * 256 + threadIdx.x;
    if (i < 128 * K) {
        int n = i / K, k = i - n * K;
        Wt[i] = f2bf(W[(size_t)k * 128 + n]);
    }
}

// ---------- MFMA GEMM: C[N,128] = f(A)[N,K] @ W[K,128]; A bf16, Wt [128][K] bf16 ----------
// FLAGS: 1=ACEN, 2=ABN, 8=STATS, 16=MAXRED, 32=K256 (A1 plain bf16 k=128..255), 64=CBF (bf16 C)
template<int FLAGS>
__global__ __launch_bounds__(256) void gemm_mfma(
    const unsigned short* __restrict__ A0, const unsigned short* __restrict__ A1,
    const unsigned short* __restrict__ Wt, void* __restrict__ Cv,
    const int* __restrict__ cl, const float* __restrict__ seg,
    const float* __restrict__ invcnt,
    const float* __restrict__ bnsc, const float* __restrict__ bnsh,
    float* __restrict__ colsum, float* __restrict__ colsq,
    unsigned int* __restrict__ gmax)
{
    constexpr bool ACEN   = (FLAGS & 1)  != 0;
    constexpr bool ABN    = (FLAGS & 2)  != 0;
    constexpr bool STATS  = (FLAGS & 8)  != 0;
    constexpr bool MAXRED = (FLAGS & 16) != 0;
    constexpr bool K256   = (FLAGS & 32) != 0;
    constexpr bool CBF    = (FLAGS & 64) != 0;
    constexpr int  KS = K256 ? 8 : 4;
    constexpr int  KW = KS * 32;

    const int t  = threadIdx.x;
    const int l  = t & 63, w = t >> 6;
    const int lc = l & 15, lk = l >> 4;
    const int wr = w >> 1, wc = w & 1;
    const int R  = blockIdx.x * 128 + wr * 64;
    const int C0 = wc * 64;

    f32x4 acc[4][4];
#pragma unroll
    for (int mi = 0; mi < 4; ++mi)
#pragma unroll
        for (int ni = 0; ni < 4; ++ni) acc[mi][ni] = (f32x4){0.f, 0.f, 0.f, 0.f};

#pragma unroll
    for (int ks = 0; ks < KS; ++ks) {
        const unsigned short* Asrc = A0;
        int ka = ks * 32;
        bool xf = true;
        if constexpr (K256) { if (ks >= 4) { Asrc = A1; ka -= 128; xf = false; } }
        const int kb = ka + lk * 8;

        bf16x8 b[4];
#pragma unroll
        for (int ni = 0; ni < 4; ++ni)
            b[ni] = *(const bf16x8*)(Wt + (size_t)(C0 + ni * 16 + lc) * KW + ks * 32 + lk * 8);

        float4 s0, s1v, h0, h1;
        if constexpr (ABN) {
            if (xf) {
                s0  = *(const float4*)(bnsc + kb); s1v = *(const float4*)(bnsc + kb + 4);
                h0  = *(const float4*)(bnsh + kb); h1  = *(const float4*)(bnsh + kb + 4);
            }
        }

        bf16x8 a[4];
#pragma unroll
        for (int mi = 0; mi < 4; ++mi) {
            int row = R + mi * 16 + lc;
            if (row > NPTS - 1) row = NPTS - 1;
            union { unsigned short u[8]; bf16x8 v; } pk;
            pk.v = *(const bf16x8*)(Asrc + (size_t)row * CH + kb);
            if ((ABN || ACEN) && xf) {
                float v[8];
#pragma unroll
                for (int e = 0; e < 8; ++e) v[e] = bf2f(pk.u[e]);
                if constexpr (ABN) {
                    v[0] = fmaxf(v[0] * s0.x + h0.x, 0.f);  v[1] = fmaxf(v[1] * s0.y + h0.y, 0.f);
                    v[2] = fmaxf(v[2] * s0.z + h0.z, 0.f);  v[3] = fmaxf(v[3] * s0.w + h0.w, 0.f);
                    v[4] = fmaxf(v[4] * s1v.x + h1.x, 0.f); v[5] = fmaxf(v[5] * s1v.y + h1.y, 0.f);
                    v[6] = fmaxf(v[6] * s1v.z + h1.z, 0.f); v[7] = fmaxf(v[7] * s1v.w + h1.w, 0.f);
                }
                if constexpr (ACEN) {
                    int sg = cl[row];
                    float ic = invcnt[sg];
                    const float* sp = seg + (size_t)sg * CH + kb;
                    float4 m0 = *(const float4*)sp, m1 = *(const float4*)(sp + 4);
                    v[0] -= m0.x * ic; v[1] -= m0.y * ic; v[2] -= m0.z * ic; v[3] -= m0.w * ic;
                    v[4] -= m1.x * ic; v[5] -= m1.y * ic; v[6] -= m1.z * ic; v[7] -= m1.w * ic;
                }
#pragma unroll
                for (int e = 0; e < 8; ++e) pk.u[e] = f2bf(v[e]);
            }
            a[mi] = pk.v;
        }
#pragma unroll
        for (int mi = 0; mi < 4; ++mi)
#pragma unroll
            for (int ni = 0; ni < 4; ++ni)
                acc[mi][ni] = __builtin_amdgcn_mfma_f32_16x16x32_bf16(a[mi], b[ni], acc[mi][ni], 0, 0, 0);
    }

    float* Cf = (float*)Cv;
    unsigned short* Chh = (unsigned short*)Cv;
    float s[4] = {0.f, 0.f, 0.f, 0.f}, q[4] = {0.f, 0.f, 0.f, 0.f};
    unsigned int lmax = 0u;
#pragma unroll
    for (int mi = 0; mi < 4; ++mi) {
#pragma unroll
        for (int r = 0; r < 4; ++r) {
            int row = R + mi * 16 + lk * 4 + r;
            if (row < NPTS) {
#pragma unroll
                for (int ni = 0; ni < 4; ++ni) {
                    float v = acc[mi][ni][r];
                    int col = C0 + ni * 16 + lc;
                    if constexpr (CBF) Chh[(size_t)row * CH + col] = f2bf(v);
                    else               Cf[(size_t)row * CH + col] = v;
                    if constexpr (STATS) { s[ni] += v; q[ni] += v * v; }
                    if constexpr (MAXRED) { unsigned int e = fenc(v); if (e > lmax) lmax = e; }
                }
            }
        }
    }

    if constexpr (STATS) {
        __shared__ float reds[4][4][16], redq[4][4][16];
#pragma unroll
        for (int ni = 0; ni < 4; ++ni) {
            s[ni] += __shfl_xor(s[ni], 16); s[ni] += __shfl_xor(s[ni], 32);
            q[ni] += __shfl_xor(q[ni], 16); q[ni] += __shfl_xor(q[ni], 32);
        }
        if (lk == 0) {
#pragma unroll
            for (int ni = 0; ni < 4; ++ni) { reds[w][ni][lc] = s[ni]; redq[w][ni][lc] = q[ni]; }
        }
        __syncthreads();
        if (t < 128) {
            int half = t >> 6, fr = (t >> 4) & 3, cc = t & 15;
            atomicAdd(colsum + t, reds[half][fr][cc] + reds[half + 2][fr][cc]);
            atomicAdd(colsq  + t, redq[half][fr][cc] + redq[half + 2][fr][cc]);
        }
    }
    if constexpr (MAXRED) {
        __shared__ unsigned int smax;
#pragma unroll
        for (int d = 1; d < 64; d <<= 1) {
            unsigned int o = __shfl_xor(lmax, d);
            if (o > lmax) lmax = o;
        }
        if (t == 0) smax = 0u;
        __syncthreads();
        if (l == 0) atomicMax(&smax, lmax);
        __syncthreads();
        if (t == 0) atomicMax(gmax, smax);
    }
}

// ---------- CSR build ----------
__global__ void count_kernel(const int* __restrict__ clusters, int* __restrict__ cnt) {
    const int tot = 3 * NPTS;
    for (int f = blockIdx.x * 256 + threadIdx.x; f < tot; f += gridDim.x * 256) {
        int i = f / NPTS;
        atomicAdd(cnt + i * NSEG_ + clusters[f], 1);
    }
}

__global__ void invcnt_kernel(const int* __restrict__ cnt, float* __restrict__ invc) {
    int x = blockIdx.x * 256 + threadIdx.x;
    if (x < 3 * NSEG_) {
        int c = cnt[x];
        invc[x] = 1.0f / (float)(c > 1 ? c : 1);
    }
}

__global__ __launch_bounds__(1024) void scan_kernel(const int* __restrict__ cnt, int* __restrict__ off) {
    __shared__ int tot[1024];
    const int L = blockIdx.x;
    const int* c = cnt + L * NSEG_;
    int* o = off + L * NSEG_;
    const int t = threadIdx.x;
    int v[4];
    int s = 0;
#pragma unroll
    for (int j = 0; j < 4; ++j) { v[j] = s; s += c[t * 4 + j]; }
    tot[t] = s;
    __syncthreads();
    for (int d = 1; d < 1024; d <<= 1) {
        int x = (t >= d) ? tot[t - d] : 0;
        __syncthreads();
        tot[t] += x;
        __syncthreads();
    }
    int pre = (t == 0) ? 0 : tot[t - 1];
#pragma unroll
    for (int j = 0; j < 4; ++j) o[t * 4 + j] = pre + v[j];
}

__global__ void fill_kernel(const int* __restrict__ clusters, const int* __restrict__ off,
                            int* __restrict__ fpos, int* __restrict__ perm) {
    const int tot = 3 * NPTS;
    for (int f = blockIdx.x * 256 + threadIdx.x; f < tot; f += gridDim.x * 256) {
        int i = f / NPTS;
        int n = f - i * NPTS;
        int s = i * NSEG_ + clusters[f];
        int pos = off[s] + atomicAdd(fpos + s, 1);
        perm[(size_t)i * NPTS + pos] = n;
    }
}

// ---------- CSR gather segment-sum (A bf16, Q fp32) ----------
template<int MODE>
__global__ __launch_bounds__(256) void gather_seg(
    const unsigned short* __restrict__ A, const float* __restrict__ Q,
    const float* __restrict__ sc, const float* __restrict__ sh,
    const float* __restrict__ s2, const unsigned int* __restrict__ gmax,
    const int* __restrict__ perm, const int* __restrict__ off,
    const int* __restrict__ cnt, float* __restrict__ segout)
{
    __shared__ float red[256];
    const int s = blockIdx.x;
    const int t = threadIdx.x;
    const int c = t & 127, h = t >> 7;
    const int start = off[s], m = cnt[s];
    float mx = 0.f, scv = 0.f, shv = 0.f, dinv = 0.f;
    if constexpr (MODE >= 1) mx = fdec(*gmax);
    if constexpr (MODE != 1) { scv = sc[c]; shv = sh[c]; }
    if constexpr (MODE == 2) dinv = 1.0f / (s2[(size_t)s * CH + c] + 1e-6f);
    float acc = 0.f;
    for (int j = h; j < m; j += 2) {
        int p = perm[start + j];
        if constexpr (MODE == 0) {
            acc += fmaxf(bf2f(A[(size_t)p * CH + c]) * scv + shv, 0.f);
        } else if constexpr (MODE == 1) {
            acc += expf(Q[(size_t)p * CH + c] - mx);
        } else {
            acc += fmaxf(bf2f(A[(size_t)p * CH + c]) * scv + shv, 0.f)
                 * expf(Q[(size_t)p * CH + c] - mx) * dinv;
        }
    }
    red[t] = acc;
    __syncthreads();
    if (h == 0) segout[(size_t)s * CH + c] = red[c] + red[c + 128];
}

// ---------- small kernels ----------
__global__ void finalize_kernel(const float* __restrict__ colsum, const float* __restrict__ colsq,
                                const float* __restrict__ g, const float* __restrict__ b,
                                float* __restrict__ sc, float* __restrict__ sh)
{
    int c = threadIdx.x;
    float mean = colsum[c] / (float)NPTS;
    float var  = colsq[c] / (float)NPTS - mean * mean;
    float istd = rsqrtf(var + BN_EPS);
    float s = istd * g[c];
    sc[c] = s;
    sh[c] = b[c] - mean * s;
}

// adp softmax + agg;  featB bf16, s3 fp32, agg out bf16
__global__ __launch_bounds__(256) void adpagg_kernel(
    const unsigned short* __restrict__ featB, const float* __restrict__ adpW,
    const int* __restrict__ cl0, const int* __restrict__ cl1, const int* __restrict__ cl2,
    const float* __restrict__ s30, const float* __restrict__ s31, const float* __restrict__ s32,
    unsigned short* __restrict__ agg)
{
    __shared__ float ftile[64][132];
    __shared__ float wl[128][3];
    __shared__ float pr[64][3];
    __shared__ int   cls[64][3];
    const int t = threadIdx.x;
    const int n0 = blockIdx.x * 64;

    if (t < 128) { wl[t][0] = adpW[t * 3]; wl[t][1] = adpW[t * 3 + 1]; wl[t][2] = adpW[t * 3 + 2]; }
#pragma unroll
    for (int h = 0; h < 4; ++h) {
        int f = t + h * 256;                 // 1024 chunks of 8
        int r = f >> 4, c8 = (f & 15) * 8;
        int n = n0 + r;
        if (n < NPTS) {
            uint4 rw = *(const uint4*)(featB + (size_t)n * CH + c8);
            ftile[r][c8 + 0] = blo(rw.x); ftile[r][c8 + 1] = bhi(rw.x);
            ftile[r][c8 + 2] = blo(rw.y); ftile[r][c8 + 3] = bhi(rw.y);
            ftile[r][c8 + 4] = blo(rw.z); ftile[r][c8 + 5] = bhi(rw.z);
            ftile[r][c8 + 6] = blo(rw.w); ftile[r][c8 + 7] = bhi(rw.w);
        } else {
#pragma unroll
            for (int e = 0; e < 8; ++e) ftile[r][c8 + e] = 0.f;
        }
    }
    if (t < 64) {
        int n = n0 + t;
        if (n < NPTS) { cls[t][0] = cl0[n]; cls[t][1] = cl1[n]; cls[t][2] = cl2[n]; }
        else { cls[t][0] = 0; cls[t][1] = 0; cls[t][2] = 0; }
    }
    __syncthreads();

    if (t < 64) {
        float p0 = 0.f, p1 = 0.f, p2 = 0.f;
        for (int k = 0; k < 128; ++k) {
            float fv = ftile[t][k];
            p0 += fv * wl[k][0]; p1 += fv * wl[k][1]; p2 += fv * wl[k][2];
        }
        float m = fmaxf(p0, fmaxf(p1, p2));
        float e0 = expf(p0 - m), e1 = expf(p1 - m), e2 = expf(p2 - m);
        float inv = 1.f / (e0 + e1 + e2);
        pr[t][0] = e0 * inv; pr[t][1] = e1 * inv; pr[t][2] = e2 * inv;
    }
    __syncthreads();

#pragma unroll
    for (int h = 0; h < 8; ++h) {
        int f = t + h * 256;
        int r = f >> 5, c4 = (f & 31) << 2;
        int n = n0 + r;
        if (n < NPTS) {
            float a0 = pr[r][0], a1 = pr[r][1], a2 = pr[r][2];
            float4 v0 = *(const float4*)(s30 + (size_t)cls[r][0] * CH + c4);
            float4 v1 = *(const float4*)(s31 + (size_t)cls[r][1] * CH + c4);
            float4 v2 = *(const float4*)(s32 + (size_t)cls[r][2] * CH + c4);
            float ox = a0 * v0.x + a1 * v1.x + a2 * v2.x;
            float oy = a0 * v0.y + a1 * v1.y + a2 * v2.y;
            float oz = a0 * v0.z + a1 * v1.z + a2 * v2.z;
            float ow = a0 * v0.w + a1 * v1.w + a2 * v2.w;
            uint2 wv; wv.x = pk2(ox, oy); wv.y = pk2(oz, ow);
            *(uint2*)(agg + (size_t)n * CH + c4) = wv;
        }
    }
}

// fused = relu(bn(fuseY)) + feat;  fY bf16, feat fp32, out bf16
__global__ void fused_kernel(const unsigned short* __restrict__ fY,
                             const float* __restrict__ sc, const float* __restrict__ sh,
                             const float* __restrict__ feat, unsigned short* __restrict__ outB)
{
    const int tot = NPTS * 32;
    for (int f = blockIdx.x * 256 + threadIdx.x; f < tot; f += gridDim.x * 256) {
        int n = f >> 5, c4 = (f & 31) << 2;
        uint2 y2 = *(const uint2*)(fY + (size_t)n * CH + c4);
        float y0 = blo(y2.x), y1 = bhi(y2.x), yz = blo(y2.y), y3 = bhi(y2.y);
        float4 s4 = *(const float4*)(sc + c4);
        float4 h4 = *(const float4*)(sh + c4);
        float4 ft = *(const float4*)(feat + (size_t)n * CH + c4);
        float o0 = fmaxf(y0 * s4.x + h4.x, 0.f) + ft.x;
        float o1 = fmaxf(y1 * s4.y + h4.y, 0.f) + ft.y;
        float o2 = fmaxf(yz * s4.z + h4.z, 0.f) + ft.z;
        float o3 = fmaxf(y3 * s4.w + h4.w, 0.f) + ft.w;
        uint2 wv; wv.x = pk2(o0, o1); wv.y = pk2(o2, o3);
        *(uint2*)(outB + (size_t)n * CH + c4) = wv;
    }
}

// grouped submanifold conv: X bf16 -> Y bf16, stats fp32
template<bool INBN>
__global__ __launch_bounds__(512) void conv_kernel(
    const unsigned short* __restrict__ X, const float* __restrict__ Wc, const int* __restrict__ nidx,
    const float* __restrict__ bnsc_g, const float* __restrict__ bnsh_g,
    unsigned short* __restrict__ Y, float* __restrict__ colsum, float* __restrict__ colsq)
{
    __shared__ float Wlds[KOFF * 4 * 128];
    __shared__ int   nlds[128 * KOFF];
    __shared__ float bnp[256];
    float* red = (float*)nlds;

    const int t = threadIdx.x;
    const int g = t & 31, ps = t >> 5;
    const int bid = xcd_swz((int)blockIdx.x, (int)gridDim.x);
    const int n0 = bid * 128;

    for (int f = t; f < KOFF * 512; f += 512) {
        int k = f >> 9, rem = f & 511;
        int gg = rem >> 4, ii = (rem >> 2) & 3, oo = rem & 3;
        Wlds[(k * 4 + ii) * 128 + gg * 4 + oo] = Wc[f];
    }
    for (int f = t; f < 128 * KOFF; f += 512) {
        int p = f / KOFF, k = f - p * KOFF;
        int n = n0 + p;
        nlds[f] = (n < NPTS) ? nidx[(size_t)n * KOFF + k] : -1;
    }
    if (INBN && t < 128) { bnp[t] = bnsc_g[t]; bnp[128 + t] = bnsh_g[t]; }
    __syncthreads();

    float4 bs4 = make_float4(1.f, 1.f, 1.f, 1.f), bh4 = make_float4(0.f, 0.f, 0.f, 0.f);
    if (INBN) { bs4 = *(float4*)&bnp[g * 4]; bh4 = *(float4*)&bnp[128 + g * 4]; }

    float acc[8][4];
#pragma unroll
    for (int j = 0; j < 8; ++j)
#pragma unroll
        for (int o = 0; o < 4; ++o) acc[j][o] = 0.f;

    for (int k = 0; k < KOFF; ++k) {
        const float4 w0 = *(const float4*)&Wlds[(k * 4 + 0) * 128 + g * 4];
        const float4 w1 = *(const float4*)&Wlds[(k * 4 + 1) * 128 + g * 4];
        const float4 w2 = *(const float4*)&Wlds[(k * 4 + 2) * 128 + g * 4];
        const float4 w3 = *(const float4*)&Wlds[(k * 4 + 3) * 128 + g * 4];
#pragma unroll
        for (int j = 0; j < 8; ++j) {
            int p = ps * 8 + j;
            int idx = nlds[p * KOFF + k];
            if (idx >= 0) {
                uint2 rw = *(const uint2*)(X + (size_t)idx * CH + g * 4);
                float vx = blo(rw.x), vy = bhi(rw.x), vz = blo(rw.y), vw = bhi(rw.y);
                if (INBN) {
                    vx = vx * bs4.x + bh4.x; vy = vy * bs4.y + bh4.y;
                    vz = vz * bs4.z + bh4.z; vw = vw * bs4.w + bh4.w;
                }
                acc[j][0] += vx * w0.x + vy * w1.x + vz * w2.x + vw * w3.x;
                acc[j][1] += vx * w0.y + vy * w1.y + vz * w2.y + vw * w3.y;
                acc[j][2] += vx * w0.z + vy * w1.z + vz * w2.z + vw * w3.z;
                acc[j][3] += vx * w0.w + vy * w1.w + vz * w2.w + vw * w3.w;
            }
        }
    }

    float s[4] = {0.f, 0.f, 0.f, 0.f}, q[4] = {0.f, 0.f, 0.f, 0.f};
#pragma unroll
    for (int j = 0; j < 8; ++j) {
        int n = n0 + ps * 8 + j;
        if (n < NPTS) {
            uint2 wv; wv.x = pk2(acc[j][0], acc[j][1]); wv.y = pk2(acc[j][2], acc[j][3]);
            *(uint2*)(Y + (size_t)n * CH + g * 4) = wv;
            s[0] += acc[j][0]; s[1] += acc[j][1]; s[2] += acc[j][2]; s[3] += acc[j][3];
            q[0] += acc[j][0] * acc[j][0]; q[1] += acc[j][1] * acc[j][1];
            q[2] += acc[j][2] * acc[j][2]; q[3] += acc[j][3] * acc[j][3];
        }
    }
    __syncthreads();
    *(float4*)&red[ps * 128 + g * 4] = make_float4(s[0], s[1], s[2], s[3]);
    __syncthreads();
    if (t < 128) {
        float tot = 0.f;
#pragma unroll
        for (int r = 0; r < 16; ++r) tot += red[r * 128 + t];
        atomicAdd(colsum + t, tot);
    }
    __syncthreads();
    *(float4*)&red[ps * 128 + g * 4] = make_float4(q[0], q[1], q[2], q[3]);
    __syncthreads();
    if (t < 128) {
        float tot = 0.f;
#pragma unroll
        for (int r = 0; r < 16; ++r) tot += red[r * 128 + t];
        atomicAdd(colsq + t, tot);
    }
}

// out = relu(bn2(c2) + fused); c2,fused bf16 -> out fp32
__global__ void final_kernel(const unsigned short* __restrict__ c2,
                             const float* __restrict__ sc, const float* __restrict__ sh,
                             const unsigned short* __restrict__ fused, float* __restrict__ out)
{
    const int tot = NPTS * 32;
    for (int f = blockIdx.x * 256 + threadIdx.x; f < tot; f += gridDim.x * 256) {
        int n = f >> 5, c4 = (f & 31) << 2;
        uint2 y2 = *(const uint2*)(c2 + (size_t)n * CH + c4);
        uint2 r2 = *(const uint2*)(fused + (size_t)n * CH + c4);
        float4 s4 = *(const float4*)(sc + c4);
        float4 h4 = *(const float4*)(sh + c4);
        float4 o;
        o.x = fmaxf(blo(y2.x) * s4.x + h4.x + blo(r2.x), 0.f);
        o.y = fmaxf(bhi(y2.x) * s4.y + h4.y + bhi(r2.x), 0.f);
        o.z = fmaxf(blo(y2.y) * s4.z + h4.z + blo(r2.y), 0.f);
        o.w = fmaxf(bhi(y2.y) * s4.w + h4.w + bhi(r2.y), 0.f);
        *(float4*)(out + (size_t)n * CH + c4) = o;
    }
}

// ---------- host ----------
extern "C" void kernel_launch(void* const* d_in, const int* in_sizes, int n_in,
                              void* d_out, int out_size, void* d_ws, size_t ws_size,
                              hipStream_t stream) {
    (void)in_sizes; (void)n_in; (void)out_size;
    const float* feat    = (const float*)d_in[0];
    const float* lw_W    = (const float*)d_in[1];
    const float* lw_g    = (const float*)d_in[2];
    const float* lw_b    = (const float*)d_in[3];
    const float* w_W     = (const float*)d_in[4];
    const float* proj_W  = (const float*)d_in[5];
    const float* proj_g  = (const float*)d_in[6];
    const float* proj_b  = (const float*)d_in[7];
    const float* adp_W   = (const float*)d_in[8];
    const float* fuse_W  = (const float*)d_in[9];
    const float* fuse_g  = (const float*)d_in[10];
    const float* fuse_b  = (const float*)d_in[11];
    const float* conv1_W = (const float*)d_in[12];
    const float* norm1_g = (const float*)d_in[13];
    const float* norm1_b = (const float*)d_in[14];
    const float* conv2_W = (const float*)d_in[15];
    const float* norm2_g = (const float*)d_in[16];
    const float* norm2_b = (const float*)d_in[17];
    const int*   clusters= (const int*)d_in[18];
    const int*   nidx    = (const int*)d_in[19];
    float* out = (float*)d_out;

    const size_t NC  = (size_t)NPTS * CH;
    const size_t SEG = (size_t)NSEG_ * CH;

    const size_t zwords = 6 * NSEG_ + 10 * 256 + 4;
    const size_t needed = (2 * NC + zwords + 6 * NSEG_ + 3 * (size_t)NPTS
                           + 10 * 256 + 5 * SEG + 98304) * sizeof(float);  // ~167 MB (passed R2-4)
    if (ws_size < needed) return;

    float* ws = (float*)d_ws;
    // 4 bf16 NxC buffers occupy the old 2xNC fp32 region
    unsigned short* B0 = (unsigned short*)ws;        // featB, later c2
    unsigned short* B1 = B0 + NC;                    // L, later fuseY->..., fused? (see wiring)
    unsigned short* B2 = B1 + NC;                    // P / P3 / c1
    unsigned short* B3 = B2 + NC;                    // agg / fused
    float* Z  = ws + 2 * NC;
    int*   cnt   = (int*)Z;
    int*   fpos  = cnt + 3 * NSEG_;
    float* stats = (float*)(fpos + 3 * NSEG_);
    unsigned int* qmax = (unsigned int*)(stats + 10 * 256);
    int*   off   = (int*)(qmax + 4);
    float* invc  = (float*)(off + 3 * NSEG_);
    int*   perm  = (int*)(invc + 3 * NSEG_);
    float* scsh  = (float*)(perm + 3 * (size_t)NPTS);
    float* S1    = scsh + 10 * 256;
    float* S2    = S1 + SEG;
    float* s3    = S2 + SEG;
    unsigned short* Wt16 = (unsigned short*)(s3 + 3 * SEG);
    unsigned short* lwT   = Wt16;
    unsigned short* wT    = Wt16 + 3 * 16384;
    unsigned short* projT = Wt16 + 6 * 16384;
    unsigned short* fuseT = Wt16 + 10 * 16384;

    const int gemmGrid = (NPTS + 127) / 128;
    const int convGrid = (NPTS + 127) / 128;
    const int aggGrid  = (NPTS + 63) / 64;
    const int mapGrid  = 2048;

    zero_kernel<<<64, 256, 0, stream>>>((float4*)Z, (int)(zwords / 4));
    count_kernel<<<512, 256, 0, stream>>>(clusters, cnt);
    invcnt_kernel<<<(3 * NSEG_ + 255) / 256, 256, 0, stream>>>(cnt, invc);
    scan_kernel<<<3, 1024, 0, stream>>>(cnt, off);
    fill_kernel<<<512, 256, 0, stream>>>(clusters, off, fpos, perm);
    cvt_bf16<<<mapGrid, 256, 0, stream>>>(feat, B0, (int)(NC / 8));

    for (int i = 0; i < 3; ++i) {
        wtr_kernel<<<64, 256, 0, stream>>>(lw_W + (size_t)i * 16384, lwT + (size_t)i * 16384, 128);
        wtr_kernel<<<64, 256, 0, stream>>>(w_W + (size_t)i * 16384, wT + (size_t)i * 16384, 128);
    }
    for (int i = 0; i < 4; ++i)
        wtr_kernel<<<64, 256, 0, stream>>>(proj_W + (size_t)i * 16384, projT + (size_t)i * 16384, 128);
    wtr_kernel<<<128, 256, 0, stream>>>(fuse_W, fuseT, 256);

    for (int i = 0; i < 3; ++i) {
        const int* cli   = clusters + (size_t)i * NPTS;
        const int* permi = perm + (size_t)i * NPTS;
        const int* offi  = off + i * NSEG_;
        const int* cnti  = cnt + i * NSEG_;
        float* st  = stats + i * 256;
        float* ss  = scsh + i * 256;
        float* stp = stats + (3 + i) * 256;
        float* ssp = scsh + (3 + i) * 256;
        // L = featB @ lw_W[i] -> B1 (bf16), stats          (STATS|CBF = 72)
        gemm_mfma<72><<<gemmGrid, 256, 0, stream>>>(B0, nullptr, lwT + (size_t)i * 16384, B1,
            nullptr, nullptr, nullptr, nullptr, nullptr, st, st + 128, nullptr);
        finalize_kernel<<<1, 128, 0, stream>>>(st, st + 128, lw_g + i * CH, lw_b + i * CH, ss, ss + 128);
        // s1 = seg_sum(relu(bn(L)))
        gather_seg<0><<<NSEG_, 256, 0, stream>>>(B1, nullptr, ss, ss + 128, nullptr, nullptr,
            permi, offi, cnti, S1);
        // q = (relu(bn(L)) - mean[cl]) @ w_W[i] -> OUT fp32, max   (ACEN|ABN|MAXRED = 19)
        gemm_mfma<19><<<gemmGrid, 256, 0, stream>>>(B1, nullptr, wT + (size_t)i * 16384, out,
            cli, S1, invc + i * NSEG_, ss, ss + 128, nullptr, nullptr, qmax + i);
        // P = featB @ proj_W[i] -> B2 (bf16), stats
        gemm_mfma<72><<<gemmGrid, 256, 0, stream>>>(B0, nullptr, projT + (size_t)i * 16384, B2,
            nullptr, nullptr, nullptr, nullptr, nullptr, stp, stp + 128, nullptr);
        finalize_kernel<<<1, 128, 0, stream>>>(stp, stp + 128, proj_g + i * CH, proj_b + i * CH, ssp, ssp + 128);
        // s2 = seg_sum(exp(q-max))
        gather_seg<1><<<NSEG_, 256, 0, stream>>>(nullptr, out, nullptr, nullptr, nullptr, qmax + i,
            permi, offi, cnti, S2);
        // s3 = seg_sum(relu(bn(P)) * exp(q-max)/(s2+eps))
        gather_seg<2><<<NSEG_, 256, 0, stream>>>(B2, out, ssp, ssp + 128, S2, qmax + i,
            permi, offi, cnti, s3 + (size_t)i * SEG);
    }

    // agg -> B3 (bf16)
    adpagg_kernel<<<aggGrid, 256, 0, stream>>>(B0, adp_W,
        clusters, clusters + NPTS, clusters + 2 * (size_t)NPTS,
        s3, s3 + SEG, s3 + 2 * SEG, B3);

    // P3 = featB @ proj_W[3] -> B2, stats
    {
        float* st = stats + 6 * 256; float* ss = scsh + 6 * 256;
        gemm_mfma<72><<<gemmGrid, 256, 0, stream>>>(B0, nullptr, projT + 3 * (size_t)16384, B2,
            nullptr, nullptr, nullptr, nullptr, nullptr, st, st + 128, nullptr);
        finalize_kernel<<<1, 128, 0, stream>>>(st, st + 128, proj_g + 3 * CH, proj_b + 3 * CH, ss, ss + 128);
    }
    // fuseY = [relu(bn(P3)), agg] @ fuse_W -> B1 (bf16), stats   (K256|ABN|STATS|CBF = 106)
    {
        float* st = stats + 7 * 256; float* ss7 = scsh + 7 * 256;
        gemm_mfma<106><<<gemmGrid, 256, 0, stream>>>(B2, B3, fuseT, B1,
            nullptr, nullptr, nullptr, scsh + 6 * 256, scsh + 6 * 256 + 128, st, st + 128, nullptr);
        finalize_kernel<<<1, 128, 0, stream>>>(st, st + 128, fuse_g, fuse_b, ss7, ss7 + 128);
    }
    // fused = relu(bn(fuseY)) + feat -> B3 (bf16)
    fused_kernel<<<mapGrid, 256, 0, stream>>>(B1, scsh + 7 * 256, scsh + 7 * 256 + 128, feat, B3);

    // conv1: B3 -> B2, stats8
    {
        float* st = stats + 8 * 256; float* ss = scsh + 8 * 256;
        conv_kernel<false><<<convGrid, 512, 0, stream>>>(B3, conv1_W, nidx, nullptr, nullptr,
            B2, st, st + 128);
        finalize_kernel<<<1, 128, 0, stream>>>(st, st + 128, norm1_g, norm1_b, ss, ss + 128);
    }
    // conv2: bn1(B2) -> B0, stats9
    {
        float* st = stats + 9 * 256; float* ss = scsh + 9 * 256;
        conv_kernel<true><<<convGrid, 512, 0, stream>>>(B2, conv2_W, nidx,
            scsh + 8 * 256, scsh + 8 * 256 + 128, B0, st, st + 128);
        finalize_kernel<<<1, 128, 0, stream>>>(st, st + 128, norm2_g, norm2_b, ss, ss + 128);
    }
    // out = relu(bn2(B0) + B3) -> fp32
    final_kernel<<<mapGrid, 256, 0, stream>>>(B0, scsh + 9 * 256, scsh + 9 * 256 + 128, B3, out);
}

// Round 6
// 1330.836 us; speedup vs baseline: 2.9149x; 1.0319x over previous
//
#include <hip/hip_runtime.h>
#include <math.h>

#define NPTS 150000
#define CH   128
#define NSEG_ 4096
#define KOFF 27
#define BN_EPS 1e-5f

typedef __attribute__((ext_vector_type(8))) short bf16x8;
typedef __attribute__((ext_vector_type(4))) float f32x4;

// ---------- helpers ----------
__device__ __forceinline__ unsigned int fenc(float f) {
    unsigned int b = __float_as_uint(f);
    return (b & 0x80000000u) ? ~b : (b | 0x80000000u);
}
__device__ __forceinline__ float fdec(unsigned int u) {
    return __uint_as_float((u & 0x80000000u) ? (u & 0x7fffffffu) : ~u);
}
__device__ __forceinline__ unsigned short f2bf(float f) {
    unsigned int u = __float_as_uint(f);
    unsigned int r = (u + 0x7fffu + ((u >> 16) & 1u)) >> 16;
    return (unsigned short)r;
}
__device__ __forceinline__ float bf2f(unsigned short h) {
    return __uint_as_float(((unsigned int)h) << 16);
}
__device__ __forceinline__ float blo(unsigned int u) { return __uint_as_float(u << 16); }
__device__ __forceinline__ float bhi(unsigned int u) { return __uint_as_float(u & 0xffff0000u); }
__device__ __forceinline__ unsigned int pk2(float a, float b) {
    return (unsigned int)f2bf(a) | ((unsigned int)f2bf(b) << 16);
}
__device__ __forceinline__ int xcd_swz(int bid, int nwg) {
    int q = nwg >> 3, r = nwg & 7;
    int xcd = bid & 7, idx = bid >> 3;
    return (xcd < r ? xcd * (q + 1) : r * (q + 1) + (xcd - r) * q) + idx;
}

__global__ void zero_kernel(float4* __restrict__ p, int n4) {
    for (int i = blockIdx.x * 256 + threadIdx.x; i < n4; i += gridDim.x * 256)
        p[i] = make_float4(0.f, 0.f, 0.f, 0.f);
}

__global__ void cvt_bf16(const float* __restrict__ in, unsigned short* __restrict__ o, int n8) {
    for (int i = blockIdx.x * 256 + threadIdx.x; i < n8; i += gridDim.x * 256) {
        float4 a = *(const float4*)(in + (size_t)i * 8);
        float4 b = *(const float4*)(in + (size_t)i * 8 + 4);
        uint4 w;
        w.x = pk2(a.x, a.y); w.y = pk2(a.z, a.w);
        w.z = pk2(b.x, b.y); w.w = pk2(b.z, b.w);
        *(uint4*)(o + (size_t)i * 8) = w;
    }
}

// all weight transposes in one kernel: 10x [128][128] + fuse [128][256]
__global__ void wtr_all(const float* __restrict__ lw, const float* __restrict__ w,
                        const float* __restrict__ proj, const float* __restrict__ fuse,
                        unsigned short* __restrict__ Wt)
{
    int i = blockIdx.x * 256 + threadIdx.x;
    if (i < 10 * 16384) {
        int u = i >> 14, r = i & 16383;
        int n = r >> 7, k = r & 127;
        const float* src = (u < 3) ? lw + (size_t)u * 16384
                         : (u < 6) ? w + (size_t)(u - 3) * 16384
                                   : proj + (size_t)(u - 6) * 16384;
        Wt[(size_t)u * 16384 + n * 128 + k] = f2bf(src[(size_t)k * 128 + n]);
    } else if (i < 10 * 16384 + 32768) {
        int r = i - 10 * 16384;
        int n = r >> 8, k = r & 255;
        Wt[10 * 16384 + (size_t)n * 256 + k] = f2bf(fuse[(size_t)k * 128 + n]);
    }
}

// ---------- shared GEMM epilogue ----------
template<bool CBF, bool STATS, bool MAXRED>
__device__ __forceinline__ void gemm_epi(
    f32x4 (&acc)[4][4], void* Cv, int R, int C0, int lc, int lk, int w, int t,
    float (*reds)[4][16], float (*redq)[4][16],
    float* colsum, float* colsq, unsigned int* gmax)
{
    float* Cf = (float*)Cv;
    unsigned short* Chh = (unsigned short*)Cv;
    float s[4] = {0.f, 0.f, 0.f, 0.f}, q[4] = {0.f, 0.f, 0.f, 0.f};
    unsigned int lmax = 0u;
#pragma unroll
    for (int mi = 0; mi < 4; ++mi) {
#pragma unroll
        for (int r = 0; r < 4; ++r) {
            int row = R + mi * 16 + lk * 4 + r;
            if (row < NPTS) {
#pragma unroll
                for (int ni = 0; ni < 4; ++ni) {
                    float v = acc[mi][ni][r];
                    int col = C0 + ni * 16 + lc;
                    if constexpr (CBF) {
                        unsigned short hb = f2bf(v);
                        Chh[(size_t)row * CH + col] = hb;
                        if constexpr (MAXRED) { unsigned int e = fenc(bf2f(hb)); if (e > lmax) lmax = e; }
                    } else {
                        Cf[(size_t)row * CH + col] = v;
                        if constexpr (MAXRED) { unsigned int e = fenc(v); if (e > lmax) lmax = e; }
                    }
                    if constexpr (STATS) { s[ni] += v; q[ni] += v * v; }
                }
            }
        }
    }
    if constexpr (STATS) {
#pragma unroll
        for (int ni = 0; ni < 4; ++ni) {
            s[ni] += __shfl_xor(s[ni], 16); s[ni] += __shfl_xor(s[ni], 32);
            q[ni] += __shfl_xor(q[ni], 16); q[ni] += __shfl_xor(q[ni], 32);
        }
        __syncthreads();   // safe reuse of reds/redq across calls
        if (lk == 0) {
#pragma unroll
            for (int ni = 0; ni < 4; ++ni) { reds[w][ni][lc] = s[ni]; redq[w][ni][lc] = q[ni]; }
        }
        __syncthreads();
        if (t < 128) {
            int half = t >> 6, fr = (t >> 4) & 3, cc = t & 15;
            atomicAdd(colsum + t, reds[half][fr][cc] + reds[half + 2][fr][cc]);
            atomicAdd(colsq  + t, redq[half][fr][cc] + redq[half + 2][fr][cc]);
        }
    }
    if constexpr (MAXRED) {
#pragma unroll
        for (int d = 1; d < 64; d <<= 1) {
            unsigned int o = __shfl_xor(lmax, d);
            if (o > lmax) lmax = o;
        }
        if ((t & 63) == 0) atomicMax(gmax, lmax);
    }
}

// ---------- dual GEMM: C1 = A@W1, C2 = A@W2 (A-frags loaded once, bf16 out, stats both) ----------
__global__ __launch_bounds__(256) void gemm_dual(
    const unsigned short* __restrict__ A,
    const unsigned short* __restrict__ W1t, const unsigned short* __restrict__ W2t,
    unsigned short* __restrict__ C1, unsigned short* __restrict__ C2,
    float* __restrict__ st1, float* __restrict__ st2)
{
    __shared__ float reds[4][4][16], redq[4][4][16];
    const int t  = threadIdx.x;
    const int l  = t & 63, w = t >> 6;
    const int lc = l & 15, lk = l >> 4;
    const int wr = w >> 1, wc = w & 1;
    const int bid = xcd_swz((int)blockIdx.x, (int)gridDim.x);
    const int R  = bid * 128 + wr * 64;
    const int C0 = wc * 64;

    int rowm[4];
#pragma unroll
    for (int mi = 0; mi < 4; ++mi) {
        int r = R + mi * 16 + lc;
        rowm[mi] = r < NPTS ? r : NPTS - 1;
    }
    // all 16 A fragments up-front: 16 loads in flight per lane
    bf16x8 a[4][4];
#pragma unroll
    for (int ks = 0; ks < 4; ++ks)
#pragma unroll
        for (int mi = 0; mi < 4; ++mi)
            a[ks][mi] = *(const bf16x8*)(A + (size_t)rowm[mi] * CH + ks * 32 + lk * 8);

    f32x4 acc[4][4];
#pragma unroll
    for (int mi = 0; mi < 4; ++mi)
#pragma unroll
        for (int ni = 0; ni < 4; ++ni) acc[mi][ni] = (f32x4){0.f, 0.f, 0.f, 0.f};
#pragma unroll
    for (int ks = 0; ks < 4; ++ks) {
        bf16x8 b[4];
#pragma unroll
        for (int ni = 0; ni < 4; ++ni)
            b[ni] = *(const bf16x8*)(W1t + (size_t)(C0 + ni * 16 + lc) * 128 + ks * 32 + lk * 8);
#pragma unroll
        for (int mi = 0; mi < 4; ++mi)
#pragma unroll
            for (int ni = 0; ni < 4; ++ni)
                acc[mi][ni] = __builtin_amdgcn_mfma_f32_16x16x32_bf16(a[ks][mi], b[ni], acc[mi][ni], 0, 0, 0);
    }
    gemm_epi<true, true, false>(acc, C1, R, C0, lc, lk, w, t, reds, redq, st1, st1 + 128, nullptr);

#pragma unroll
    for (int mi = 0; mi < 4; ++mi)
#pragma unroll
        for (int ni = 0; ni < 4; ++ni) acc[mi][ni] = (f32x4){0.f, 0.f, 0.f, 0.f};
#pragma unroll
    for (int ks = 0; ks < 4; ++ks) {
        bf16x8 b[4];
#pragma unroll
        for (int ni = 0; ni < 4; ++ni)
            b[ni] = *(const bf16x8*)(W2t + (size_t)(C0 + ni * 16 + lc) * 128 + ks * 32 + lk * 8);
#pragma unroll
        for (int mi = 0; mi < 4; ++mi)
#pragma unroll
            for (int ni = 0; ni < 4; ++ni)
                acc[mi][ni] = __builtin_amdgcn_mfma_f32_16x16x32_bf16(a[ks][mi], b[ni], acc[mi][ni], 0, 0, 0);
    }
    gemm_epi<true, true, false>(acc, C2, R, C0, lc, lk, w, t, reds, redq, st2, st2 + 128, nullptr);
}

// ---------- single GEMM with transforms ----------
// FLAGS: 1=ACEN, 2=ABN, 8=STATS, 16=MAXRED, 32=K256 (A1 = second half, plain), 64=CBF
template<int FLAGS>
__global__ __launch_bounds__(256) void gemm_one(
    const unsigned short* A0, const unsigned short* A1,
    const unsigned short* __restrict__ Wt, void* Cv,
    const int* __restrict__ cl, const float* __restrict__ seg, const float* __restrict__ invcnt,
    const float* __restrict__ bnsc, const float* __restrict__ bnsh,
    float* __restrict__ colsum, float* __restrict__ colsq, unsigned int* __restrict__ gmax)
{
    constexpr bool ACEN   = (FLAGS & 1)  != 0;
    constexpr bool ABN    = (FLAGS & 2)  != 0;
    constexpr bool STATS  = (FLAGS & 8)  != 0;
    constexpr bool MAXRED = (FLAGS & 16) != 0;
    constexpr bool K256   = (FLAGS & 32) != 0;
    constexpr bool CBF    = (FLAGS & 64) != 0;
    constexpr int  KW = K256 ? 256 : 128;
    constexpr int  NH = K256 ? 2 : 1;

    __shared__ float reds[4][4][16], redq[4][4][16];
    const int t  = threadIdx.x;
    const int l  = t & 63, w = t >> 6;
    const int lc = l & 15, lk = l >> 4;
    const int wr = w >> 1, wc = w & 1;
    const int bid = xcd_swz((int)blockIdx.x, (int)gridDim.x);
    const int R  = bid * 128 + wr * 64;
    const int C0 = wc * 64;

    int rowm[4];
#pragma unroll
    for (int mi = 0; mi < 4; ++mi) {
        int r = R + mi * 16 + lc;
        rowm[mi] = r < NPTS ? r : NPTS - 1;
    }
    int sg4[4]; float ic4[4];
    if constexpr (ACEN) {
#pragma unroll
        for (int mi = 0; mi < 4; ++mi) { sg4[mi] = cl[rowm[mi]]; ic4[mi] = invcnt[sg4[mi]]; }
    }

    f32x4 acc[4][4];
#pragma unroll
    for (int mi = 0; mi < 4; ++mi)
#pragma unroll
        for (int ni = 0; ni < 4; ++ni) acc[mi][ni] = (f32x4){0.f, 0.f, 0.f, 0.f};

#pragma unroll
    for (int hh = 0; hh < NH; ++hh) {
        const unsigned short* Asrc = (K256 && hh) ? A1 : A0;
        bf16x8 a[4][4];
#pragma unroll
        for (int ks = 0; ks < 4; ++ks)
#pragma unroll
            for (int mi = 0; mi < 4; ++mi)
                a[ks][mi] = *(const bf16x8*)(Asrc + (size_t)rowm[mi] * CH + ks * 32 + lk * 8);

        if constexpr (ABN || ACEN) {
            if (hh == 0) {
#pragma unroll
                for (int ks = 0; ks < 4; ++ks) {
                    const int kb = ks * 32 + lk * 8;
                    float4 s0, s1v, h0, h1;
                    if constexpr (ABN) {
                        s0  = *(const float4*)(bnsc + kb); s1v = *(const float4*)(bnsc + kb + 4);
                        h0  = *(const float4*)(bnsh + kb); h1  = *(const float4*)(bnsh + kb + 4);
                    }
#pragma unroll
                    for (int mi = 0; mi < 4; ++mi) {
                        union { unsigned short u[8]; bf16x8 v; } pk;
                        pk.v = a[ks][mi];
                        float v[8];
#pragma unroll
                        for (int e = 0; e < 8; ++e) v[e] = bf2f(pk.u[e]);
                        if constexpr (ABN) {
                            v[0] = fmaxf(v[0] * s0.x + h0.x, 0.f);  v[1] = fmaxf(v[1] * s0.y + h0.y, 0.f);
                            v[2] = fmaxf(v[2] * s0.z + h0.z, 0.f);  v[3] = fmaxf(v[3] * s0.w + h0.w, 0.f);
                            v[4] = fmaxf(v[4] * s1v.x + h1.x, 0.f); v[5] = fmaxf(v[5] * s1v.y + h1.y, 0.f);
                            v[6] = fmaxf(v[6] * s1v.z + h1.z, 0.f); v[7] = fmaxf(v[7] * s1v.w + h1.w, 0.f);
                        }
                        if constexpr (ACEN) {
                            const float* sp = seg + (size_t)sg4[mi] * CH + kb;
                            float4 m0 = *(const float4*)sp, m1 = *(const float4*)(sp + 4);
                            float ic = ic4[mi];
                            v[0] -= m0.x * ic; v[1] -= m0.y * ic; v[2] -= m0.z * ic; v[3] -= m0.w * ic;
                            v[4] -= m1.x * ic; v[5] -= m1.y * ic; v[6] -= m1.z * ic; v[7] -= m1.w * ic;
                        }
#pragma unroll
                        for (int e = 0; e < 8; ++e) pk.u[e] = f2bf(v[e]);
                        a[ks][mi] = pk.v;
                    }
                }
            }
        }
#pragma unroll
        for (int ks = 0; ks < 4; ++ks) {
            bf16x8 b[4];
#pragma unroll
            for (int ni = 0; ni < 4; ++ni)
                b[ni] = *(const bf16x8*)(Wt + (size_t)(C0 + ni * 16 + lc) * KW + hh * 128 + ks * 32 + lk * 8);
#pragma unroll
            for (int mi = 0; mi < 4; ++mi)
#pragma unroll
                for (int ni = 0; ni < 4; ++ni)
                    acc[mi][ni] = __builtin_amdgcn_mfma_f32_16x16x32_bf16(a[ks][mi], b[ni], acc[mi][ni], 0, 0, 0);
        }
    }
    gemm_epi<CBF, STATS, MAXRED>(acc, Cv, R, C0, lc, lk, w, t, reds, redq, colsum, colsq, gmax);
}

// ---------- CSR build ----------
__global__ void count_kernel(const int* __restrict__ clusters, int* __restrict__ cnt) {
    const int tot = 3 * NPTS;
    for (int f = blockIdx.x * 256 + threadIdx.x; f < tot; f += gridDim.x * 256) {
        int i = f / NPTS;
        atomicAdd(cnt + i * NSEG_ + clusters[f], 1);
    }
}

__global__ void invcnt_kernel(const int* __restrict__ cnt, float* __restrict__ invc) {
    int x = blockIdx.x * 256 + threadIdx.x;
    if (x < 3 * NSEG_) {
        int c = cnt[x];
        invc[x] = 1.0f / (float)(c > 1 ? c : 1);
    }
}

__global__ __launch_bounds__(1024) void scan_kernel(const int* __restrict__ cnt, int* __restrict__ off) {
    __shared__ int tot[1024];
    const int L = blockIdx.x;
    const int* c = cnt + L * NSEG_;
    int* o = off + L * NSEG_;
    const int t = threadIdx.x;
    int v[4];
    int s = 0;
#pragma unroll
    for (int j = 0; j < 4; ++j) { v[j] = s; s += c[t * 4 + j]; }
    tot[t] = s;
    __syncthreads();
    for (int d = 1; d < 1024; d <<= 1) {
        int x = (t >= d) ? tot[t - d] : 0;
        __syncthreads();
        tot[t] += x;
        __syncthreads();
    }
    int pre = (t == 0) ? 0 : tot[t - 1];
#pragma unroll
    for (int j = 0; j < 4; ++j) o[t * 4 + j] = pre + v[j];
}

__global__ void fill_kernel(const int* __restrict__ clusters, const int* __restrict__ off,
                            int* __restrict__ fpos, int* __restrict__ perm) {
    const int tot = 3 * NPTS;
    for (int f = blockIdx.x * 256 + threadIdx.x; f < tot; f += gridDim.x * 256) {
        int i = f / NPTS;
        int n = f - i * NPTS;
        int s = i * NSEG_ + clusters[f];
        int pos = off[s] + atomicAdd(fpos + s, 1);
        perm[(size_t)i * NPTS + pos] = n;
    }
}

// ---------- s1 = seg_sum(relu(bn(L))), bn inlined from stats ----------
__global__ __launch_bounds__(256) void gather_s1(
    const unsigned short* __restrict__ L,
    const float* __restrict__ cs, const float* __restrict__ cq,
    const float* __restrict__ g, const float* __restrict__ b,
    const int* __restrict__ perm, const int* __restrict__ off, const int* __restrict__ cnt,
    float* __restrict__ segout)
{
    __shared__ float red[256];
    const int s = blockIdx.x;
    const int t = threadIdx.x;
    const int c = t & 127, h = t >> 7;
    const int start = off[s], m = cnt[s];
    float mean = cs[c] / (float)NPTS;
    float var  = cq[c] / (float)NPTS - mean * mean;
    float istd = rsqrtf(var + BN_EPS);
    float scv = istd * g[c];
    float shv = b[c] - mean * scv;
    float acc = 0.f;
    for (int j = h; j < m; j += 2) {
        int p = perm[start + j];
        acc += fmaxf(bf2f(L[(size_t)p * CH + c]) * scv + shv, 0.f);
    }
    red[t] = acc;
    __syncthreads();
    if (h == 0) segout[(size_t)s * CH + c] = red[c] + red[c + 128];
}

// ---------- fused s2+s3: block=segment; pass1 local s2, pass2 s3 (q,P bf16; bn inlined) ----------
__global__ __launch_bounds__(256) void gather_s23(
    const unsigned short* __restrict__ Q, const unsigned short* __restrict__ P,
    const float* __restrict__ cs, const float* __restrict__ cq,
    const float* __restrict__ g, const float* __restrict__ b,
    const unsigned int* __restrict__ gmax,
    const int* __restrict__ perm, const int* __restrict__ off, const int* __restrict__ cnt,
    float* __restrict__ s3out)
{
    __shared__ float red[256];
    __shared__ float s2sh[128];
    const int s = blockIdx.x;
    const int t = threadIdx.x;
    const int c = t & 127, h = t >> 7;
    const int start = off[s], m = cnt[s];
    const float mx = fdec(*gmax);
    float mean = cs[c] / (float)NPTS;
    float var  = cq[c] / (float)NPTS - mean * mean;
    float istd = rsqrtf(var + BN_EPS);
    float scv = istd * g[c];
    float shv = b[c] - mean * scv;

    float accE = 0.f;
    for (int j = h; j < m; j += 2) {
        int p = perm[start + j];
        accE += expf(bf2f(Q[(size_t)p * CH + c]) - mx);
    }
    red[t] = accE;
    __syncthreads();
    if (h == 0) s2sh[c] = red[c] + red[c + 128];
    __syncthreads();
    float dinv = 1.0f / (s2sh[c] + 1e-6f);

    float accS = 0.f;
    for (int j = h; j < m; j += 2) {
        int p = perm[start + j];
        float pf = fmaxf(bf2f(P[(size_t)p * CH + c]) * scv + shv, 0.f);
        accS += pf * expf(bf2f(Q[(size_t)p * CH + c]) - mx) * dinv;
    }
    red[t] = accS;
    __syncthreads();
    if (h == 0) s3out[(size_t)s * CH + c] = red[c] + red[c + 128];
}

// ---------- finalize (kept for the two ABN-GEMM consumers) ----------
__global__ void finalize_kernel(const float* __restrict__ colsum, const float* __restrict__ colsq,
                                const float* __restrict__ g, const float* __restrict__ b,
                                float* __restrict__ sc, float* __restrict__ sh)
{
    int c = threadIdx.x;
    float mean = colsum[c] / (float)NPTS;
    float var  = colsq[c] / (float)NPTS - mean * mean;
    float istd = rsqrtf(var + BN_EPS);
    float s = istd * g[c];
    sc[c] = s;
    sh[c] = b[c] - mean * s;
}

// ---------- adp softmax + agg ----------
__global__ __launch_bounds__(256) void adpagg_kernel(
    const unsigned short* __restrict__ featB, const float* __restrict__ adpW,
    const int* __restrict__ cl0, const int* __restrict__ cl1, const int* __restrict__ cl2,
    const float* __restrict__ s30, const float* __restrict__ s31, const float* __restrict__ s32,
    unsigned short* __restrict__ agg)
{
    __shared__ float ftile[64][132];
    __shared__ float wl[128][3];
    __shared__ float pr[64][3];
    __shared__ int   cls[64][3];
    const int t = threadIdx.x;
    const int n0 = blockIdx.x * 64;

    if (t < 128) { wl[t][0] = adpW[t * 3]; wl[t][1] = adpW[t * 3 + 1]; wl[t][2] = adpW[t * 3 + 2]; }
#pragma unroll
    for (int h = 0; h < 4; ++h) {
        int f = t + h * 256;
        int r = f >> 4, c8 = (f & 15) * 8;
        int n = n0 + r;
        if (n < NPTS) {
            uint4 rw = *(const uint4*)(featB + (size_t)n * CH + c8);
            ftile[r][c8 + 0] = blo(rw.x); ftile[r][c8 + 1] = bhi(rw.x);
            ftile[r][c8 + 2] = blo(rw.y); ftile[r][c8 + 3] = bhi(rw.y);
            ftile[r][c8 + 4] = blo(rw.z); ftile[r][c8 + 5] = bhi(rw.z);
            ftile[r][c8 + 6] = blo(rw.w); ftile[r][c8 + 7] = bhi(rw.w);
        } else {
#pragma unroll
            for (int e = 0; e < 8; ++e) ftile[r][c8 + e] = 0.f;
        }
    }
    if (t < 64) {
        int n = n0 + t;
        if (n < NPTS) { cls[t][0] = cl0[n]; cls[t][1] = cl1[n]; cls[t][2] = cl2[n]; }
        else { cls[t][0] = 0; cls[t][1] = 0; cls[t][2] = 0; }
    }
    __syncthreads();

    if (t < 64) {
        float p0 = 0.f, p1 = 0.f, p2 = 0.f;
        for (int k = 0; k < 128; ++k) {
            float fv = ftile[t][k];
            p0 += fv * wl[k][0]; p1 += fv * wl[k][1]; p2 += fv * wl[k][2];
        }
        float m = fmaxf(p0, fmaxf(p1, p2));
        float e0 = expf(p0 - m), e1 = expf(p1 - m), e2 = expf(p2 - m);
        float inv = 1.f / (e0 + e1 + e2);
        pr[t][0] = e0 * inv; pr[t][1] = e1 * inv; pr[t][2] = e2 * inv;
    }
    __syncthreads();

#pragma unroll
    for (int h = 0; h < 8; ++h) {
        int f = t + h * 256;
        int r = f >> 5, c4 = (f & 31) << 2;
        int n = n0 + r;
        if (n < NPTS) {
            float a0 = pr[r][0], a1 = pr[r][1], a2 = pr[r][2];
            float4 v0 = *(const float4*)(s30 + (size_t)cls[r][0] * CH + c4);
            float4 v1 = *(const float4*)(s31 + (size_t)cls[r][1] * CH + c4);
            float4 v2 = *(const float4*)(s32 + (size_t)cls[r][2] * CH + c4);
            float ox = a0 * v0.x + a1 * v1.x + a2 * v2.x;
            float oy = a0 * v0.y + a1 * v1.y + a2 * v2.y;
            float oz = a0 * v0.z + a1 * v1.z + a2 * v2.z;
            float ow = a0 * v0.w + a1 * v1.w + a2 * v2.w;
            uint2 wv; wv.x = pk2(ox, oy); wv.y = pk2(oz, ow);
            *(uint2*)(agg + (size_t)n * CH + c4) = wv;
        }
    }
}

// ---------- fused = relu(bn(fuseY)) + featB (bn inlined) ----------
__global__ void fused_kernel(const unsigned short* __restrict__ fY,
                             const float* __restrict__ cs, const float* __restrict__ cq,
                             const float* __restrict__ g, const float* __restrict__ b,
                             const unsigned short* __restrict__ featB, unsigned short* __restrict__ outB)
{
    const int tot = NPTS * 32;
    for (int f = blockIdx.x * 256 + threadIdx.x; f < tot; f += gridDim.x * 256) {
        int n = f >> 5, c4 = (f & 31) << 2;
        float4 cs4 = *(const float4*)(cs + c4);
        float4 cq4 = *(const float4*)(cq + c4);
        float4 g4  = *(const float4*)(g + c4);
        float4 b4  = *(const float4*)(b + c4);
        float mx0 = cs4.x / (float)NPTS, mx1 = cs4.y / (float)NPTS,
              mx2 = cs4.z / (float)NPTS, mx3 = cs4.w / (float)NPTS;
        float sc0 = rsqrtf(cq4.x / (float)NPTS - mx0 * mx0 + BN_EPS) * g4.x;
        float sc1 = rsqrtf(cq4.y / (float)NPTS - mx1 * mx1 + BN_EPS) * g4.y;
        float sc2 = rsqrtf(cq4.z / (float)NPTS - mx2 * mx2 + BN_EPS) * g4.z;
        float sc3 = rsqrtf(cq4.w / (float)NPTS - mx3 * mx3 + BN_EPS) * g4.w;
        float sh0 = b4.x - mx0 * sc0, sh1 = b4.y - mx1 * sc1;
        float sh2 = b4.z - mx2 * sc2, sh3 = b4.w - mx3 * sc3;
        uint2 y2 = *(const uint2*)(fY + (size_t)n * CH + c4);
        uint2 f2 = *(const uint2*)(featB + (size_t)n * CH + c4);
        float o0 = fmaxf(blo(y2.x) * sc0 + sh0, 0.f) + blo(f2.x);
        float o1 = fmaxf(bhi(y2.x) * sc1 + sh1, 0.f) + bhi(f2.x);
        float o2 = fmaxf(blo(y2.y) * sc2 + sh2, 0.f) + blo(f2.y);
        float o3 = fmaxf(bhi(y2.y) * sc3 + sh3, 0.f) + bhi(f2.y);
        uint2 wv; wv.x = pk2(o0, o1); wv.y = pk2(o2, o3);
        *(uint2*)(outB + (size_t)n * CH + c4) = wv;
    }
}

// ---------- grouped subm conv: bf16 weights in LDS (42.5 KB total -> 3 blocks/CU) ----------
template<bool INBN>
__global__ __launch_bounds__(512) void conv_kernel(
    const unsigned short* __restrict__ X, const float* __restrict__ Wc, const int* __restrict__ nidx,
    const float* __restrict__ csIn, const float* __restrict__ cqIn,
    const float* __restrict__ gIn, const float* __restrict__ bIn,
    unsigned short* __restrict__ Y, float* __restrict__ colsum, float* __restrict__ colsq)
{
    __shared__ unsigned short Wh[KOFF * 4 * 128];  // 27648 B
    __shared__ int   nlds[128 * KOFF];             // 13824 B (aliased as red later)
    __shared__ float bnp[256];
    float* red = (float*)nlds;

    const int t = threadIdx.x;
    const int g = t & 31, ps = t >> 5;
    const int bid = xcd_swz((int)blockIdx.x, (int)gridDim.x);
    const int n0 = bid * 128;

    for (int f = t; f < KOFF * 512; f += 512) {
        int k = f >> 9, rem = f & 511;
        int gg = rem >> 4, ii = (rem >> 2) & 3, oo = rem & 3;
        Wh[(k * 4 + ii) * 128 + gg * 4 + oo] = f2bf(Wc[f]);
    }
    for (int f = t; f < 128 * KOFF; f += 512) {
        int p = f / KOFF, k = f - p * KOFF;
        int n = n0 + p;
        nlds[f] = (n < NPTS) ? nidx[(size_t)n * KOFF + k] : -1;
    }
    if (INBN && t < 128) {
        float mean = csIn[t] / (float)NPTS;
        float var  = cqIn[t] / (float)NPTS - mean * mean;
        float sc = rsqrtf(var + BN_EPS) * gIn[t];
        bnp[t] = sc; bnp[128 + t] = bIn[t] - mean * sc;
    }
    __syncthreads();

    float4 bs4 = make_float4(1.f, 1.f, 1.f, 1.f), bh4 = make_float4(0.f, 0.f, 0.f, 0.f);
    if (INBN) { bs4 = *(float4*)&bnp[g * 4]; bh4 = *(float4*)&bnp[128 + g * 4]; }

    float acc[8][4];
#pragma unroll
    for (int j = 0; j < 8; ++j)
#pragma unroll
        for (int o = 0; o < 4; ++o) acc[j][o] = 0.f;

    for (int k = 0; k < KOFF; ++k) {
        uint2 u0 = *(const uint2*)&Wh[(k * 4 + 0) * 128 + g * 4];
        uint2 u1 = *(const uint2*)&Wh[(k * 4 + 1) * 128 + g * 4];
        uint2 u2 = *(const uint2*)&Wh[(k * 4 + 2) * 128 + g * 4];
        uint2 u3 = *(const uint2*)&Wh[(k * 4 + 3) * 128 + g * 4];
        float w0x = blo(u0.x), w0y = bhi(u0.x), w0z = blo(u0.y), w0w = bhi(u0.y);
        float w1x = blo(u1.x), w1y = bhi(u1.x), w1z = blo(u1.y), w1w = bhi(u1.y);
        float w2x = blo(u2.x), w2y = bhi(u2.x), w2z = blo(u2.y), w2w = bhi(u2.y);
        float w3x = blo(u3.x), w3y = bhi(u3.x), w3z = blo(u3.y), w3w = bhi(u3.y);
#pragma unroll
        for (int j = 0; j < 8; ++j) {
            int p = ps * 8 + j;
            int idx = nlds[p * KOFF + k];
            if (idx >= 0) {
                uint2 rw = *(const uint2*)(X + (size_t)idx * CH + g * 4);
                float vx = blo(rw.x), vy = bhi(rw.x), vz = blo(rw.y), vw = bhi(rw.y);
                if (INBN) {
                    vx = vx * bs4.x + bh4.x; vy = vy * bs4.y + bh4.y;
                    vz = vz * bs4.z + bh4.z; vw = vw * bs4.w + bh4.w;
                }
                acc[j][0] += vx * w0x + vy * w1x + vz * w2x + vw * w3x;
                acc[j][1] += vx * w0y + vy * w1y + vz * w2y + vw * w3y;
                acc[j][2] += vx * w0z + vy * w1z + vz * w2z + vw * w3z;
                acc[j][3] += vx * w0w + vy * w1w + vz * w2w + vw * w3w;
            }
        }
    }

    float s[4] = {0.f, 0.f, 0.f, 0.f}, q[4] = {0.f, 0.f, 0.f, 0.f};
#pragma unroll
    for (int j = 0; j < 8; ++j) {
        int n = n0 + ps * 8 + j;
        if (n < NPTS) {
            uint2 wv; wv.x = pk2(acc[j][0], acc[j][1]); wv.y = pk2(acc[j][2], acc[j][3]);
            *(uint2*)(Y + (size_t)n * CH + g * 4) = wv;
            s[0] += acc[j][0]; s[1] += acc[j][1]; s[2] += acc[j][2]; s[3] += acc[j][3];
            q[0] += acc[j][0] * acc[j][0]; q[1] += acc[j][1] * acc[j][1];
            q[2] += acc[j][2] * acc[j][2]; q[3] += acc[j][3] * acc[j][3];
        }
    }
    __syncthreads();
    *(float4*)&red[ps * 128 + g * 4] = make_float4(s[0], s[1], s[2], s[3]);
    __syncthreads();
    if (t < 128) {
        float tot = 0.f;
#pragma unroll
        for (int r = 0; r < 16; ++r) tot += red[r * 128 + t];
        atomicAdd(colsum + t, tot);
    }
    __syncthreads();
    *(float4*)&red[ps * 128 + g * 4] = make_float4(q[0], q[1], q[2], q[3]);
    __syncthreads();
    if (t < 128) {
        float tot = 0.f;
#pragma unroll
        for (int r = 0; r < 16; ++r) tot += red[r * 128 + t];
        atomicAdd(colsq + t, tot);
    }
}

// ---------- out = relu(bn2(c2) + fused), bn inlined ----------
__global__ void final_kernel(const unsigned short* __restrict__ c2,
                             const float* __restrict__ cs, const float* __restrict__ cq,
                             const float* __restrict__ g, const float* __restrict__ b,
                             const unsigned short* __restrict__ fused, float* __restrict__ out)
{
    const int tot = NPTS * 32;
    for (int f = blockIdx.x * 256 + threadIdx.x; f < tot; f += gridDim.x * 256) {
        int n = f >> 5, c4 = (f & 31) << 2;
        float4 cs4 = *(const float4*)(cs + c4);
        float4 cq4 = *(const float4*)(cq + c4);
        float4 g4  = *(const float4*)(g + c4);
        float4 b4  = *(const float4*)(b + c4);
        float mx0 = cs4.x / (float)NPTS, mx1 = cs4.y / (float)NPTS,
              mx2 = cs4.z / (float)NPTS, mx3 = cs4.w / (float)NPTS;
        float sc0 = rsqrtf(cq4.x / (float)NPTS - mx0 * mx0 + BN_EPS) * g4.x;
        float sc1 = rsqrtf(cq4.y / (float)NPTS - mx1 * mx1 + BN_EPS) * g4.y;
        float sc2 = rsqrtf(cq4.z / (float)NPTS - mx2 * mx2 + BN_EPS) * g4.z;
        float sc3 = rsqrtf(cq4.w / (float)NPTS - mx3 * mx3 + BN_EPS) * g4.w;
        float sh0 = b4.x - mx0 * sc0, sh1 = b4.y - mx1 * sc1;
        float sh2 = b4.z - mx2 * sc2, sh3 = b4.w - mx3 * sc3;
        uint2 y2 = *(const uint2*)(c2 + (size_t)n * CH + c4);
        uint2 r2 = *(const uint2*)(fused + (size_t)n * CH + c4);
        float4 o;
        o.x = fmaxf(blo(y2.x) * sc0 + sh0 + blo(r2.x), 0.f);
        o.y = fmaxf(bhi(y2.x) * sc1 + sh1 + bhi(r2.x), 0.f);
        o.z = fmaxf(blo(y2.y) * sc2 + sh2 + blo(r2.y), 0.f);
        o.w = fmaxf(bhi(y2.y) * sc3 + sh3 + bhi(r2.y), 0.f);
        *(float4*)(out + (size_t)n * CH + c4) = o;
    }
}

// ---------- host ----------
extern "C" void kernel_launch(void* const* d_in, const int* in_sizes, int n_in,
                              void* d_out, int out_size, void* d_ws, size_t ws_size,
                              hipStream_t stream) {
    (void)in_sizes; (void)n_in; (void)out_size;
    const float* feat    = (const float*)d_in[0];
    const float* lw_W    = (const float*)d_in[1];
    const float* lw_g    = (const float*)d_in[2];
    const float* lw_b    = (const float*)d_in[3];
    const float* w_W     = (const float*)d_in[4];
    const float* proj_W  = (const float*)d_in[5];
    const float* proj_g  = (const float*)d_in[6];
    const float* proj_b  = (const float*)d_in[7];
    const float* adp_W   = (const float*)d_in[8];
    const float* fuse_W  = (const float*)d_in[9];
    const float* fuse_g  = (const float*)d_in[10];
    const float* fuse_b  = (const float*)d_in[11];
    const float* conv1_W = (const float*)d_in[12];
    const float* norm1_g = (const float*)d_in[13];
    const float* norm1_b = (const float*)d_in[14];
    const float* conv2_W = (const float*)d_in[15];
    const float* norm2_g = (const float*)d_in[16];
    const float* norm2_b = (const float*)d_in[17];
    const int*   clusters= (const int*)d_in[18];
    const int*   nidx    = (const int*)d_in[19];
    float* out = (float*)d_out;

    const size_t NC  = (size_t)NPTS * CH;
    const size_t SEG = (size_t)NSEG_ * CH;

    const size_t zwords = 6 * NSEG_ + 10 * 256 + 4;
    const size_t needed = (2 * NC + zwords + 6 * NSEG_ + 3 * (size_t)NPTS
                           + 10 * 256 + 5 * SEG + 98304) * sizeof(float);  // ~167 MB (known good)
    if (ws_size < needed) return;

    float* ws = (float*)d_ws;
    unsigned short* B0 = (unsigned short*)ws;   // featB
    unsigned short* B1 = B0 + NC;               // L -> q (in place) / fuseY / conv2 out
    unsigned short* B2 = B1 + NC;               // P / P3 / fused
    unsigned short* B3 = B2 + NC;               // agg / conv1 out
    float* Z  = ws + 2 * NC;
    int*   cnt   = (int*)Z;
    int*   fpos  = cnt + 3 * NSEG_;
    float* stats = (float*)(fpos + 3 * NSEG_);
    unsigned int* qmax = (unsigned int*)(stats + 10 * 256);
    int*   off   = (int*)(qmax + 4);
    float* invc  = (float*)(off + 3 * NSEG_);
    int*   perm  = (int*)(invc + 3 * NSEG_);
    float* scsh  = (float*)(perm + 3 * (size_t)NPTS);
    float* S1    = scsh + 10 * 256;
    float* s3    = S1 + 2 * SEG;                // (S2 slot unused, layout kept)
    unsigned short* Wt16 = (unsigned short*)(s3 + 3 * SEG);
    unsigned short* lwT   = Wt16;
    unsigned short* wT    = Wt16 + 3 * 16384;
    unsigned short* projT = Wt16 + 6 * 16384;
    unsigned short* fuseT = Wt16 + 10 * 16384;

    const int gemmGrid = (NPTS + 127) / 128;
    const int convGrid = (NPTS + 127) / 128;
    const int aggGrid  = (NPTS + 63) / 64;
    const int mapGrid  = 2048;

    zero_kernel<<<64, 256, 0, stream>>>((float4*)Z, (int)(zwords / 4));
    count_kernel<<<512, 256, 0, stream>>>(clusters, cnt);
    invcnt_kernel<<<(3 * NSEG_ + 255) / 256, 256, 0, stream>>>(cnt, invc);
    scan_kernel<<<3, 1024, 0, stream>>>(cnt, off);
    fill_kernel<<<512, 256, 0, stream>>>(clusters, off, fpos, perm);
    cvt_bf16<<<mapGrid, 256, 0, stream>>>(feat, B0, (int)(NC / 8));
    wtr_all<<<768, 256, 0, stream>>>(lw_W, w_W, proj_W, fuse_W, Wt16);

    for (int i = 0; i < 3; ++i) {
        const int* cli   = clusters + (size_t)i * NPTS;
        const int* permi = perm + (size_t)i * NPTS;
        const int* offi  = off + i * NSEG_;
        const int* cnti  = cnt + i * NSEG_;
        float* st  = stats + i * 256;          // lw stats
        float* stp = stats + (3 + i) * 256;    // proj stats
        float* ss  = scsh + i * 256;           // finalized lw bn
        // L -> B1, P -> B2 (one A read)
        gemm_dual<<<gemmGrid, 256, 0, stream>>>(B0, lwT + (size_t)i * 16384,
            projT + (size_t)i * 16384, B1, B2, st, stp);
        finalize_kernel<<<1, 128, 0, stream>>>(st, st + 128, lw_g + i * CH, lw_b + i * CH, ss, ss + 128);
        // s1 = seg_sum(relu(bn(L)))
        gather_s1<<<NSEG_, 256, 0, stream>>>(B1, st, st + 128, lw_g + i * CH, lw_b + i * CH,
            permi, offi, cnti, S1);
        // q = (relu(bn(L)) - mean[cl]) @ w_W[i] -> B1 in place (bf16), global max
        gemm_one<83><<<gemmGrid, 256, 0, stream>>>(B1, nullptr, wT + (size_t)i * 16384, B1,
            cli, S1, invc + i * NSEG_, ss, ss + 128, nullptr, nullptr, qmax + i);
        // s3 = seg_sum(relu(bn(P)) * softmax-ratio)  (s2 computed in-block)
        gather_s23<<<NSEG_, 256, 0, stream>>>(B1, B2, stp, stp + 128, proj_g + i * CH, proj_b + i * CH,
            qmax + i, permi, offi, cnti, s3 + (size_t)i * SEG);
    }

    // agg -> B3
    adpagg_kernel<<<aggGrid, 256, 0, stream>>>(B0, adp_W,
        clusters, clusters + NPTS, clusters + 2 * (size_t)NPTS,
        s3, s3 + SEG, s3 + 2 * SEG, B3);

    // P3 -> B2, stats6
    {
        float* st = stats + 6 * 256; float* ss = scsh + 6 * 256;
        gemm_one<72><<<gemmGrid, 256, 0, stream>>>(B0, nullptr, projT + 3 * (size_t)16384, B2,
            nullptr, nullptr, nullptr, nullptr, nullptr, st, st + 128, nullptr);
        finalize_kernel<<<1, 128, 0, stream>>>(st, st + 128, proj_g + 3 * CH, proj_b + 3 * CH, ss, ss + 128);
    }
    // fuseY = [relu(bn(P3)), agg] @ fuse_W -> B1, stats7   (K256|ABN|STATS|CBF = 106)
    {
        float* st = stats + 7 * 256;
        gemm_one<106><<<gemmGrid, 256, 0, stream>>>(B2, B3, fuseT, B1,
            nullptr, nullptr, nullptr, scsh + 6 * 256, scsh + 6 * 256 + 128, st, st + 128, nullptr);
    }
    // fused = relu(bn(fuseY)) + featB -> B2
    fused_kernel<<<mapGrid, 256, 0, stream>>>(B1, stats + 7 * 256, stats + 7 * 256 + 128,
        fuse_g, fuse_b, B0, B2);

    // conv1: B2 -> B3, stats8
    conv_kernel<false><<<convGrid, 512, 0, stream>>>(B2, conv1_W, nidx,
        nullptr, nullptr, nullptr, nullptr, B3, stats + 8 * 256, stats + 8 * 256 + 128);
    // conv2: bn1(B3) -> B1, stats9 (bn inlined from stats8)
    conv_kernel<true><<<convGrid, 512, 0, stream>>>(B3, conv2_W, nidx,
        stats + 8 * 256, stats + 8 * 256 + 128, norm1_g, norm1_b,
        B1, stats + 9 * 256, stats + 9 * 256 + 128);
    // out = relu(bn2(B1) + B2)
    final_kernel<<<mapGrid, 256, 0, stream>>>(B1, stats + 9 * 256, stats + 9 * 256 + 128,
        norm2_g, norm2_b, B2, out);
}

// Round 7
// 1117.508 us; speedup vs baseline: 3.4714x; 1.1909x over previous
//
#include <hip/hip_runtime.h>
#include <math.h>

#define NPTS 150000
#define CH   128
#define NSEG_ 4096
#define KOFF 27
#define BN_EPS 1e-5f

typedef __attribute__((ext_vector_type(8))) short bf16x8;
typedef __attribute__((ext_vector_type(4))) float f32x4;

// ---------- helpers ----------
__device__ __forceinline__ unsigned int fenc(float f) {
    unsigned int b = __float_as_uint(f);
    return (b & 0x80000000u) ? ~b : (b | 0x80000000u);
}
__device__ __forceinline__ float fdec(unsigned int u) {
    return __uint_as_float((u & 0x80000000u) ? (u & 0x7fffffffu) : ~u);
}
__device__ __forceinline__ unsigned short f2bf(float f) {
    unsigned int u = __float_as_uint(f);
    unsigned int r = (u + 0x7fffu + ((u >> 16) & 1u)) >> 16;
    return (unsigned short)r;
}
__device__ __forceinline__ float bf2f(unsigned short h) {
    return __uint_as_float(((unsigned int)h) << 16);
}
__device__ __forceinline__ float blo(unsigned int u) { return __uint_as_float(u << 16); }
__device__ __forceinline__ float bhi(unsigned int u) { return __uint_as_float(u & 0xffff0000u); }
__device__ __forceinline__ unsigned int pk2(float a, float b) {
    return (unsigned int)f2bf(a) | ((unsigned int)f2bf(b) << 16);
}
__device__ __forceinline__ int xcd_swz(int bid, int nwg) {
    int q = nwg >> 3, r = nwg & 7;
    int xcd = bid & 7, idx = bid >> 3;
    return (xcd < r ? xcd * (q + 1) : r * (q + 1) + (xcd - r) * q) + idx;
}

__global__ void zero_kernel(float4* __restrict__ p, int n4) {
    for (int i = blockIdx.x * 256 + threadIdx.x; i < n4; i += gridDim.x * 256)
        p[i] = make_float4(0.f, 0.f, 0.f, 0.f);
}

__global__ void cvt_bf16(const float* __restrict__ in, unsigned short* __restrict__ o, int n8) {
    for (int i = blockIdx.x * 256 + threadIdx.x; i < n8; i += gridDim.x * 256) {
        float4 a = *(const float4*)(in + (size_t)i * 8);
        float4 b = *(const float4*)(in + (size_t)i * 8 + 4);
        uint4 w;
        w.x = pk2(a.x, a.y); w.y = pk2(a.z, a.w);
        w.z = pk2(b.x, b.y); w.w = pk2(b.z, b.w);
        *(uint4*)(o + (size_t)i * 8) = w;
    }
}

__global__ void wtr_all(const float* __restrict__ lw, const float* __restrict__ w,
                        const float* __restrict__ proj, const float* __restrict__ fuse,
                        unsigned short* __restrict__ Wt)
{
    int i = blockIdx.x * 256 + threadIdx.x;
    if (i < 10 * 16384) {
        int u = i >> 14, r = i & 16383;
        int n = r >> 7, k = r & 127;
        const float* src = (u < 3) ? lw + (size_t)u * 16384
                         : (u < 6) ? w + (size_t)(u - 3) * 16384
                                   : proj + (size_t)(u - 6) * 16384;
        Wt[(size_t)u * 16384 + n * 128 + k] = f2bf(src[(size_t)k * 128 + n]);
    } else if (i < 10 * 16384 + 32768) {
        int r = i - 10 * 16384;
        int n = r >> 8, k = r & 255;
        Wt[10 * 16384 + (size_t)n * 256 + k] = f2bf(fuse[(size_t)k * 128 + n]);
    }
}

// compact valid neighbors: pk[n*27+e] = (k<<18)|idx, pcnt[n] = count
__global__ void compact_nidx(const int* __restrict__ nidx, int* __restrict__ pk, int* __restrict__ pcnt) {
    int p = blockIdx.x * 256 + threadIdx.x;
    if (p < NPTS) {
        int c = 0;
        const int* row = nidx + (size_t)p * KOFF;
        int* orow = pk + (size_t)p * KOFF;
#pragma unroll
        for (int k = 0; k < KOFF; ++k) {
            int idx = row[k];
            if (idx >= 0) orow[c++] = (k << 18) | idx;
        }
        pcnt[p] = c;
    }
}

// ---------- shared GEMM epilogue ----------
template<bool CBF, bool STATS, bool MAXRED>
__device__ __forceinline__ void gemm_epi(
    f32x4 (&acc)[4][4], void* Cv, int R, int C0, int lc, int lk, int w, int t,
    float (*reds)[4][16], float (*redq)[4][16],
    float* colsum, float* colsq, unsigned int* gmax)
{
    float* Cf = (float*)Cv;
    unsigned short* Chh = (unsigned short*)Cv;
    float s[4] = {0.f, 0.f, 0.f, 0.f}, q[4] = {0.f, 0.f, 0.f, 0.f};
    unsigned int lmax = 0u;
#pragma unroll
    for (int mi = 0; mi < 4; ++mi) {
#pragma unroll
        for (int r = 0; r < 4; ++r) {
            int row = R + mi * 16 + lk * 4 + r;
            if (row < NPTS) {
#pragma unroll
                for (int ni = 0; ni < 4; ++ni) {
                    float v = acc[mi][ni][r];
                    int col = C0 + ni * 16 + lc;
                    if constexpr (CBF) {
                        unsigned short hb = f2bf(v);
                        Chh[(size_t)row * CH + col] = hb;
                        if constexpr (MAXRED) { unsigned int e = fenc(bf2f(hb)); if (e > lmax) lmax = e; }
                    } else {
                        Cf[(size_t)row * CH + col] = v;
                        if constexpr (MAXRED) { unsigned int e = fenc(v); if (e > lmax) lmax = e; }
                    }
                    if constexpr (STATS) { s[ni] += v; q[ni] += v * v; }
                }
            }
        }
    }
    if constexpr (STATS) {
#pragma unroll
        for (int ni = 0; ni < 4; ++ni) {
            s[ni] += __shfl_xor(s[ni], 16); s[ni] += __shfl_xor(s[ni], 32);
            q[ni] += __shfl_xor(q[ni], 16); q[ni] += __shfl_xor(q[ni], 32);
        }
        __syncthreads();
        if (lk == 0) {
#pragma unroll
            for (int ni = 0; ni < 4; ++ni) { reds[w][ni][lc] = s[ni]; redq[w][ni][lc] = q[ni]; }
        }
        __syncthreads();
        if (t < 128) {
            int half = t >> 6, fr = (t >> 4) & 3, cc = t & 15;
            atomicAdd(colsum + t, reds[half][fr][cc] + reds[half + 2][fr][cc]);
            atomicAdd(colsq  + t, redq[half][fr][cc] + redq[half + 2][fr][cc]);
        }
    }
    if constexpr (MAXRED) {
#pragma unroll
        for (int d = 1; d < 64; d <<= 1) {
            unsigned int o = __shfl_xor(lmax, d);
            if (o > lmax) lmax = o;
        }
        if ((t & 63) == 0) atomicMax(gmax, lmax);
    }
}

// ---------- dual GEMM ----------
__global__ __launch_bounds__(256) void gemm_dual(
    const unsigned short* __restrict__ A,
    const unsigned short* __restrict__ W1t, const unsigned short* __restrict__ W2t,
    unsigned short* __restrict__ C1, unsigned short* __restrict__ C2,
    float* __restrict__ st1, float* __restrict__ st2)
{
    __shared__ float reds[4][4][16], redq[4][4][16];
    const int t  = threadIdx.x;
    const int l  = t & 63, w = t >> 6;
    const int lc = l & 15, lk = l >> 4;
    const int wr = w >> 1, wc = w & 1;
    const int bid = xcd_swz((int)blockIdx.x, (int)gridDim.x);
    const int R  = bid * 128 + wr * 64;
    const int C0 = wc * 64;

    int rowm[4];
#pragma unroll
    for (int mi = 0; mi < 4; ++mi) {
        int r = R + mi * 16 + lc;
        rowm[mi] = r < NPTS ? r : NPTS - 1;
    }
    bf16x8 a[4][4];
#pragma unroll
    for (int ks = 0; ks < 4; ++ks)
#pragma unroll
        for (int mi = 0; mi < 4; ++mi)
            a[ks][mi] = *(const bf16x8*)(A + (size_t)rowm[mi] * CH + ks * 32 + lk * 8);

    f32x4 acc[4][4];
#pragma unroll
    for (int mi = 0; mi < 4; ++mi)
#pragma unroll
        for (int ni = 0; ni < 4; ++ni) acc[mi][ni] = (f32x4){0.f, 0.f, 0.f, 0.f};
#pragma unroll
    for (int ks = 0; ks < 4; ++ks) {
        bf16x8 b[4];
#pragma unroll
        for (int ni = 0; ni < 4; ++ni)
            b[ni] = *(const bf16x8*)(W1t + (size_t)(C0 + ni * 16 + lc) * 128 + ks * 32 + lk * 8);
#pragma unroll
        for (int mi = 0; mi < 4; ++mi)
#pragma unroll
            for (int ni = 0; ni < 4; ++ni)
                acc[mi][ni] = __builtin_amdgcn_mfma_f32_16x16x32_bf16(a[ks][mi], b[ni], acc[mi][ni], 0, 0, 0);
    }
    gemm_epi<true, true, false>(acc, C1, R, C0, lc, lk, w, t, reds, redq, st1, st1 + 128, nullptr);

#pragma unroll
    for (int mi = 0; mi < 4; ++mi)
#pragma unroll
        for (int ni = 0; ni < 4; ++ni) acc[mi][ni] = (f32x4){0.f, 0.f, 0.f, 0.f};
#pragma unroll
    for (int ks = 0; ks < 4; ++ks) {
        bf16x8 b[4];
#pragma unroll
        for (int ni = 0; ni < 4; ++ni)
            b[ni] = *(const bf16x8*)(W2t + (size_t)(C0 + ni * 16 + lc) * 128 + ks * 32 + lk * 8);
#pragma unroll
        for (int mi = 0; mi < 4; ++mi)
#pragma unroll
            for (int ni = 0; ni < 4; ++ni)
                acc[mi][ni] = __builtin_amdgcn_mfma_f32_16x16x32_bf16(a[ks][mi], b[ni], acc[mi][ni], 0, 0, 0);
    }
    gemm_epi<true, true, false>(acc, C2, R, C0, lc, lk, w, t, reds, redq, st2, st2 + 128, nullptr);
}

// ---------- single GEMM with transforms ----------
// FLAGS: 1=ACEN, 2=ABN, 8=STATS, 16=MAXRED, 32=K256, 64=CBF
template<int FLAGS>
__global__ __launch_bounds__(256) void gemm_one(
    const unsigned short* A0, const unsigned short* A1,
    const unsigned short* __restrict__ Wt, void* Cv,
    const int* __restrict__ cl, const float* __restrict__ seg, const float* __restrict__ invcnt,
    const float* __restrict__ bnsc, const float* __restrict__ bnsh,
    float* __restrict__ colsum, float* __restrict__ colsq, unsigned int* __restrict__ gmax)
{
    constexpr bool ACEN   = (FLAGS & 1)  != 0;
    constexpr bool ABN    = (FLAGS & 2)  != 0;
    constexpr bool STATS  = (FLAGS & 8)  != 0;
    constexpr bool MAXRED = (FLAGS & 16) != 0;
    constexpr bool K256   = (FLAGS & 32) != 0;
    constexpr bool CBF    = (FLAGS & 64) != 0;
    constexpr int  KW = K256 ? 256 : 128;
    constexpr int  NH = K256 ? 2 : 1;

    __shared__ float reds[4][4][16], redq[4][4][16];
    const int t  = threadIdx.x;
    const int l  = t & 63, w = t >> 6;
    const int lc = l & 15, lk = l >> 4;
    const int wr = w >> 1, wc = w & 1;
    const int bid = xcd_swz((int)blockIdx.x, (int)gridDim.x);
    const int R  = bid * 128 + wr * 64;
    const int C0 = wc * 64;

    int rowm[4];
#pragma unroll
    for (int mi = 0; mi < 4; ++mi) {
        int r = R + mi * 16 + lc;
        rowm[mi] = r < NPTS ? r : NPTS - 1;
    }
    int sg4[4]; float ic4[4];
    if constexpr (ACEN) {
#pragma unroll
        for (int mi = 0; mi < 4; ++mi) { sg4[mi] = cl[rowm[mi]]; ic4[mi] = invcnt[sg4[mi]]; }
    }

    f32x4 acc[4][4];
#pragma unroll
    for (int mi = 0; mi < 4; ++mi)
#pragma unroll
        for (int ni = 0; ni < 4; ++ni) acc[mi][ni] = (f32x4){0.f, 0.f, 0.f, 0.f};

#pragma unroll
    for (int hh = 0; hh < NH; ++hh) {
        const unsigned short* Asrc = (K256 && hh) ? A1 : A0;
        bf16x8 a[4][4];
#pragma unroll
        for (int ks = 0; ks < 4; ++ks)
#pragma unroll
            for (int mi = 0; mi < 4; ++mi)
                a[ks][mi] = *(const bf16x8*)(Asrc + (size_t)rowm[mi] * CH + ks * 32 + lk * 8);

        if constexpr (ABN || ACEN) {
            if (hh == 0) {
#pragma unroll
                for (int ks = 0; ks < 4; ++ks) {
                    const int kb = ks * 32 + lk * 8;
                    float4 s0, s1v, h0, h1;
                    if constexpr (ABN) {
                        s0  = *(const float4*)(bnsc + kb); s1v = *(const float4*)(bnsc + kb + 4);
                        h0  = *(const float4*)(bnsh + kb); h1  = *(const float4*)(bnsh + kb + 4);
                    }
#pragma unroll
                    for (int mi = 0; mi < 4; ++mi) {
                        union { unsigned short u[8]; bf16x8 v; } pk;
                        pk.v = a[ks][mi];
                        float v[8];
#pragma unroll
                        for (int e = 0; e < 8; ++e) v[e] = bf2f(pk.u[e]);
                        if constexpr (ABN) {
                            v[0] = fmaxf(v[0] * s0.x + h0.x, 0.f);  v[1] = fmaxf(v[1] * s0.y + h0.y, 0.f);
                            v[2] = fmaxf(v[2] * s0.z + h0.z, 0.f);  v[3] = fmaxf(v[3] * s0.w + h0.w, 0.f);
                            v[4] = fmaxf(v[4] * s1v.x + h1.x, 0.f); v[5] = fmaxf(v[5] * s1v.y + h1.y, 0.f);
                            v[6] = fmaxf(v[6] * s1v.z + h1.z, 0.f); v[7] = fmaxf(v[7] * s1v.w + h1.w, 0.f);
                        }
                        if constexpr (ACEN) {
                            const float* sp = seg + (size_t)sg4[mi] * CH + kb;
                            float4 m0 = *(const float4*)sp, m1 = *(const float4*)(sp + 4);
                            float ic = ic4[mi];
                            v[0] -= m0.x * ic; v[1] -= m0.y * ic; v[2] -= m0.z * ic; v[3] -= m0.w * ic;
                            v[4] -= m1.x * ic; v[5] -= m1.y * ic; v[6] -= m1.z * ic; v[7] -= m1.w * ic;
                        }
#pragma unroll
                        for (int e = 0; e < 8; ++e) pk.u[e] = f2bf(v[e]);
                        a[ks][mi] = pk.v;
                    }
                }
            }
        }
#pragma unroll
        for (int ks = 0; ks < 4; ++ks) {
            bf16x8 b[4];
#pragma unroll
            for (int ni = 0; ni < 4; ++ni)
                b[ni] = *(const bf16x8*)(Wt + (size_t)(C0 + ni * 16 + lc) * KW + hh * 128 + ks * 32 + lk * 8);
#pragma unroll
            for (int mi = 0; mi < 4; ++mi)
#pragma unroll
                for (int ni = 0; ni < 4; ++ni)
                    acc[mi][ni] = __builtin_amdgcn_mfma_f32_16x16x32_bf16(a[ks][mi], b[ni], acc[mi][ni], 0, 0, 0);
        }
    }
    gemm_epi<CBF, STATS, MAXRED>(acc, Cv, R, C0, lc, lk, w, t, reds, redq, colsum, colsq, gmax);
}

// ---------- CSR build ----------
__global__ void count_kernel(const int* __restrict__ clusters, int* __restrict__ cnt) {
    const int tot = 3 * NPTS;
    for (int f = blockIdx.x * 256 + threadIdx.x; f < tot; f += gridDim.x * 256) {
        int i = f / NPTS;
        atomicAdd(cnt + i * NSEG_ + clusters[f], 1);
    }
}

__global__ void invcnt_kernel(const int* __restrict__ cnt, float* __restrict__ invc) {
    int x = blockIdx.x * 256 + threadIdx.x;
    if (x < 3 * NSEG_) {
        int c = cnt[x];
        invc[x] = 1.0f / (float)(c > 1 ? c : 1);
    }
}

__global__ __launch_bounds__(1024) void scan_kernel(const int* __restrict__ cnt, int* __restrict__ off) {
    __shared__ int tot[1024];
    const int L = blockIdx.x;
    const int* c = cnt + L * NSEG_;
    int* o = off + L * NSEG_;
    const int t = threadIdx.x;
    int v[4];
    int s = 0;
#pragma unroll
    for (int j = 0; j < 4; ++j) { v[j] = s; s += c[t * 4 + j]; }
    tot[t] = s;
    __syncthreads();
    for (int d = 1; d < 1024; d <<= 1) {
        int x = (t >= d) ? tot[t - d] : 0;
        __syncthreads();
        tot[t] += x;
        __syncthreads();
    }
    int pre = (t == 0) ? 0 : tot[t - 1];
#pragma unroll
    for (int j = 0; j < 4; ++j) o[t * 4 + j] = pre + v[j];
}

__global__ void fill_kernel(const int* __restrict__ clusters, const int* __restrict__ off,
                            int* __restrict__ fpos, int* __restrict__ perm) {
    const int tot = 3 * NPTS;
    for (int f = blockIdx.x * 256 + threadIdx.x; f < tot; f += gridDim.x * 256) {
        int i = f / NPTS;
        int n = f - i * NPTS;
        int s = i * NSEG_ + clusters[f];
        int pos = off[s] + atomicAdd(fpos + s, 1);
        perm[(size_t)i * NPTS + pos] = n;
    }
}

// ---------- s1 = seg_sum(relu(bn(L))), 4ch/lane, 8 rows in flight ----------
__global__ __launch_bounds__(256) void gather_s1(
    const unsigned short* __restrict__ L,
    const float* __restrict__ cs, const float* __restrict__ cq,
    const float* __restrict__ g, const float* __restrict__ b,
    const int* __restrict__ perm, const int* __restrict__ off, const int* __restrict__ cnt,
    float* __restrict__ segout)
{
    __shared__ float red[8][132];
    const int s = blockIdx.x;
    const int t = threadIdx.x;
    const int c4 = (t & 31) * 4, h = t >> 5;
    const int start = off[s], m = cnt[s];
    float4 cs4 = *(const float4*)(cs + c4);
    float4 cq4 = *(const float4*)(cq + c4);
    float4 g4  = *(const float4*)(g + c4);
    float4 b4  = *(const float4*)(b + c4);
    float m0 = cs4.x / (float)NPTS, m1 = cs4.y / (float)NPTS,
          m2 = cs4.z / (float)NPTS, m3 = cs4.w / (float)NPTS;
    float sc0 = rsqrtf(cq4.x / (float)NPTS - m0 * m0 + BN_EPS) * g4.x;
    float sc1 = rsqrtf(cq4.y / (float)NPTS - m1 * m1 + BN_EPS) * g4.y;
    float sc2 = rsqrtf(cq4.z / (float)NPTS - m2 * m2 + BN_EPS) * g4.z;
    float sc3 = rsqrtf(cq4.w / (float)NPTS - m3 * m3 + BN_EPS) * g4.w;
    float sh0 = b4.x - m0 * sc0, sh1 = b4.y - m1 * sc1;
    float sh2 = b4.z - m2 * sc2, sh3 = b4.w - m3 * sc3;

    float a0 = 0.f, a1 = 0.f, a2 = 0.f, a3 = 0.f;
    for (int j = h; j < m; j += 8) {
        int p = perm[start + j];
        uint2 rw = *(const uint2*)(L + (size_t)p * CH + c4);
        a0 += fmaxf(blo(rw.x) * sc0 + sh0, 0.f);
        a1 += fmaxf(bhi(rw.x) * sc1 + sh1, 0.f);
        a2 += fmaxf(blo(rw.y) * sc2 + sh2, 0.f);
        a3 += fmaxf(bhi(rw.y) * sc3 + sh3, 0.f);
    }
    *(float4*)&red[h][c4] = make_float4(a0, a1, a2, a3);
    __syncthreads();
    if (t < 128) {
        float tot = 0.f;
#pragma unroll
        for (int r = 0; r < 8; ++r) tot += red[r][t];
        segout[(size_t)s * CH + t] = tot;
    }
}

// ---------- single-pass s3: accE = sum(e), accS = sum(pf*e); s3 = accS/(accE+eps) ----------
__global__ __launch_bounds__(256) void gather_s23(
    const unsigned short* __restrict__ Q, const unsigned short* __restrict__ P,
    const float* __restrict__ cs, const float* __restrict__ cq,
    const float* __restrict__ g, const float* __restrict__ b,
    const unsigned int* __restrict__ gmax,
    const int* __restrict__ perm, const int* __restrict__ off, const int* __restrict__ cnt,
    float* __restrict__ s3out)
{
    __shared__ float red[8][132];
    const int s = blockIdx.x;
    const int t = threadIdx.x;
    const int c4 = (t & 31) * 4, h = t >> 5;
    const int start = off[s], m = cnt[s];
    const float mx = fdec(*gmax);
    float4 cs4 = *(const float4*)(cs + c4);
    float4 cq4 = *(const float4*)(cq + c4);
    float4 g4  = *(const float4*)(g + c4);
    float4 b4  = *(const float4*)(b + c4);
    float m0 = cs4.x / (float)NPTS, m1 = cs4.y / (float)NPTS,
          m2 = cs4.z / (float)NPTS, m3 = cs4.w / (float)NPTS;
    float sc0 = rsqrtf(cq4.x / (float)NPTS - m0 * m0 + BN_EPS) * g4.x;
    float sc1 = rsqrtf(cq4.y / (float)NPTS - m1 * m1 + BN_EPS) * g4.y;
    float sc2 = rsqrtf(cq4.z / (float)NPTS - m2 * m2 + BN_EPS) * g4.z;
    float sc3 = rsqrtf(cq4.w / (float)NPTS - m3 * m3 + BN_EPS) * g4.w;
    float sh0 = b4.x - m0 * sc0, sh1 = b4.y - m1 * sc1;
    float sh2 = b4.z - m2 * sc2, sh3 = b4.w - m3 * sc3;

    float e0 = 0.f, e1 = 0.f, e2 = 0.f, e3 = 0.f;
    float s0 = 0.f, s1 = 0.f, s2 = 0.f, s3 = 0.f;
    for (int j = h; j < m; j += 8) {
        int p = perm[start + j];
        uint2 qw = *(const uint2*)(Q + (size_t)p * CH + c4);
        uint2 pw = *(const uint2*)(P + (size_t)p * CH + c4);
        float ex0 = expf(blo(qw.x) - mx), ex1 = expf(bhi(qw.x) - mx);
        float ex2 = expf(blo(qw.y) - mx), ex3 = expf(bhi(qw.y) - mx);
        e0 += ex0; e1 += ex1; e2 += ex2; e3 += ex3;
        s0 += fmaxf(blo(pw.x) * sc0 + sh0, 0.f) * ex0;
        s1 += fmaxf(bhi(pw.x) * sc1 + sh1, 0.f) * ex1;
        s2 += fmaxf(blo(pw.y) * sc2 + sh2, 0.f) * ex2;
        s3 += fmaxf(bhi(pw.y) * sc3 + sh3, 0.f) * ex3;
    }
    *(float4*)&red[h][c4] = make_float4(e0, e1, e2, e3);
    __syncthreads();
    float etot = 0.f;
    if (t < 128) {
#pragma unroll
        for (int r = 0; r < 8; ++r) etot += red[r][t];
    }
    __syncthreads();
    *(float4*)&red[h][c4] = make_float4(s0, s1, s2, s3);
    __syncthreads();
    if (t < 128) {
        float stot = 0.f;
#pragma unroll
        for (int r = 0; r < 8; ++r) stot += red[r][t];
        s3out[(size_t)s * CH + t] = stot / (etot + 1e-6f);
    }
}

// ---------- finalize ----------
__global__ void finalize_kernel(const float* __restrict__ colsum, const float* __restrict__ colsq,
                                const float* __restrict__ g, const float* __restrict__ b,
                                float* __restrict__ sc, float* __restrict__ sh)
{
    int c = threadIdx.x;
    float mean = colsum[c] / (float)NPTS;
    float var  = colsq[c] / (float)NPTS - mean * mean;
    float istd = rsqrtf(var + BN_EPS);
    float s = istd * g[c];
    sc[c] = s;
    sh[c] = b[c] - mean * s;
}

// ---------- adp softmax + agg ----------
__global__ __launch_bounds__(256) void adpagg_kernel(
    const unsigned short* __restrict__ featB, const float* __restrict__ adpW,
    const int* __restrict__ cl0, const int* __restrict__ cl1, const int* __restrict__ cl2,
    const float* __restrict__ s30, const float* __restrict__ s31, const float* __restrict__ s32,
    unsigned short* __restrict__ agg)
{
    __shared__ float ftile[64][132];
    __shared__ float wl[128][3];
    __shared__ float pr[64][3];
    __shared__ int   cls[64][3];
    const int t = threadIdx.x;
    const int n0 = blockIdx.x * 64;

    if (t < 128) { wl[t][0] = adpW[t * 3]; wl[t][1] = adpW[t * 3 + 1]; wl[t][2] = adpW[t * 3 + 2]; }
#pragma unroll
    for (int h = 0; h < 4; ++h) {
        int f = t + h * 256;
        int r = f >> 4, c8 = (f & 15) * 8;
        int n = n0 + r;
        if (n < NPTS) {
            uint4 rw = *(const uint4*)(featB + (size_t)n * CH + c8);
            ftile[r][c8 + 0] = blo(rw.x); ftile[r][c8 + 1] = bhi(rw.x);
            ftile[r][c8 + 2] = blo(rw.y); ftile[r][c8 + 3] = bhi(rw.y);
            ftile[r][c8 + 4] = blo(rw.z); ftile[r][c8 + 5] = bhi(rw.z);
            ftile[r][c8 + 6] = blo(rw.w); ftile[r][c8 + 7] = bhi(rw.w);
        } else {
#pragma unroll
            for (int e = 0; e < 8; ++e) ftile[r][c8 + e] = 0.f;
        }
    }
    if (t < 64) {
        int n = n0 + t;
        if (n < NPTS) { cls[t][0] = cl0[n]; cls[t][1] = cl1[n]; cls[t][2] = cl2[n]; }
        else { cls[t][0] = 0; cls[t][1] = 0; cls[t][2] = 0; }
    }
    __syncthreads();

    if (t < 64) {
        float p0 = 0.f, p1 = 0.f, p2 = 0.f;
        for (int k = 0; k < 128; ++k) {
            float fv = ftile[t][k];
            p0 += fv * wl[k][0]; p1 += fv * wl[k][1]; p2 += fv * wl[k][2];
        }
        float m = fmaxf(p0, fmaxf(p1, p2));
        float e0 = expf(p0 - m), e1 = expf(p1 - m), e2 = expf(p2 - m);
        float inv = 1.f / (e0 + e1 + e2);
        pr[t][0] = e0 * inv; pr[t][1] = e1 * inv; pr[t][2] = e2 * inv;
    }
    __syncthreads();

#pragma unroll
    for (int h = 0; h < 8; ++h) {
        int f = t + h * 256;
        int r = f >> 5, c4 = (f & 31) << 2;
        int n = n0 + r;
        if (n < NPTS) {
            float a0 = pr[r][0], a1 = pr[r][1], a2 = pr[r][2];
            float4 v0 = *(const float4*)(s30 + (size_t)cls[r][0] * CH + c4);
            float4 v1 = *(const float4*)(s31 + (size_t)cls[r][1] * CH + c4);
            float4 v2 = *(const float4*)(s32 + (size_t)cls[r][2] * CH + c4);
            float ox = a0 * v0.x + a1 * v1.x + a2 * v2.x;
            float oy = a0 * v0.y + a1 * v1.y + a2 * v2.y;
            float oz = a0 * v0.z + a1 * v1.z + a2 * v2.z;
            float ow = a0 * v0.w + a1 * v1.w + a2 * v2.w;
            uint2 wv; wv.x = pk2(ox, oy); wv.y = pk2(oz, ow);
            *(uint2*)(agg + (size_t)n * CH + c4) = wv;
        }
    }
}

// ---------- fused = relu(bn(fuseY)) + featB ----------
__global__ void fused_kernel(const unsigned short* __restrict__ fY,
                             const float* __restrict__ cs, const float* __restrict__ cq,
                             const float* __restrict__ g, const float* __restrict__ b,
                             const unsigned short* __restrict__ featB, unsigned short* __restrict__ outB)
{
    const int tot = NPTS * 32;
    for (int f = blockIdx.x * 256 + threadIdx.x; f < tot; f += gridDim.x * 256) {
        int n = f >> 5, c4 = (f & 31) << 2;
        float4 cs4 = *(const float4*)(cs + c4);
        float4 cq4 = *(const float4*)(cq + c4);
        float4 g4  = *(const float4*)(g + c4);
        float4 b4  = *(const float4*)(b + c4);
        float mx0 = cs4.x / (float)NPTS, mx1 = cs4.y / (float)NPTS,
              mx2 = cs4.z / (float)NPTS, mx3 = cs4.w / (float)NPTS;
        float sc0 = rsqrtf(cq4.x / (float)NPTS - mx0 * mx0 + BN_EPS) * g4.x;
        float sc1 = rsqrtf(cq4.y / (float)NPTS - mx1 * mx1 + BN_EPS) * g4.y;
        float sc2 = rsqrtf(cq4.z / (float)NPTS - mx2 * mx2 + BN_EPS) * g4.z;
        float sc3 = rsqrtf(cq4.w / (float)NPTS - mx3 * mx3 + BN_EPS) * g4.w;
        float sh0 = b4.x - mx0 * sc0, sh1 = b4.y - mx1 * sc1;
        float sh2 = b4.z - mx2 * sc2, sh3 = b4.w - mx3 * sc3;
        uint2 y2 = *(const uint2*)(fY + (size_t)n * CH + c4);
        uint2 f2 = *(const uint2*)(featB + (size_t)n * CH + c4);
        float o0 = fmaxf(blo(y2.x) * sc0 + sh0, 0.f) + blo(f2.x);
        float o1 = fmaxf(bhi(y2.x) * sc1 + sh1, 0.f) + bhi(f2.x);
        float o2 = fmaxf(blo(y2.y) * sc2 + sh2, 0.f) + blo(f2.y);
        float o3 = fmaxf(bhi(y2.y) * sc3 + sh3, 0.f) + bhi(f2.y);
        uint2 wv; wv.x = pk2(o0, o1); wv.y = pk2(o2, o3);
        *(uint2*)(outB + (size_t)n * CH + c4) = wv;
    }
}

// ---------- sparse grouped conv: compacted neighbor list (avg ~1.24 valid of 27) ----------
template<bool INBN>
__global__ __launch_bounds__(512) void conv_kernel(
    const unsigned short* __restrict__ X, const float* __restrict__ Wc,
    const int* __restrict__ pk, const int* __restrict__ pcnt,
    const float* __restrict__ csIn, const float* __restrict__ cqIn,
    const float* __restrict__ gIn, const float* __restrict__ bIn,
    unsigned short* __restrict__ Y, float* __restrict__ colsum, float* __restrict__ colsq)
{
    __shared__ unsigned short Wh[KOFF * 4 * 128];  // 27648 B
    __shared__ float red[16 * 128];                // 8192 B
    __shared__ int   cntl[128];
    __shared__ float bnp[256];

    const int t = threadIdx.x;
    const int g = t & 31, ps = t >> 5;
    const int bid = xcd_swz((int)blockIdx.x, (int)gridDim.x);
    const int n0 = bid * 128;

    for (int f = t; f < KOFF * 512; f += 512) {
        int k = f >> 9, rem = f & 511;
        int gg = rem >> 4, ii = (rem >> 2) & 3, oo = rem & 3;
        Wh[(k * 4 + ii) * 128 + gg * 4 + oo] = f2bf(Wc[f]);
    }
    if (t < 128) {
        int n = n0 + t;
        cntl[t] = (n < NPTS) ? pcnt[n] : 0;
    }
    if (INBN && t < 128) {
        float mean = csIn[t] / (float)NPTS;
        float var  = cqIn[t] / (float)NPTS - mean * mean;
        float sc = rsqrtf(var + BN_EPS) * gIn[t];
        bnp[t] = sc; bnp[128 + t] = bIn[t] - mean * sc;
    }
    __syncthreads();

    float4 bs4 = make_float4(1.f, 1.f, 1.f, 1.f), bh4 = make_float4(0.f, 0.f, 0.f, 0.f);
    if (INBN) { bs4 = *(float4*)&bnp[g * 4]; bh4 = *(float4*)&bnp[128 + g * 4]; }

    float acc[8][4];
#pragma unroll
    for (int j = 0; j < 8; ++j)
#pragma unroll
        for (int o = 0; o < 4; ++o) acc[j][o] = 0.f;

#pragma unroll
    for (int j = 0; j < 8; ++j) {
        int p = ps * 8 + j;
        int n = n0 + p;
        int m = cntl[p];
        for (int e = 0; e < m; ++e) {
            int ent = pk[(size_t)n * KOFF + e];    // broadcast across the 32-lane group
            int k = ent >> 18, idx = ent & 0x3FFFF;
            uint2 u0 = *(const uint2*)&Wh[(k * 4 + 0) * 128 + g * 4];
            uint2 u1 = *(const uint2*)&Wh[(k * 4 + 1) * 128 + g * 4];
            uint2 u2 = *(const uint2*)&Wh[(k * 4 + 2) * 128 + g * 4];
            uint2 u3 = *(const uint2*)&Wh[(k * 4 + 3) * 128 + g * 4];
            uint2 rw = *(const uint2*)(X + (size_t)idx * CH + g * 4);
            float vx = blo(rw.x), vy = bhi(rw.x), vz = blo(rw.y), vw = bhi(rw.y);
            if (INBN) {
                vx = vx * bs4.x + bh4.x; vy = vy * bs4.y + bh4.y;
                vz = vz * bs4.z + bh4.z; vw = vw * bs4.w + bh4.w;
            }
            acc[j][0] += vx * blo(u0.x) + vy * blo(u1.x) + vz * blo(u2.x) + vw * blo(u3.x);
            acc[j][1] += vx * bhi(u0.x) + vy * bhi(u1.x) + vz * bhi(u2.x) + vw * bhi(u3.x);
            acc[j][2] += vx * blo(u0.y) + vy * blo(u1.y) + vz * blo(u2.y) + vw * blo(u3.y);
            acc[j][3] += vx * bhi(u0.y) + vy * bhi(u1.y) + vz * bhi(u2.y) + vw * bhi(u3.y);
        }
    }

    float s[4] = {0.f, 0.f, 0.f, 0.f}, q[4] = {0.f, 0.f, 0.f, 0.f};
#pragma unroll
    for (int j = 0; j < 8; ++j) {
        int n = n0 + ps * 8 + j;
        if (n < NPTS) {
            uint2 wv; wv.x = pk2(acc[j][0], acc[j][1]); wv.y = pk2(acc[j][2], acc[j][3]);
            *(uint2*)(Y + (size_t)n * CH + g * 4) = wv;
            s[0] += acc[j][0]; s[1] += acc[j][1]; s[2] += acc[j][2]; s[3] += acc[j][3];
            q[0] += acc[j][0] * acc[j][0]; q[1] += acc[j][1] * acc[j][1];
            q[2] += acc[j][2] * acc[j][2]; q[3] += acc[j][3] * acc[j][3];
        }
    }
    __syncthreads();
    *(float4*)&red[ps * 128 + g * 4] = make_float4(s[0], s[1], s[2], s[3]);
    __syncthreads();
    if (t < 128) {
        float tot = 0.f;
#pragma unroll
        for (int r = 0; r < 16; ++r) tot += red[r * 128 + t];
        atomicAdd(colsum + t, tot);
    }
    __syncthreads();
    *(float4*)&red[ps * 128 + g * 4] = make_float4(q[0], q[1], q[2], q[3]);
    __syncthreads();
    if (t < 128) {
        float tot = 0.f;
#pragma unroll
        for (int r = 0; r < 16; ++r) tot += red[r * 128 + t];
        atomicAdd(colsq + t, tot);
    }
}

// ---------- out = relu(bn2(c2) + fused) ----------
__global__ void final_kernel(const unsigned short* __restrict__ c2,
                             const float* __restrict__ cs, const float* __restrict__ cq,
                             const float* __restrict__ g, const float* __restrict__ b,
                             const unsigned short* __restrict__ fused, float* __restrict__ out)
{
    const int tot = NPTS * 32;
    for (int f = blockIdx.x * 256 + threadIdx.x; f < tot; f += gridDim.x * 256) {
        int n = f >> 5, c4 = (f & 31) << 2;
        float4 cs4 = *(const float4*)(cs + c4);
        float4 cq4 = *(const float4*)(cq + c4);
        float4 g4  = *(const float4*)(g + c4);
        float4 b4  = *(const float4*)(b + c4);
        float mx0 = cs4.x / (float)NPTS, mx1 = cs4.y / (float)NPTS,
              mx2 = cs4.z / (float)NPTS, mx3 = cs4.w / (float)NPTS;
        float sc0 = rsqrtf(cq4.x / (float)NPTS - mx0 * mx0 + BN_EPS) * g4.x;
        float sc1 = rsqrtf(cq4.y / (float)NPTS - mx1 * mx1 + BN_EPS) * g4.y;
        float sc2 = rsqrtf(cq4.z / (float)NPTS - mx2 * mx2 + BN_EPS) * g4.z;
        float sc3 = rsqrtf(cq4.w / (float)NPTS - mx3 * mx3 + BN_EPS) * g4.w;
        float sh0 = b4.x - mx0 * sc0, sh1 = b4.y - mx1 * sc1;
        float sh2 = b4.z - mx2 * sc2, sh3 = b4.w - mx3 * sc3;
        uint2 y2 = *(const uint2*)(c2 + (size_t)n * CH + c4);
        uint2 r2 = *(const uint2*)(fused + (size_t)n * CH + c4);
        float4 o;
        o.x = fmaxf(blo(y2.x) * sc0 + sh0 + blo(r2.x), 0.f);
        o.y = fmaxf(bhi(y2.x) * sc1 + sh1 + bhi(r2.x), 0.f);
        o.z = fmaxf(blo(y2.y) * sc2 + sh2 + blo(r2.y), 0.f);
        o.w = fmaxf(bhi(y2.y) * sc3 + sh3 + bhi(r2.y), 0.f);
        *(float4*)(out + (size_t)n * CH + c4) = o;
    }
}

// ---------- host ----------
extern "C" void kernel_launch(void* const* d_in, const int* in_sizes, int n_in,
                              void* d_out, int out_size, void* d_ws, size_t ws_size,
                              hipStream_t stream) {
    (void)in_sizes; (void)n_in; (void)out_size;
    const float* feat    = (const float*)d_in[0];
    const float* lw_W    = (const float*)d_in[1];
    const float* lw_g    = (const float*)d_in[2];
    const float* lw_b    = (const float*)d_in[3];
    const float* w_W     = (const float*)d_in[4];
    const float* proj_W  = (const float*)d_in[5];
    const float* proj_g  = (const float*)d_in[6];
    const float* proj_b  = (const float*)d_in[7];
    const float* adp_W   = (const float*)d_in[8];
    const float* fuse_W  = (const float*)d_in[9];
    const float* fuse_g  = (const float*)d_in[10];
    const float* fuse_b  = (const float*)d_in[11];
    const float* conv1_W = (const float*)d_in[12];
    const float* norm1_g = (const float*)d_in[13];
    const float* norm1_b = (const float*)d_in[14];
    const float* conv2_W = (const float*)d_in[15];
    const float* norm2_g = (const float*)d_in[16];
    const float* norm2_b = (const float*)d_in[17];
    const int*   clusters= (const int*)d_in[18];
    const int*   nidx    = (const int*)d_in[19];
    float* out = (float*)d_out;

    const size_t NC  = (size_t)NPTS * CH;
    const size_t SEG = (size_t)NSEG_ * CH;

    const size_t zwords = 6 * NSEG_ + 10 * 256 + 4;
    const size_t needed = (2 * NC + zwords + 6 * NSEG_ + 3 * (size_t)NPTS
                           + 10 * 256 + 5 * SEG + 98304) * sizeof(float);  // ~167 MB (known good)
    if (ws_size < needed) return;

    float* ws = (float*)d_ws;
    unsigned short* B0 = (unsigned short*)ws;   // featB; after fused: pk/pcnt alias
    unsigned short* B1 = B0 + NC;               // L -> q (in place) / fuseY / conv2 out
    unsigned short* B2 = B1 + NC;               // P / P3 / fused
    unsigned short* B3 = B2 + NC;               // agg / conv1 out
    float* Z  = ws + 2 * NC;
    int*   cnt   = (int*)Z;
    int*   fpos  = cnt + 3 * NSEG_;
    float* stats = (float*)(fpos + 3 * NSEG_);
    unsigned int* qmax = (unsigned int*)(stats + 10 * 256);
    int*   off   = (int*)(qmax + 4);
    float* invc  = (float*)(off + 3 * NSEG_);
    int*   perm  = (int*)(invc + 3 * NSEG_);
    float* scsh  = (float*)(perm + 3 * (size_t)NPTS);
    float* S1    = scsh + 10 * 256;
    float* s3    = S1 + 2 * SEG;
    unsigned short* Wt16 = (unsigned short*)(s3 + 3 * SEG);
    unsigned short* lwT   = Wt16;
    unsigned short* wT    = Wt16 + 3 * 16384;
    unsigned short* projT = Wt16 + 6 * 16384;
    unsigned short* fuseT = Wt16 + 10 * 16384;
    // pk/pcnt alias into B0 region (featB dead after fused_kernel)
    int* pkArr = (int*)B0;                      // NPTS*27 ints = 16.2 MB  (< 38.4 MB region)
    int* pcnt  = pkArr + (size_t)NPTS * KOFF;   // NPTS ints

    const int gemmGrid = (NPTS + 127) / 128;
    const int convGrid = (NPTS + 127) / 128;
    const int aggGrid  = (NPTS + 63) / 64;
    const int mapGrid  = 2048;

    zero_kernel<<<64, 256, 0, stream>>>((float4*)Z, (int)(zwords / 4));
    count_kernel<<<512, 256, 0, stream>>>(clusters, cnt);
    invcnt_kernel<<<(3 * NSEG_ + 255) / 256, 256, 0, stream>>>(cnt, invc);
    scan_kernel<<<3, 1024, 0, stream>>>(cnt, off);
    fill_kernel<<<512, 256, 0, stream>>>(clusters, off, fpos, perm);
    cvt_bf16<<<mapGrid, 256, 0, stream>>>(feat, B0, (int)(NC / 8));
    wtr_all<<<768, 256, 0, stream>>>(lw_W, w_W, proj_W, fuse_W, Wt16);

    for (int i = 0; i < 3; ++i) {
        const int* cli   = clusters + (size_t)i * NPTS;
        const int* permi = perm + (size_t)i * NPTS;
        const int* offi  = off + i * NSEG_;
        const int* cnti  = cnt + i * NSEG_;
        float* st  = stats + i * 256;
        float* stp = stats + (3 + i) * 256;
        float* ss  = scsh + i * 256;
        gemm_dual<<<gemmGrid, 256, 0, stream>>>(B0, lwT + (size_t)i * 16384,
            projT + (size_t)i * 16384, B1, B2, st, stp);
        finalize_kernel<<<1, 128, 0, stream>>>(st, st + 128, lw_g + i * CH, lw_b + i * CH, ss, ss + 128);
        gather_s1<<<NSEG_, 256, 0, stream>>>(B1, st, st + 128, lw_g + i * CH, lw_b + i * CH,
            permi, offi, cnti, S1);
        gemm_one<83><<<gemmGrid, 256, 0, stream>>>(B1, nullptr, wT + (size_t)i * 16384, B1,
            cli, S1, invc + i * NSEG_, ss, ss + 128, nullptr, nullptr, qmax + i);
        gather_s23<<<NSEG_, 256, 0, stream>>>(B1, B2, stp, stp + 128, proj_g + i * CH, proj_b + i * CH,
            qmax + i, permi, offi, cnti, s3 + (size_t)i * SEG);
    }

    adpagg_kernel<<<aggGrid, 256, 0, stream>>>(B0, adp_W,
        clusters, clusters + NPTS, clusters + 2 * (size_t)NPTS,
        s3, s3 + SEG, s3 + 2 * SEG, B3);

    {
        float* st = stats + 6 * 256; float* ss = scsh + 6 * 256;
        gemm_one<72><<<gemmGrid, 256, 0, stream>>>(B0, nullptr, projT + 3 * (size_t)16384, B2,
            nullptr, nullptr, nullptr, nullptr, nullptr, st, st + 128, nullptr);
        finalize_kernel<<<1, 128, 0, stream>>>(st, st + 128, proj_g + 3 * CH, proj_b + 3 * CH, ss, ss + 128);
    }
    {
        float* st = stats + 7 * 256;
        gemm_one<106><<<gemmGrid, 256, 0, stream>>>(B2, B3, fuseT, B1,
            nullptr, nullptr, nullptr, scsh + 6 * 256, scsh + 6 * 256 + 128, st, st + 128, nullptr);
    }
    // fused = relu(bn(fuseY)) + featB -> B2   (last reader of B0-as-featB)
    fused_kernel<<<mapGrid, 256, 0, stream>>>(B1, stats + 7 * 256, stats + 7 * 256 + 128,
        fuse_g, fuse_b, B0, B2);

    // build compacted neighbor list into B0 region (featB now dead)
    compact_nidx<<<(NPTS + 255) / 256, 256, 0, stream>>>(nidx, pkArr, pcnt);

    // conv1: B2 -> B3, stats8
    conv_kernel<false><<<convGrid, 512, 0, stream>>>(B2, conv1_W, pkArr, pcnt,
        nullptr, nullptr, nullptr, nullptr, B3, stats + 8 * 256, stats + 8 * 256 + 128);
    // conv2: bn1(B3) -> B1, stats9
    conv_kernel<true><<<convGrid, 512, 0, stream>>>(B3, conv2_W, pkArr, pcnt,
        stats + 8 * 256, stats + 8 * 256 + 128, norm1_g, norm1_b,
        B1, stats + 9 * 256, stats + 9 * 256 + 128);
    // out = relu(bn2(B1) + B2)
    final_kernel<<<mapGrid, 256, 0, stream>>>(B1, stats + 9 * 256, stats + 9 * 256 + 128,
        norm2_g, norm2_b, B2, out);
}

// Round 8
// 917.686 us; speedup vs baseline: 4.2273x; 1.2177x over previous
//
#include <hip/hip_runtime.h>
#include <math.h>

#define NPTS 150000
#define CH   128
#define NSEG_ 4096
#define KOFF 27
#define BN_EPS 1e-5f
#define NPART 32

typedef __attribute__((ext_vector_type(8))) short bf16x8;
typedef __attribute__((ext_vector_type(4))) float f32x4;

// ---------- helpers ----------
__device__ __forceinline__ unsigned short f2bf(float f) {
    unsigned int u = __float_as_uint(f);
    unsigned int r = (u + 0x7fffu + ((u >> 16) & 1u)) >> 16;
    return (unsigned short)r;
}
__device__ __forceinline__ float bf2f(unsigned short h) {
    return __uint_as_float(((unsigned int)h) << 16);
}
__device__ __forceinline__ float blo(unsigned int u) { return __uint_as_float(u << 16); }
__device__ __forceinline__ float bhi(unsigned int u) { return __uint_as_float(u & 0xffff0000u); }
__device__ __forceinline__ unsigned int pk2(float a, float b) {
    return (unsigned int)f2bf(a) | ((unsigned int)f2bf(b) << 16);
}
__device__ __forceinline__ int xcd_swz(int bid, int nwg) {
    int q = nwg >> 3, r = nwg & 7;
    int xcd = bid & 7, idx = bid >> 3;
    return (xcd < r ? xcd * (q + 1) : r * (q + 1) + (xcd - r) * q) + idx;
}

__global__ void zero_kernel(float4* __restrict__ p, int n4) {
    for (int i = blockIdx.x * 256 + threadIdx.x; i < n4; i += gridDim.x * 256)
        p[i] = make_float4(0.f, 0.f, 0.f, 0.f);
}

__global__ void cvt_bf16(const float* __restrict__ in, unsigned short* __restrict__ o, int n8) {
    for (int i = blockIdx.x * 256 + threadIdx.x; i < n8; i += gridDim.x * 256) {
        float4 a = *(const float4*)(in + (size_t)i * 8);
        float4 b = *(const float4*)(in + (size_t)i * 8 + 4);
        uint4 w;
        w.x = pk2(a.x, a.y); w.y = pk2(a.z, a.w);
        w.z = pk2(b.x, b.y); w.w = pk2(b.z, b.w);
        *(uint4*)(o + (size_t)i * 8) = w;
    }
}

__global__ void wtr_all(const float* __restrict__ lw, const float* __restrict__ w,
                        const float* __restrict__ proj, const float* __restrict__ fuse,
                        unsigned short* __restrict__ Wt)
{
    int i = blockIdx.x * 256 + threadIdx.x;
    if (i < 10 * 16384) {
        int u = i >> 14, r = i & 16383;
        int n = r >> 7, k = r & 127;
        const float* src = (u < 3) ? lw + (size_t)u * 16384
                         : (u < 6) ? w + (size_t)(u - 3) * 16384
                                   : proj + (size_t)(u - 6) * 16384;
        Wt[(size_t)u * 16384 + n * 128 + k] = f2bf(src[(size_t)k * 128 + n]);
    } else if (i < 10 * 16384 + 32768) {
        int r = i - 10 * 16384;
        int n = r >> 8, k = r & 255;
        Wt[10 * 16384 + (size_t)n * 256 + k] = f2bf(fuse[(size_t)k * 128 + n]);
    }
}

// compact valid neighbors: pk[n*27+e] = (k<<18)|idx, pcnt[n] = count
__global__ void compact_nidx(const int* __restrict__ nidx, int* __restrict__ pk, int* __restrict__ pcnt) {
    int p = blockIdx.x * 256 + threadIdx.x;
    if (p < NPTS) {
        int c = 0;
        const int* row = nidx + (size_t)p * KOFF;
        int* orow = pk + (size_t)p * KOFF;
#pragma unroll
        for (int k = 0; k < KOFF; ++k) {
            int idx = row[k];
            if (idx >= 0) orow[c++] = (k << 18) | idx;
        }
        pcnt[p] = c;
    }
}

// collapse NPART partial stats -> F[256] (sum|sumsq); optionally bn scale/shift -> S[256]
__global__ void collapse2(const float* p0, const float* g0, const float* b0, float* f0, float* s0,
                          const float* p1, const float* g1, const float* b1, float* f1, float* s1)
{
    const float* P = blockIdx.x == 0 ? p0 : p1;
    if (!P) return;
    const float* G = blockIdx.x == 0 ? g0 : g1;
    const float* B = blockIdx.x == 0 ? b0 : b1;
    float* F = blockIdx.x == 0 ? f0 : f1;
    float* S = blockIdx.x == 0 ? s0 : s1;
    int c = threadIdx.x;  // 128
    float s = 0.f, q = 0.f;
    for (int r = 0; r < NPART; ++r) { s += P[r * 256 + c]; q += P[r * 256 + 128 + c]; }
    F[c] = s; F[128 + c] = q;
    if (S) {
        float mean = s / (float)NPTS;
        float var  = q / (float)NPTS - mean * mean;
        float scv = rsqrtf(var + BN_EPS) * G[c];
        S[c] = scv; S[128 + c] = B[c] - mean * scv;
    }
}

// ---------- shared GEMM epilogue (stats go to per-part buffers; no global max) ----------
template<bool CBF, bool STATS>
__device__ __forceinline__ void gemm_epi(
    f32x4 (&acc)[4][4], void* Cv, int R, int C0, int lc, int lk, int w, int t,
    float (*reds)[4][16], float (*redq)[4][16], float* statsP)
{
    float* Cf = (float*)Cv;
    unsigned short* Chh = (unsigned short*)Cv;
    float s[4] = {0.f, 0.f, 0.f, 0.f}, q[4] = {0.f, 0.f, 0.f, 0.f};
#pragma unroll
    for (int mi = 0; mi < 4; ++mi) {
#pragma unroll
        for (int r = 0; r < 4; ++r) {
            int row = R + mi * 16 + lk * 4 + r;
            if (row < NPTS) {
#pragma unroll
                for (int ni = 0; ni < 4; ++ni) {
                    float v = acc[mi][ni][r];
                    int col = C0 + ni * 16 + lc;
                    if constexpr (CBF) Chh[(size_t)row * CH + col] = f2bf(v);
                    else               Cf[(size_t)row * CH + col] = v;
                    if constexpr (STATS) { s[ni] += v; q[ni] += v * v; }
                }
            }
        }
    }
    if constexpr (STATS) {
#pragma unroll
        for (int ni = 0; ni < 4; ++ni) {
            s[ni] += __shfl_xor(s[ni], 16); s[ni] += __shfl_xor(s[ni], 32);
            q[ni] += __shfl_xor(q[ni], 16); q[ni] += __shfl_xor(q[ni], 32);
        }
        __syncthreads();
        if (lk == 0) {
#pragma unroll
            for (int ni = 0; ni < 4; ++ni) { reds[w][ni][lc] = s[ni]; redq[w][ni][lc] = q[ni]; }
        }
        __syncthreads();
        if (t < 128) {
            int half = t >> 6, fr = (t >> 4) & 3, cc = t & 15;
            float* pb = statsP + (blockIdx.x & (NPART - 1)) * 256;
            atomicAdd(pb + t, reds[half][fr][cc] + reds[half + 2][fr][cc]);
            atomicAdd(pb + 128 + t, redq[half][fr][cc] + redq[half + 2][fr][cc]);
        }
    }
}

// ---------- dual GEMM ----------
__global__ __launch_bounds__(256) void gemm_dual(
    const unsigned short* __restrict__ A,
    const unsigned short* __restrict__ W1t, const unsigned short* __restrict__ W2t,
    unsigned short* __restrict__ C1, unsigned short* __restrict__ C2,
    float* __restrict__ st1P, float* __restrict__ st2P)
{
    __shared__ float reds[4][4][16], redq[4][4][16];
    const int t  = threadIdx.x;
    const int l  = t & 63, w = t >> 6;
    const int lc = l & 15, lk = l >> 4;
    const int wr = w >> 1, wc = w & 1;
    const int bid = xcd_swz((int)blockIdx.x, (int)gridDim.x);
    const int R  = bid * 128 + wr * 64;
    const int C0 = wc * 64;

    int rowm[4];
#pragma unroll
    for (int mi = 0; mi < 4; ++mi) {
        int r = R + mi * 16 + lc;
        rowm[mi] = r < NPTS ? r : NPTS - 1;
    }
    bf16x8 a[4][4];
#pragma unroll
    for (int ks = 0; ks < 4; ++ks)
#pragma unroll
        for (int mi = 0; mi < 4; ++mi)
            a[ks][mi] = *(const bf16x8*)(A + (size_t)rowm[mi] * CH + ks * 32 + lk * 8);

    f32x4 acc[4][4];
#pragma unroll
    for (int mi = 0; mi < 4; ++mi)
#pragma unroll
        for (int ni = 0; ni < 4; ++ni) acc[mi][ni] = (f32x4){0.f, 0.f, 0.f, 0.f};
#pragma unroll
    for (int ks = 0; ks < 4; ++ks) {
        bf16x8 b[4];
#pragma unroll
        for (int ni = 0; ni < 4; ++ni)
            b[ni] = *(const bf16x8*)(W1t + (size_t)(C0 + ni * 16 + lc) * 128 + ks * 32 + lk * 8);
#pragma unroll
        for (int mi = 0; mi < 4; ++mi)
#pragma unroll
            for (int ni = 0; ni < 4; ++ni)
                acc[mi][ni] = __builtin_amdgcn_mfma_f32_16x16x32_bf16(a[ks][mi], b[ni], acc[mi][ni], 0, 0, 0);
    }
    gemm_epi<true, true>(acc, C1, R, C0, lc, lk, w, t, reds, redq, st1P);

#pragma unroll
    for (int mi = 0; mi < 4; ++mi)
#pragma unroll
        for (int ni = 0; ni < 4; ++ni) acc[mi][ni] = (f32x4){0.f, 0.f, 0.f, 0.f};
#pragma unroll
    for (int ks = 0; ks < 4; ++ks) {
        bf16x8 b[4];
#pragma unroll
        for (int ni = 0; ni < 4; ++ni)
            b[ni] = *(const bf16x8*)(W2t + (size_t)(C0 + ni * 16 + lc) * 128 + ks * 32 + lk * 8);
#pragma unroll
        for (int mi = 0; mi < 4; ++mi)
#pragma unroll
            for (int ni = 0; ni < 4; ++ni)
                acc[mi][ni] = __builtin_amdgcn_mfma_f32_16x16x32_bf16(a[ks][mi], b[ni], acc[mi][ni], 0, 0, 0);
    }
    gemm_epi<true, true>(acc, C2, R, C0, lc, lk, w, t, reds, redq, st2P);
}

// ---------- single GEMM with transforms ----------
// FLAGS: 1=ACEN, 2=ABN, 8=STATS, 32=K256, 64=CBF
template<int FLAGS>
__global__ __launch_bounds__(256) void gemm_one(
    const unsigned short* A0, const unsigned short* A1,
    const unsigned short* __restrict__ Wt, void* Cv,
    const int* __restrict__ cl, const float* __restrict__ seg, const float* __restrict__ invcnt,
    const float* __restrict__ bnsc, const float* __restrict__ bnsh,
    float* __restrict__ statsP)
{
    constexpr bool ACEN   = (FLAGS & 1)  != 0;
    constexpr bool ABN    = (FLAGS & 2)  != 0;
    constexpr bool STATS  = (FLAGS & 8)  != 0;
    constexpr bool K256   = (FLAGS & 32) != 0;
    constexpr bool CBF    = (FLAGS & 64) != 0;
    constexpr int  KW = K256 ? 256 : 128;
    constexpr int  NH = K256 ? 2 : 1;

    __shared__ float reds[4][4][16], redq[4][4][16];
    const int t  = threadIdx.x;
    const int l  = t & 63, w = t >> 6;
    const int lc = l & 15, lk = l >> 4;
    const int wr = w >> 1, wc = w & 1;
    const int bid = xcd_swz((int)blockIdx.x, (int)gridDim.x);
    const int R  = bid * 128 + wr * 64;
    const int C0 = wc * 64;

    int rowm[4];
#pragma unroll
    for (int mi = 0; mi < 4; ++mi) {
        int r = R + mi * 16 + lc;
        rowm[mi] = r < NPTS ? r : NPTS - 1;
    }
    int sg4[4]; float ic4[4];
    if constexpr (ACEN) {
#pragma unroll
        for (int mi = 0; mi < 4; ++mi) { sg4[mi] = cl[rowm[mi]]; ic4[mi] = invcnt[sg4[mi]]; }
    }

    f32x4 acc[4][4];
#pragma unroll
    for (int mi = 0; mi < 4; ++mi)
#pragma unroll
        for (int ni = 0; ni < 4; ++ni) acc[mi][ni] = (f32x4){0.f, 0.f, 0.f, 0.f};

#pragma unroll
    for (int hh = 0; hh < NH; ++hh) {
        const unsigned short* Asrc = (K256 && hh) ? A1 : A0;
        bf16x8 a[4][4];
#pragma unroll
        for (int ks = 0; ks < 4; ++ks)
#pragma unroll
            for (int mi = 0; mi < 4; ++mi)
                a[ks][mi] = *(const bf16x8*)(Asrc + (size_t)rowm[mi] * CH + ks * 32 + lk * 8);

        if constexpr (ABN || ACEN) {
            if (hh == 0) {
#pragma unroll
                for (int ks = 0; ks < 4; ++ks) {
                    const int kb = ks * 32 + lk * 8;
                    float4 s0, s1v, h0, h1;
                    if constexpr (ABN) {
                        s0  = *(const float4*)(bnsc + kb); s1v = *(const float4*)(bnsc + kb + 4);
                        h0  = *(const float4*)(bnsh + kb); h1  = *(const float4*)(bnsh + kb + 4);
                    }
#pragma unroll
                    for (int mi = 0; mi < 4; ++mi) {
                        union { unsigned short u[8]; bf16x8 v; } pk;
                        pk.v = a[ks][mi];
                        float v[8];
#pragma unroll
                        for (int e = 0; e < 8; ++e) v[e] = bf2f(pk.u[e]);
                        if constexpr (ABN) {
                            v[0] = fmaxf(v[0] * s0.x + h0.x, 0.f);  v[1] = fmaxf(v[1] * s0.y + h0.y, 0.f);
                            v[2] = fmaxf(v[2] * s0.z + h0.z, 0.f);  v[3] = fmaxf(v[3] * s0.w + h0.w, 0.f);
                            v[4] = fmaxf(v[4] * s1v.x + h1.x, 0.f); v[5] = fmaxf(v[5] * s1v.y + h1.y, 0.f);
                            v[6] = fmaxf(v[6] * s1v.z + h1.z, 0.f); v[7] = fmaxf(v[7] * s1v.w + h1.w, 0.f);
                        }
                        if constexpr (ACEN) {
                            const float* sp = seg + (size_t)sg4[mi] * CH + kb;
                            float4 m0 = *(const float4*)sp, m1 = *(const float4*)(sp + 4);
                            float ic = ic4[mi];
                            v[0] -= m0.x * ic; v[1] -= m0.y * ic; v[2] -= m0.z * ic; v[3] -= m0.w * ic;
                            v[4] -= m1.x * ic; v[5] -= m1.y * ic; v[6] -= m1.z * ic; v[7] -= m1.w * ic;
                        }
#pragma unroll
                        for (int e = 0; e < 8; ++e) pk.u[e] = f2bf(v[e]);
                        a[ks][mi] = pk.v;
                    }
                }
            }
        }
#pragma unroll
        for (int ks = 0; ks < 4; ++ks) {
            bf16x8 b[4];
#pragma unroll
            for (int ni = 0; ni < 4; ++ni)
                b[ni] = *(const bf16x8*)(Wt + (size_t)(C0 + ni * 16 + lc) * KW + hh * 128 + ks * 32 + lk * 8);
#pragma unroll
            for (int mi = 0; mi < 4; ++mi)
#pragma unroll
                for (int ni = 0; ni < 4; ++ni)
                    acc[mi][ni] = __builtin_amdgcn_mfma_f32_16x16x32_bf16(a[ks][mi], b[ni], acc[mi][ni], 0, 0, 0);
        }
    }
    gemm_epi<CBF, STATS>(acc, Cv, R, C0, lc, lk, w, t, reds, redq, statsP);
}

// ---------- CSR build ----------
__global__ void count_kernel(const int* __restrict__ clusters, int* __restrict__ cnt) {
    const int tot = 3 * NPTS;
    for (int f = blockIdx.x * 256 + threadIdx.x; f < tot; f += gridDim.x * 256) {
        int i = f / NPTS;
        atomicAdd(cnt + i * NSEG_ + clusters[f], 1);
    }
}

__global__ void invcnt_kernel(const int* __restrict__ cnt, float* __restrict__ invc) {
    int x = blockIdx.x * 256 + threadIdx.x;
    if (x < 3 * NSEG_) {
        int c = cnt[x];
        invc[x] = 1.0f / (float)(c > 1 ? c : 1);
    }
}

__global__ __launch_bounds__(1024) void scan_kernel(const int* __restrict__ cnt, int* __restrict__ off) {
    __shared__ int tot[1024];
    const int L = blockIdx.x;
    const int* c = cnt + L * NSEG_;
    int* o = off + L * NSEG_;
    const int t = threadIdx.x;
    int v[4];
    int s = 0;
#pragma unroll
    for (int j = 0; j < 4; ++j) { v[j] = s; s += c[t * 4 + j]; }
    tot[t] = s;
    __syncthreads();
    for (int d = 1; d < 1024; d <<= 1) {
        int x = (t >= d) ? tot[t - d] : 0;
        __syncthreads();
        tot[t] += x;
        __syncthreads();
    }
    int pre = (t == 0) ? 0 : tot[t - 1];
#pragma unroll
    for (int j = 0; j < 4; ++j) o[t * 4 + j] = pre + v[j];
}

__global__ void fill_kernel(const int* __restrict__ clusters, const int* __restrict__ off,
                            int* __restrict__ fpos, int* __restrict__ perm) {
    const int tot = 3 * NPTS;
    for (int f = blockIdx.x * 256 + threadIdx.x; f < tot; f += gridDim.x * 256) {
        int i = f / NPTS;
        int n = f - i * NPTS;
        int s = i * NSEG_ + clusters[f];
        int pos = off[s] + atomicAdd(fpos + s, 1);
        perm[(size_t)i * NPTS + pos] = n;
    }
}

// ---------- s1 = seg_sum(relu(bn(L))) ----------
__global__ __launch_bounds__(256) void gather_s1(
    const unsigned short* __restrict__ L,
    const float* __restrict__ cs, const float* __restrict__ cq,
    const float* __restrict__ g, const float* __restrict__ b,
    const int* __restrict__ perm, const int* __restrict__ off, const int* __restrict__ cnt,
    float* __restrict__ segout)
{
    __shared__ float red[8][132];
    const int s = blockIdx.x;
    const int t = threadIdx.x;
    const int c4 = (t & 31) * 4, h = t >> 5;
    const int start = off[s], m = cnt[s];
    float4 cs4 = *(const float4*)(cs + c4);
    float4 cq4 = *(const float4*)(cq + c4);
    float4 g4  = *(const float4*)(g + c4);
    float4 b4  = *(const float4*)(b + c4);
    float m0 = cs4.x / (float)NPTS, m1 = cs4.y / (float)NPTS,
          m2 = cs4.z / (float)NPTS, m3 = cs4.w / (float)NPTS;
    float sc0 = rsqrtf(cq4.x / (float)NPTS - m0 * m0 + BN_EPS) * g4.x;
    float sc1 = rsqrtf(cq4.y / (float)NPTS - m1 * m1 + BN_EPS) * g4.y;
    float sc2 = rsqrtf(cq4.z / (float)NPTS - m2 * m2 + BN_EPS) * g4.z;
    float sc3 = rsqrtf(cq4.w / (float)NPTS - m3 * m3 + BN_EPS) * g4.w;
    float sh0 = b4.x - m0 * sc0, sh1 = b4.y - m1 * sc1;
    float sh2 = b4.z - m2 * sc2, sh3 = b4.w - m3 * sc3;

    float a0 = 0.f, a1 = 0.f, a2 = 0.f, a3 = 0.f;
    for (int j = h; j < m; j += 8) {
        int p = perm[start + j];
        uint2 rw = *(const uint2*)(L + (size_t)p * CH + c4);
        a0 += fmaxf(blo(rw.x) * sc0 + sh0, 0.f);
        a1 += fmaxf(bhi(rw.x) * sc1 + sh1, 0.f);
        a2 += fmaxf(blo(rw.y) * sc2 + sh2, 0.f);
        a3 += fmaxf(bhi(rw.y) * sc3 + sh3, 0.f);
    }
    *(float4*)&red[h][c4] = make_float4(a0, a1, a2, a3);
    __syncthreads();
    if (t < 128) {
        float tot = 0.f;
#pragma unroll
        for (int r = 0; r < 8; ++r) tot += red[r][t];
        segout[(size_t)s * CH + t] = tot;
    }
}

// ---------- single-pass s3 (no global max needed: ratio is shift-invariant) ----------
__global__ __launch_bounds__(256) void gather_s23(
    const unsigned short* __restrict__ Q, const unsigned short* __restrict__ P,
    const float* __restrict__ cs, const float* __restrict__ cq,
    const float* __restrict__ g, const float* __restrict__ b,
    const int* __restrict__ perm, const int* __restrict__ off, const int* __restrict__ cnt,
    float* __restrict__ s3out)
{
    __shared__ float red[8][132];
    const int s = blockIdx.x;
    const int t = threadIdx.x;
    const int c4 = (t & 31) * 4, h = t >> 5;
    const int start = off[s], m = cnt[s];
    float4 cs4 = *(const float4*)(cs + c4);
    float4 cq4 = *(const float4*)(cq + c4);
    float4 g4  = *(const float4*)(g + c4);
    float4 b4  = *(const float4*)(b + c4);
    float m0 = cs4.x / (float)NPTS, m1 = cs4.y / (float)NPTS,
          m2 = cs4.z / (float)NPTS, m3 = cs4.w / (float)NPTS;
    float sc0 = rsqrtf(cq4.x / (float)NPTS - m0 * m0 + BN_EPS) * g4.x;
    float sc1 = rsqrtf(cq4.y / (float)NPTS - m1 * m1 + BN_EPS) * g4.y;
    float sc2 = rsqrtf(cq4.z / (float)NPTS - m2 * m2 + BN_EPS) * g4.z;
    float sc3 = rsqrtf(cq4.w / (float)NPTS - m3 * m3 + BN_EPS) * g4.w;
    float sh0 = b4.x - m0 * sc0, sh1 = b4.y - m1 * sc1;
    float sh2 = b4.z - m2 * sc2, sh3 = b4.w - m3 * sc3;

    float e0 = 0.f, e1 = 0.f, e2 = 0.f, e3 = 0.f;
    float s0 = 0.f, s1 = 0.f, s2 = 0.f, s3 = 0.f;
    for (int j = h; j < m; j += 8) {
        int p = perm[start + j];
        uint2 qw = *(const uint2*)(Q + (size_t)p * CH + c4);
        uint2 pw = *(const uint2*)(P + (size_t)p * CH + c4);
        float ex0 = expf(blo(qw.x)), ex1 = expf(bhi(qw.x));
        float ex2 = expf(blo(qw.y)), ex3 = expf(bhi(qw.y));
        e0 += ex0; e1 += ex1; e2 += ex2; e3 += ex3;
        s0 += fmaxf(blo(pw.x) * sc0 + sh0, 0.f) * ex0;
        s1 += fmaxf(bhi(pw.x) * sc1 + sh1, 0.f) * ex1;
        s2 += fmaxf(blo(pw.y) * sc2 + sh2, 0.f) * ex2;
        s3 += fmaxf(bhi(pw.y) * sc3 + sh3, 0.f) * ex3;
    }
    *(float4*)&red[h][c4] = make_float4(e0, e1, e2, e3);
    __syncthreads();
    float etot = 0.f;
    if (t < 128) {
#pragma unroll
        for (int r = 0; r < 8; ++r) etot += red[r][t];
    }
    __syncthreads();
    *(float4*)&red[h][c4] = make_float4(s0, s1, s2, s3);
    __syncthreads();
    if (t < 128) {
        float stot = 0.f;
#pragma unroll
        for (int r = 0; r < 8; ++r) stot += red[r][t];
        s3out[(size_t)s * CH + t] = stot / (etot + 1e-6f);
    }
}

// ---------- adp softmax + agg ----------
__global__ __launch_bounds__(256) void adpagg_kernel(
    const unsigned short* __restrict__ featB, const float* __restrict__ adpW,
    const int* __restrict__ cl0, const int* __restrict__ cl1, const int* __restrict__ cl2,
    const float* __restrict__ s30, const float* __restrict__ s31, const float* __restrict__ s32,
    unsigned short* __restrict__ agg)
{
    __shared__ float ftile[64][132];
    __shared__ float wl[128][3];
    __shared__ float pr[64][3];
    __shared__ int   cls[64][3];
    const int t = threadIdx.x;
    const int n0 = blockIdx.x * 64;

    if (t < 128) { wl[t][0] = adpW[t * 3]; wl[t][1] = adpW[t * 3 + 1]; wl[t][2] = adpW[t * 3 + 2]; }
#pragma unroll
    for (int h = 0; h < 4; ++h) {
        int f = t + h * 256;
        int r = f >> 4, c8 = (f & 15) * 8;
        int n = n0 + r;
        if (n < NPTS) {
            uint4 rw = *(const uint4*)(featB + (size_t)n * CH + c8);
            ftile[r][c8 + 0] = blo(rw.x); ftile[r][c8 + 1] = bhi(rw.x);
            ftile[r][c8 + 2] = blo(rw.y); ftile[r][c8 + 3] = bhi(rw.y);
            ftile[r][c8 + 4] = blo(rw.z); ftile[r][c8 + 5] = bhi(rw.z);
            ftile[r][c8 + 6] = blo(rw.w); ftile[r][c8 + 7] = bhi(rw.w);
        } else {
#pragma unroll
            for (int e = 0; e < 8; ++e) ftile[r][c8 + e] = 0.f;
        }
    }
    if (t < 64) {
        int n = n0 + t;
        if (n < NPTS) { cls[t][0] = cl0[n]; cls[t][1] = cl1[n]; cls[t][2] = cl2[n]; }
        else { cls[t][0] = 0; cls[t][1] = 0; cls[t][2] = 0; }
    }
    __syncthreads();

    if (t < 64) {
        float p0 = 0.f, p1 = 0.f, p2 = 0.f;
        for (int k = 0; k < 128; ++k) {
            float fv = ftile[t][k];
            p0 += fv * wl[k][0]; p1 += fv * wl[k][1]; p2 += fv * wl[k][2];
        }
        float m = fmaxf(p0, fmaxf(p1, p2));
        float e0 = expf(p0 - m), e1 = expf(p1 - m), e2 = expf(p2 - m);
        float inv = 1.f / (e0 + e1 + e2);
        pr[t][0] = e0 * inv; pr[t][1] = e1 * inv; pr[t][2] = e2 * inv;
    }
    __syncthreads();

#pragma unroll
    for (int h = 0; h < 8; ++h) {
        int f = t + h * 256;
        int r = f >> 5, c4 = (f & 31) << 2;
        int n = n0 + r;
        if (n < NPTS) {
            float a0 = pr[r][0], a1 = pr[r][1], a2 = pr[r][2];
            float4 v0 = *(const float4*)(s30 + (size_t)cls[r][0] * CH + c4);
            float4 v1 = *(const float4*)(s31 + (size_t)cls[r][1] * CH + c4);
            float4 v2 = *(const float4*)(s32 + (size_t)cls[r][2] * CH + c4);
            float ox = a0 * v0.x + a1 * v1.x + a2 * v2.x;
            float oy = a0 * v0.y + a1 * v1.y + a2 * v2.y;
            float oz = a0 * v0.z + a1 * v1.z + a2 * v2.z;
            float ow = a0 * v0.w + a1 * v1.w + a2 * v2.w;
            uint2 wv; wv.x = pk2(ox, oy); wv.y = pk2(oz, ow);
            *(uint2*)(agg + (size_t)n * CH + c4) = wv;
        }
    }
}

// ---------- fused = relu(bn(fuseY)) + featB ----------
__global__ void fused_kernel(const unsigned short* __restrict__ fY,
                             const float* __restrict__ cs, const float* __restrict__ cq,
                             const float* __restrict__ g, const float* __restrict__ b,
                             const unsigned short* __restrict__ featB, unsigned short* __restrict__ outB)
{
    const int tot = NPTS * 32;
    for (int f = blockIdx.x * 256 + threadIdx.x; f < tot; f += gridDim.x * 256) {
        int n = f >> 5, c4 = (f & 31) << 2;
        float4 cs4 = *(const float4*)(cs + c4);
        float4 cq4 = *(const float4*)(cq + c4);
        float4 g4  = *(const float4*)(g + c4);
        float4 b4  = *(const float4*)(b + c4);
        float mx0 = cs4.x / (float)NPTS, mx1 = cs4.y / (float)NPTS,
              mx2 = cs4.z / (float)NPTS, mx3 = cs4.w / (float)NPTS;
        float sc0 = rsqrtf(cq4.x / (float)NPTS - mx0 * mx0 + BN_EPS) * g4.x;
        float sc1 = rsqrtf(cq4.y / (float)NPTS - mx1 * mx1 + BN_EPS) * g4.y;
        float sc2 = rsqrtf(cq4.z / (float)NPTS - mx2 * mx2 + BN_EPS) * g4.z;
        float sc3 = rsqrtf(cq4.w / (float)NPTS - mx3 * mx3 + BN_EPS) * g4.w;
        float sh0 = b4.x - mx0 * sc0, sh1 = b4.y - mx1 * sc1;
        float sh2 = b4.z - mx2 * sc2, sh3 = b4.w - mx3 * sc3;
        uint2 y2 = *(const uint2*)(fY + (size_t)n * CH + c4);
        uint2 f2 = *(const uint2*)(featB + (size_t)n * CH + c4);
        float o0 = fmaxf(blo(y2.x) * sc0 + sh0, 0.f) + blo(f2.x);
        float o1 = fmaxf(bhi(y2.x) * sc1 + sh1, 0.f) + bhi(f2.x);
        float o2 = fmaxf(blo(y2.y) * sc2 + sh2, 0.f) + blo(f2.y);
        float o3 = fmaxf(bhi(y2.y) * sc3 + sh3, 0.f) + bhi(f2.y);
        uint2 wv; wv.x = pk2(o0, o1); wv.y = pk2(o2, o3);
        *(uint2*)(outB + (size_t)n * CH + c4) = wv;
    }
}

// ---------- sparse grouped conv (compacted neighbor list), stats -> parts ----------
template<bool INBN>
__global__ __launch_bounds__(512) void conv_kernel(
    const unsigned short* __restrict__ X, const float* __restrict__ Wc,
    const int* __restrict__ pk, const int* __restrict__ pcnt,
    const float* __restrict__ csIn, const float* __restrict__ cqIn,
    const float* __restrict__ gIn, const float* __restrict__ bIn,
    unsigned short* __restrict__ Y, float* __restrict__ statsP)
{
    __shared__ unsigned short Wh[KOFF * 4 * 128];
    __shared__ float red[16 * 128];
    __shared__ int   cntl[128];
    __shared__ float bnp[256];

    const int t = threadIdx.x;
    const int g = t & 31, ps = t >> 5;
    const int bid = xcd_swz((int)blockIdx.x, (int)gridDim.x);
    const int n0 = bid * 128;

    for (int f = t; f < KOFF * 512; f += 512) {
        int k = f >> 9, rem = f & 511;
        int gg = rem >> 4, ii = (rem >> 2) & 3, oo = rem & 3;
        Wh[(k * 4 + ii) * 128 + gg * 4 + oo] = f2bf(Wc[f]);
    }
    if (t < 128) {
        int n = n0 + t;
        cntl[t] = (n < NPTS) ? pcnt[n] : 0;
    }
    if (INBN && t < 128) {
        float mean = csIn[t] / (float)NPTS;
        float var  = cqIn[t] / (float)NPTS - mean * mean;
        float sc = rsqrtf(var + BN_EPS) * gIn[t];
        bnp[t] = sc; bnp[128 + t] = bIn[t] - mean * sc;
    }
    __syncthreads();

    float4 bs4 = make_float4(1.f, 1.f, 1.f, 1.f), bh4 = make_float4(0.f, 0.f, 0.f, 0.f);
    if (INBN) { bs4 = *(float4*)&bnp[g * 4]; bh4 = *(float4*)&bnp[128 + g * 4]; }

    float acc[8][4];
#pragma unroll
    for (int j = 0; j < 8; ++j)
#pragma unroll
        for (int o = 0; o < 4; ++o) acc[j][o] = 0.f;

#pragma unroll
    for (int j = 0; j < 8; ++j) {
        int p = ps * 8 + j;
        int n = n0 + p;
        int m = cntl[p];
        for (int e = 0; e < m; ++e) {
            int ent = pk[(size_t)n * KOFF + e];
            int k = ent >> 18, idx = ent & 0x3FFFF;
            uint2 u0 = *(const uint2*)&Wh[(k * 4 + 0) * 128 + g * 4];
            uint2 u1 = *(const uint2*)&Wh[(k * 4 + 1) * 128 + g * 4];
            uint2 u2 = *(const uint2*)&Wh[(k * 4 + 2) * 128 + g * 4];
            uint2 u3 = *(const uint2*)&Wh[(k * 4 + 3) * 128 + g * 4];
            uint2 rw = *(const uint2*)(X + (size_t)idx * CH + g * 4);
            float vx = blo(rw.x), vy = bhi(rw.x), vz = blo(rw.y), vw = bhi(rw.y);
            if (INBN) {
                vx = vx * bs4.x + bh4.x; vy = vy * bs4.y + bh4.y;
                vz = vz * bs4.z + bh4.z; vw = vw * bs4.w + bh4.w;
            }
            acc[j][0] += vx * blo(u0.x) + vy * blo(u1.x) + vz * blo(u2.x) + vw * blo(u3.x);
            acc[j][1] += vx * bhi(u0.x) + vy * bhi(u1.x) + vz * bhi(u2.x) + vw * bhi(u3.x);
            acc[j][2] += vx * blo(u0.y) + vy * blo(u1.y) + vz * blo(u2.y) + vw * blo(u3.y);
            acc[j][3] += vx * bhi(u0.y) + vy * bhi(u1.y) + vz * bhi(u2.y) + vw * bhi(u3.y);
        }
    }

    float s[4] = {0.f, 0.f, 0.f, 0.f}, q[4] = {0.f, 0.f, 0.f, 0.f};
#pragma unroll
    for (int j = 0; j < 8; ++j) {
        int n = n0 + ps * 8 + j;
        if (n < NPTS) {
            uint2 wv; wv.x = pk2(acc[j][0], acc[j][1]); wv.y = pk2(acc[j][2], acc[j][3]);
            *(uint2*)(Y + (size_t)n * CH + g * 4) = wv;
            s[0] += acc[j][0]; s[1] += acc[j][1]; s[2] += acc[j][2]; s[3] += acc[j][3];
            q[0] += acc[j][0] * acc[j][0]; q[1] += acc[j][1] * acc[j][1];
            q[2] += acc[j][2] * acc[j][2]; q[3] += acc[j][3] * acc[j][3];
        }
    }
    float* pb = statsP + (bid & (NPART - 1)) * 256;
    __syncthreads();
    *(float4*)&red[ps * 128 + g * 4] = make_float4(s[0], s[1], s[2], s[3]);
    __syncthreads();
    if (t < 128) {
        float tot = 0.f;
#pragma unroll
        for (int r = 0; r < 16; ++r) tot += red[r * 128 + t];
        atomicAdd(pb + t, tot);
    }
    __syncthreads();
    *(float4*)&red[ps * 128 + g * 4] = make_float4(q[0], q[1], q[2], q[3]);
    __syncthreads();
    if (t < 128) {
        float tot = 0.f;
#pragma unroll
        for (int r = 0; r < 16; ++r) tot += red[r * 128 + t];
        atomicAdd(pb + 128 + t, tot);
    }
}

// ---------- out = relu(bn2(c2) + fused) ----------
__global__ void final_kernel(const unsigned short* __restrict__ c2,
                             const float* __restrict__ cs, const float* __restrict__ cq,
                             const float* __restrict__ g, const float* __restrict__ b,
                             const unsigned short* __restrict__ fused, float* __restrict__ out)
{
    const int tot = NPTS * 32;
    for (int f = blockIdx.x * 256 + threadIdx.x; f < tot; f += gridDim.x * 256) {
        int n = f >> 5, c4 = (f & 31) << 2;
        float4 cs4 = *(const float4*)(cs + c4);
        float4 cq4 = *(const float4*)(cq + c4);
        float4 g4  = *(const float4*)(g + c4);
        float4 b4  = *(const float4*)(b + c4);
        float mx0 = cs4.x / (float)NPTS, mx1 = cs4.y / (float)NPTS,
              mx2 = cs4.z / (float)NPTS, mx3 = cs4.w / (float)NPTS;
        float sc0 = rsqrtf(cq4.x / (float)NPTS - mx0 * mx0 + BN_EPS) * g4.x;
        float sc1 = rsqrtf(cq4.y / (float)NPTS - mx1 * mx1 + BN_EPS) * g4.y;
        float sc2 = rsqrtf(cq4.z / (float)NPTS - mx2 * mx2 + BN_EPS) * g4.z;
        float sc3 = rsqrtf(cq4.w / (float)NPTS - mx3 * mx3 + BN_EPS) * g4.w;
        float sh0 = b4.x - mx0 * sc0, sh1 = b4.y - mx1 * sc1;
        float sh2 = b4.z - mx2 * sc2, sh3 = b4.w - mx3 * sc3;
        uint2 y2 = *(const uint2*)(c2 + (size_t)n * CH + c4);
        uint2 r2 = *(const uint2*)(fused + (size_t)n * CH + c4);
        float4 o;
        o.x = fmaxf(blo(y2.x) * sc0 + sh0 + blo(r2.x), 0.f);
        o.y = fmaxf(bhi(y2.x) * sc1 + sh1 + bhi(r2.x), 0.f);
        o.z = fmaxf(blo(y2.y) * sc2 + sh2 + blo(r2.y), 0.f);
        o.w = fmaxf(bhi(y2.y) * sc3 + sh3 + bhi(r2.y), 0.f);
        *(float4*)(out + (size_t)n * CH + c4) = o;
    }
}

// ---------- host ----------
extern "C" void kernel_launch(void* const* d_in, const int* in_sizes, int n_in,
                              void* d_out, int out_size, void* d_ws, size_t ws_size,
                              hipStream_t stream) {
    (void)in_sizes; (void)n_in; (void)out_size;
    const float* feat    = (const float*)d_in[0];
    const float* lw_W    = (const float*)d_in[1];
    const float* lw_g    = (const float*)d_in[2];
    const float* lw_b    = (const float*)d_in[3];
    const float* w_W     = (const float*)d_in[4];
    const float* proj_W  = (const float*)d_in[5];
    const float* proj_g  = (const float*)d_in[6];
    const float* proj_b  = (const float*)d_in[7];
    const float* adp_W   = (const float*)d_in[8];
    const float* fuse_W  = (const float*)d_in[9];
    const float* fuse_g  = (const float*)d_in[10];
    const float* fuse_b  = (const float*)d_in[11];
    const float* conv1_W = (const float*)d_in[12];
    const float* norm1_g = (const float*)d_in[13];
    const float* norm1_b = (const float*)d_in[14];
    const float* conv2_W = (const float*)d_in[15];
    const float* norm2_g = (const float*)d_in[16];
    const float* norm2_b = (const float*)d_in[17];
    const int*   clusters= (const int*)d_in[18];
    const int*   nidx    = (const int*)d_in[19];
    float* out = (float*)d_out;

    const size_t NC  = (size_t)NPTS * CH;
    const size_t SEG = (size_t)NSEG_ * CH;
    const size_t PSLOT = (size_t)NPART * 256;          // one stats slot (parts)

    const size_t zwords = 6 * NSEG_ + 10 * PSLOT;      // cnt,fpos,statsP
    const size_t tail   = 20 * 256 + 6 * NSEG_ + 3 * (size_t)NPTS + 4 * SEG + 98304;
    const size_t needed = (2 * NC + zwords + tail) * sizeof(float);   // ~165 MB
    if (ws_size < needed) return;

    float* ws = (float*)d_ws;
    unsigned short* B0 = (unsigned short*)ws;   // featB; later pk/pcnt alias
    unsigned short* B1 = B0 + NC;               // L -> q (in place) / fuseY / conv2 out
    unsigned short* B2 = B1 + NC;               // P / P3 / fused
    unsigned short* B3 = B2 + NC;               // agg / conv1 out
    float* Z  = ws + 2 * NC;
    int*   cnt   = (int*)Z;
    int*   fpos  = cnt + 3 * NSEG_;
    float* statsP = (float*)(fpos + 3 * NSEG_);        // 10 slots x NPART x 256 (zeroed)
    float* statsF = statsP + 10 * PSLOT;               // 10 x 256 collapsed
    float* scsh   = statsF + 10 * 256;                 // 10 x 256 bn scale/shift
    int*   off   = (int*)(scsh + 10 * 256);
    float* invc  = (float*)(off + 3 * NSEG_);
    int*   perm  = (int*)(invc + 3 * NSEG_);
    float* S1    = (float*)(perm + 3 * (size_t)NPTS);
    float* s3    = S1 + SEG;
    unsigned short* Wt16 = (unsigned short*)(s3 + 3 * SEG);
    unsigned short* lwT   = Wt16;
    unsigned short* wT    = Wt16 + 3 * 16384;
    unsigned short* projT = Wt16 + 6 * 16384;
    unsigned short* fuseT = Wt16 + 10 * 16384;
    int* pkArr = (int*)B0;
    int* pcnt  = pkArr + (size_t)NPTS * KOFF;

    const int gemmGrid = (NPTS + 127) / 128;
    const int convGrid = (NPTS + 127) / 128;
    const int aggGrid  = (NPTS + 63) / 64;
    const int mapGrid  = 2048;

    zero_kernel<<<256, 256, 0, stream>>>((float4*)Z, (int)(zwords / 4));
    count_kernel<<<512, 256, 0, stream>>>(clusters, cnt);
    invcnt_kernel<<<(3 * NSEG_ + 255) / 256, 256, 0, stream>>>(cnt, invc);
    scan_kernel<<<3, 1024, 0, stream>>>(cnt, off);
    fill_kernel<<<512, 256, 0, stream>>>(clusters, off, fpos, perm);
    cvt_bf16<<<mapGrid, 256, 0, stream>>>(feat, B0, (int)(NC / 8));
    wtr_all<<<768, 256, 0, stream>>>(lw_W, w_W, proj_W, fuse_W, Wt16);

    for (int i = 0; i < 3; ++i) {
        const int* cli   = clusters + (size_t)i * NPTS;
        const int* permi = perm + (size_t)i * NPTS;
        const int* offi  = off + i * NSEG_;
        const int* cnti  = cnt + i * NSEG_;
        float* pA = statsP + (size_t)i * PSLOT;        // lw stats parts
        float* pB = statsP + (size_t)(3 + i) * PSLOT;  // proj stats parts
        float* fA = statsF + i * 256;
        float* fB = statsF + (3 + i) * 256;
        float* ss = scsh + i * 256;                    // lw bn scale/shift (for q ABN)
        gemm_dual<<<gemmGrid, 256, 0, stream>>>(B0, lwT + (size_t)i * 16384,
            projT + (size_t)i * 16384, B1, B2, pA, pB);
        collapse2<<<2, 128, 0, stream>>>(pA, lw_g + i * CH, lw_b + i * CH, fA, ss,
                                         pB, nullptr, nullptr, fB, nullptr);
        gather_s1<<<NSEG_, 256, 0, stream>>>(B1, fA, fA + 128, lw_g + i * CH, lw_b + i * CH,
            permi, offi, cnti, S1);
        // q = (relu(bn(L)) - mean[cl]) @ w_W[i] -> B1 in place (bf16)   ACEN|ABN|CBF = 67
        gemm_one<67><<<gemmGrid, 256, 0, stream>>>(B1, nullptr, wT + (size_t)i * 16384, B1,
            cli, S1, invc + i * NSEG_, ss, ss + 128, nullptr);
        gather_s23<<<NSEG_, 256, 0, stream>>>(B1, B2, fB, fB + 128, proj_g + i * CH, proj_b + i * CH,
            permi, offi, cnti, s3 + (size_t)i * SEG);
    }

    adpagg_kernel<<<aggGrid, 256, 0, stream>>>(B0, adp_W,
        clusters, clusters + NPTS, clusters + 2 * (size_t)NPTS,
        s3, s3 + SEG, s3 + 2 * SEG, B3);

    // P3 -> B2 (STATS|CBF = 72), collapse slot6 with proj bn -> scsh6
    gemm_one<72><<<gemmGrid, 256, 0, stream>>>(B0, nullptr, projT + 3 * (size_t)16384, B2,
        nullptr, nullptr, nullptr, nullptr, nullptr, statsP + 6 * PSLOT);
    collapse2<<<1, 128, 0, stream>>>(statsP + 6 * PSLOT, proj_g + 3 * CH, proj_b + 3 * CH,
        statsF + 6 * 256, scsh + 6 * 256, nullptr, nullptr, nullptr, nullptr, nullptr);
    // fuseY = [relu(bn(P3)), agg] @ fuse_W -> B1 (CBF|K256|STATS|ABN = 106)
    gemm_one<106><<<gemmGrid, 256, 0, stream>>>(B2, B3, fuseT, B1,
        nullptr, nullptr, nullptr, scsh + 6 * 256, scsh + 6 * 256 + 128, statsP + 7 * PSLOT);
    collapse2<<<1, 128, 0, stream>>>(statsP + 7 * PSLOT, nullptr, nullptr,
        statsF + 7 * 256, nullptr, nullptr, nullptr, nullptr, nullptr, nullptr);
    // fused = relu(bn(fuseY)) + featB -> B2   (last reader of B0-as-featB)
    fused_kernel<<<mapGrid, 256, 0, stream>>>(B1, statsF + 7 * 256, statsF + 7 * 256 + 128,
        fuse_g, fuse_b, B0, B2);

    compact_nidx<<<(NPTS + 255) / 256, 256, 0, stream>>>(nidx, pkArr, pcnt);

    // conv1: B2 -> B3, stats slot8
    conv_kernel<false><<<convGrid, 512, 0, stream>>>(B2, conv1_W, pkArr, pcnt,
        nullptr, nullptr, nullptr, nullptr, B3, statsP + 8 * PSLOT);
    collapse2<<<1, 128, 0, stream>>>(statsP + 8 * PSLOT, nullptr, nullptr,
        statsF + 8 * 256, nullptr, nullptr, nullptr, nullptr, nullptr, nullptr);
    // conv2: bn1(B3) -> B1, stats slot9
    conv_kernel<true><<<convGrid, 512, 0, stream>>>(B3, conv2_W, pkArr, pcnt,
        statsF + 8 * 256, statsF + 8 * 256 + 128, norm1_g, norm1_b,
        B1, statsP + 9 * PSLOT);
    collapse2<<<1, 128, 0, stream>>>(statsP + 9 * PSLOT, nullptr, nullptr,
        statsF + 9 * 256, nullptr, nullptr, nullptr, nullptr, nullptr, nullptr);
    // out = relu(bn2(B1) + B2)
    final_kernel<<<mapGrid, 256, 0, stream>>>(B1, statsF + 9 * 256, statsF + 9 * 256 + 128,
        norm2_g, norm2_b, B2, out);
}